// Round 2
// baseline (622.707 us; speedup 1.0000x reference)
//
#include <hip/hip_runtime.h>
#include <cstddef>

typedef unsigned short u16;
typedef __attribute__((ext_vector_type(8))) short bf8;   // 8 x bf16 (4 VGPRs)
typedef __attribute__((ext_vector_type(4))) float f4;
typedef __attribute__((ext_vector_type(4))) unsigned short us4;

#define NATOMS 11776
#define NBLK   368

__device__ __forceinline__ u16 f2b(float x){
  union { float f; unsigned u; } v; v.f = x;
  unsigned r = v.u + 0x7fffu + ((v.u >> 16) & 1u);
  return (u16)(r >> 16);
}
__device__ __forceinline__ f4 f4zero(){ f4 z = {0.f,0.f,0.f,0.f}; return z; }
__device__ __forceinline__ f4 mfma16(bf8 a, bf8 b, f4 c){
  return __builtin_amdgcn_mfma_f32_16x16x32_bf16(a, b, c, 0, 0, 0);
}
__device__ __forceinline__ int iclamp(int v, int lo, int hi){ return v < lo ? lo : (v > hi ? hi : v); }

// ---------------------------------------------------------------- convert fp32 -> bf16
struct CvtArgs {
  const float* src[13];
  u16* dst[13];
  int n4[13];
};

__global__ __launch_bounds__(256) void k_convert(CvtArgs a){
  int stride = gridDim.x * 256;
  int tid = blockIdx.x * 256 + threadIdx.x;
  for (int s = 0; s < 13; ++s){
    const float4* src = (const float4*)a.src[s];
    us4* dst = (us4*)a.dst[s];
    int n = a.n4[s];
    for (int i = tid; i < n; i += stride){
      float4 v = src[i];
      us4 o;
      o.x = f2b(v.x); o.y = f2b(v.y); o.z = f2b(v.z); o.w = f2b(v.w);
      dst[i] = o;
    }
  }
}

// ---------------------------------------------------------------- generic 16-row MFMA strip GEMM
// WG = 256 threads (4 waves). Computes C[16][N] = A16[16][K] @ W[N][K]^T into LDS (f32).
template<int N, int K>
__device__ __forceinline__ void gemm_strip(const u16* __restrict__ A, const u16* __restrict__ W, float* L){
  constexpr int CPW = N / 4;       // cols per wave
  constexpr int T = CPW / 16;      // 16x16 tiles per wave
  const int lane = threadIdx.x & 63;
  const int wave = threadIdx.x >> 6;
  const int rr = lane & 15, grp = lane >> 4;
  f4 acc[T];
#pragma unroll
  for (int t = 0; t < T; ++t) acc[t] = f4zero();
#pragma unroll
  for (int kc = 0; kc < K / 32; ++kc){
    bf8 af = *(const bf8*)(A + rr * K + kc * 32 + grp * 8);
#pragma unroll
    for (int t = 0; t < T; ++t){
      const u16* wp = W + (size_t)(wave * CPW + t * 16 + rr) * K + kc * 32 + grp * 8;
      acc[t] = mfma16(af, *(const bf8*)wp, acc[t]);
    }
  }
  // C/D layout (verified): col = lane&15, row = (lane>>4)*4 + reg
#pragma unroll
  for (int t = 0; t < T; ++t)
#pragma unroll
    for (int r = 0; r < 4; ++r)
      L[(grp * 4 + r) * N + wave * CPW + t * 16 + rr] = acc[t][r];
}

// plain f32 output
template<int N, int K>
__global__ __launch_bounds__(256) void k_gemm_f32(const u16* __restrict__ A, const u16* __restrict__ W,
                                                  float* __restrict__ out){
  __shared__ float L[16 * N];
  const int strip = blockIdx.x;
  gemm_strip<N, K>(A + (size_t)strip * 16 * K, W, L);
  __syncthreads();
  const size_t base = (size_t)strip * 16 * N;
  for (int i = threadIdx.x; i < 16 * N; i += 256) out[base + i] = L[i];
}

// x = sigmoid(gb[:,:128]) * lnA + gb[:,128:]  (adaLN)  -> bf16
__global__ __launch_bounds__(256) void k_gemm_x(const u16* __restrict__ A, const u16* __restrict__ W,
                                                const float* __restrict__ lnA, u16* __restrict__ xout){
  __shared__ float L[16 * 256];
  const int strip = blockIdx.x;
  gemm_strip<256, 128>(A + (size_t)strip * 2048, W, L);
  __syncthreads();
  for (int i = threadIdx.x; i < 16 * 128; i += 256){
    int r = i >> 7, c = i & 127;
    float g1 = L[r * 256 + c], g2 = L[r * 256 + 128 + c];
    float s = 1.f / (1.f + __expf(-g1));
    size_t idx = (size_t)(strip * 16 + r) * 128 + c;
    xout[idx] = f2b(s * lnA[idx] + g2);
  }
}

// qkv with q-bias + score-scale folded into q  -> bf16
__global__ __launch_bounds__(256) void k_gemm_qkv(const u16* __restrict__ A, const u16* __restrict__ W,
                                                  const float* __restrict__ qb, u16* __restrict__ out){
  __shared__ float L[16 * 384];
  const int strip = blockIdx.x;
  gemm_strip<384, 128>(A + (size_t)strip * 2048, W, L);
  __syncthreads();
  const float scale = 0.17677669529663687f; // 1/sqrt(32)
  for (int i = threadIdx.x; i < 16 * 384; i += 256){
    int r = i / 384, c = i - r * 384;
    float v = L[i];
    if (c < 128) v = (v + qb[c]) * scale;
    out[(size_t)(strip * 16 + r) * 384 + c] = f2b(v);
  }
}

// gate = sigmoid(gemm + gate_b)  -> f32
__global__ __launch_bounds__(256) void k_gemm_gate(const u16* __restrict__ A, const u16* __restrict__ W,
                                                   const float* __restrict__ gb, float* __restrict__ gate){
  __shared__ float L[16 * 128];
  const int strip = blockIdx.x;
  gemm_strip<128, 128>(A + (size_t)strip * 2048, W, L);
  __syncthreads();
  for (int i = threadIdx.x; i < 2048; i += 256){
    int c = i & 127;
    gate[(size_t)strip * 2048 + i] = 1.f / (1.f + __expf(-(L[i] + gb[c])));
  }
}

// relu epilogue (atom_out = relu(a @ W_tok^T)) -> f32
__global__ __launch_bounds__(256) void k_gemm_relu(const u16* __restrict__ A, const u16* __restrict__ W,
                                                   float* __restrict__ out){
  __shared__ float L[16 * 384];
  const int strip = blockIdx.x;
  gemm_strip<384, 128>(A + (size_t)strip * 2048, W, L);
  __syncthreads();
  const size_t base = (size_t)strip * 16 * 384;
  for (int i = threadIdx.x; i < 16 * 384; i += 256) out[base + i] = fmaxf(L[i], 0.f);
}

// GLU: g = silu(ab[:,:256]) * ab[:,256:]  -> bf16
__global__ __launch_bounds__(256) void k_gemm_glu(const u16* __restrict__ A, const u16* __restrict__ W,
                                                  u16* __restrict__ g){
  __shared__ float L[16 * 512];
  const int strip = blockIdx.x;
  gemm_strip<512, 128>(A + (size_t)strip * 2048, W, L);
  __syncthreads();
  for (int i = threadIdx.x; i < 16 * 256; i += 256){
    int r = i >> 8, c = i & 255;
    float ab1 = L[r * 512 + c], ab2 = L[r * 512 + 256 + c];
    float silu = ab1 / (1.f + __expf(-ab1));
    g[(size_t)(strip * 16 + r) * 256 + c] = f2b(silu * ab2);
  }
}

// h-gemm (K=256) + gated residual a += gate*h, then row-LN -> lnA
__global__ __launch_bounds__(256) void k_gemm_tb(const u16* __restrict__ A, const u16* __restrict__ W,
                                                 const float* __restrict__ gate, float* __restrict__ a,
                                                 u16* __restrict__ a_bf, float* __restrict__ lnA){
  __shared__ float L[16 * 128];
  const int strip = blockIdx.x;
  gemm_strip<128, 256>(A + (size_t)strip * 16 * 256, W, L);
  __syncthreads();
  for (int i = threadIdx.x; i < 2048; i += 256){
    size_t idx = (size_t)strip * 2048 + i;
    float v = a[idx] + gate[idx] * L[i];
    a[idx] = v;
    a_bf[idx] = f2b(v);
    L[i] = v;
  }
  __syncthreads();
  int r = threadIdx.x >> 4, s = threadIdx.x & 15;
  float sum = 0.f, sq = 0.f;
#pragma unroll
  for (int j = 0; j < 8; ++j){ float v = L[r * 128 + s * 8 + j]; sum += v; sq += v * v; }
#pragma unroll
  for (int m = 1; m < 16; m <<= 1){ sum += __shfl_xor(sum, m); sq += __shfl_xor(sq, m); }
  float mu = sum * (1.f / 128.f);
  float var = sq * (1.f / 128.f) - mu * mu;
  float rs = rsqrtf(var + 1e-5f);
#pragma unroll
  for (int j = 0; j < 8; ++j){
    int c = s * 8 + j;
    lnA[(size_t)(strip * 16 + r) * 128 + c] = (L[r * 128 + c] - mu) * rs;
  }
}

// ---------------------------------------------------------------- LN(c) + relu -> ph/pw projections
__global__ __launch_bounds__(256) void k_ln_phpw(const float* __restrict__ c, float* __restrict__ lnA,
                                                 u16* __restrict__ slnb, const float* __restrict__ Wph,
                                                 const float* __restrict__ Wpw, float* __restrict__ ph,
                                                 float* __restrict__ pw){
  __shared__ float rs[4][128];
  const int wave = threadIdx.x >> 6, lane = threadIdx.x & 63;
  const int row = blockIdx.x * 4 + wave;
  const float* cr = c + (size_t)row * 128;
  float2 v = *(const float2*)(cr + lane * 2);
  float sum = v.x + v.y, sq = v.x * v.x + v.y * v.y;
#pragma unroll
  for (int m = 1; m < 64; m <<= 1){ sum += __shfl_xor(sum, m); sq += __shfl_xor(sq, m); }
  float mu = sum * (1.f / 128.f);
  float var = sq * (1.f / 128.f) - mu * mu;
  float r = rsqrtf(var + 1e-5f);
  float s0 = (v.x - mu) * r, s1 = (v.y - mu) * r;
  size_t base = (size_t)row * 128 + lane * 2;
  lnA[base] = s0; lnA[base + 1] = s1;
  slnb[base] = f2b(s0); slnb[base + 1] = f2b(s1);
  rs[wave][lane * 2] = fmaxf(s0, 0.f); rs[wave][lane * 2 + 1] = fmaxf(s1, 0.f);
  __syncthreads();
  int h = lane & 15, part = lane >> 4;
  float acch = 0.f, accw = 0.f;
#pragma unroll
  for (int k = 0; k < 32; ++k){
    int kk = part * 32 + k;
    float rv = rs[wave][kk];
    acch += rv * Wph[h * 128 + kk];
    accw += rv * Wpw[h * 128 + kk];
  }
  acch += __shfl_xor(acch, 16); acch += __shfl_xor(acch, 32);
  accw += __shfl_xor(accw, 16); accw += __shfl_xor(accw, 32);
  if (lane < 16){
    ph[(size_t)row * 16 + h] = acch;
    pw[(size_t)row * 16 + h] = accw;
  }
}

// ---------------------------------------------------------------- pair-bias MLP v2 -> bias[b][h][q][k]
// grid: NBLK*8 blocks; block handles 4 q-rows x 128 k. Thread: k = t&127, 2 q's.
// LN affine folded into pb projection: pb_h = rr*(dot(p,w2_h) - mu*w2sum_h) + bb_h,
//   w2 = pb_w * ln_w (elementwise over channel), bb_h = dot(pb_w[h], ln_b).
__global__ __launch_bounds__(256) void k_pb(const float* __restrict__ ph, const float* __restrict__ pw,
                                            const float* __restrict__ W1, const float* __restrict__ W2,
                                            const float* __restrict__ lnw, const float* __restrict__ lnb,
                                            const float* __restrict__ pbw, float* __restrict__ bias){
  __shared__ float sW1[256], sW2[256], sw2[64], sw2sum[4], sbb[4];
  const int t = threadIdx.x;
  const int b = blockIdx.x >> 3, qblk = blockIdx.x & 7;
  if (t < 256){ sW1[t] = W1[t]; }
  else {}
  sW2[t] = W2[t]; // t in [0,256)
  if (t < 64) sw2[t] = pbw[t] * lnw[t & 15];
  if (t < 4){
    float s = 0.f, b2 = 0.f;
#pragma unroll
    for (int cc = 0; cc < 16; ++cc){
      s  += pbw[t * 16 + cc] * lnw[cc];
      b2 += pbw[t * 16 + cc] * lnb[cc];
    }
    sw2sum[t] = s;
    sbb[t] = b2;
  }
  __syncthreads();
  const int k = t & 127, qh = t >> 7;
  const int win = b * 32 + k - 48;
  const bool valid = (win >= 0) && (win < NATOMS);
  const int ka = iclamp(win, 0, NATOMS - 1);
  const float negv = valid ? 0.f : -1e9f;
  // pw row (vectorized)
  float pwv[16];
  {
    const float4* p4 = (const float4*)(pw + (size_t)ka * 16);
#pragma unroll
    for (int j = 0; j < 4; ++j){
      float4 v = p4[j];
      pwv[j * 4 + 0] = v.x; pwv[j * 4 + 1] = v.y; pwv[j * 4 + 2] = v.z; pwv[j * 4 + 3] = v.w;
    }
  }
#pragma unroll
  for (int i = 0; i < 2; ++i){
    int q = qblk * 4 + qh * 2 + i;
    int qa = b * 32 + q;
    float p[16];
    {
      const float4* p4 = (const float4*)(ph + (size_t)qa * 16);
#pragma unroll
      for (int j = 0; j < 4; ++j){
        float4 v = p4[j];
        p[j * 4 + 0] = v.x + pwv[j * 4 + 0];
        p[j * 4 + 1] = v.y + pwv[j * 4 + 1];
        p[j * 4 + 2] = v.z + pwv[j * 4 + 2];
        p[j * 4 + 3] = v.w + pwv[j * 4 + 3];
      }
    }
    float rp[16];
#pragma unroll
    for (int cc = 0; cc < 16; ++cc) rp[cc] = fmaxf(p[cc], 0.f);
    float m[16];
#pragma unroll
    for (int o = 0; o < 16; ++o){
      float s = 0.f;
#pragma unroll
      for (int cc = 0; cc < 16; ++cc) s += rp[cc] * sW1[o * 16 + cc];
      m[o] = fmaxf(s, 0.f);
    }
    float sum = 0.f, sq = 0.f;
#pragma unroll
    for (int cc = 0; cc < 16; ++cc){
      float s = 0.f;
#pragma unroll
      for (int o = 0; o < 16; ++o) s += m[o] * sW2[cc * 16 + o];
      float v = p[cc] + s;
      p[cc] = v;
      sum += v; sq += v * v;
    }
    float mu = sum * (1.f / 16.f);
    float var = sq * (1.f / 16.f) - mu * mu;
    float rr = rsqrtf(var + 1e-5f);
#pragma unroll
    for (int hh = 0; hh < 4; ++hh){
      float d = 0.f;
#pragma unroll
      for (int cc = 0; cc < 16; ++cc) d += p[cc] * sw2[hh * 16 + cc];
      float pb = rr * (d - mu * sw2sum[hh]) + sbb[hh];
      bias[((size_t)((b * 4 + hh) * 32) + q) * 128 + k] = pb + negv;
    }
  }
}

// ---------------------------------------------------------------- block attention + out-proj + residual + row-LN
__global__ __launch_bounds__(256) void k_attn(const u16* __restrict__ qkv, const float* __restrict__ bias,
                                              const u16* __restrict__ outw, const float* __restrict__ outb,
                                              float* __restrict__ a, float* __restrict__ lnA){
  __shared__ u16 VT[128][136];      // V transposed: [dim][k-atom]
  __shared__ u16 P[4][32 * 136];    // softmax probs per head
  __shared__ u16 O[32][136];        // attention output (q x 128)
  __shared__ float aL[32][128];     // updated residual rows for LN
  const int t = threadIdx.x;
  const int lane = t & 63, wave = t >> 6;
  const int b = blockIdx.x;
  const int rr = lane & 15, grp = lane >> 4;

  for (int i = 0; i < 8; ++i){
    int s = t + 256 * i;
    int ka = s & 127, d0 = (s >> 7) * 8;
    int win = b * 32 + ka - 48;
    int src = iclamp(win, 0, NATOMS - 1);
    bf8 v = *(const bf8*)(qkv + (size_t)src * 384 + 256 + d0);
#pragma unroll
    for (int j = 0; j < 8; ++j) VT[d0 + j][ka] = (u16)v[j];
  }
  __syncthreads();

  const int h = wave;
  bf8 kfr[8];
#pragma unroll
  for (int kt = 0; kt < 8; ++kt){
    int ka = kt * 16 + rr;
    int win = b * 32 + ka - 48;
    int src = iclamp(win, 0, NATOMS - 1);
    kfr[kt] = *(const bf8*)(qkv + (size_t)src * 384 + 128 + h * 32 + grp * 8);
  }
  f4 S[2][8];
#pragma unroll
  for (int qt = 0; qt < 2; ++qt){
    bf8 qf = *(const bf8*)(qkv + (size_t)(b * 32 + qt * 16 + rr) * 384 + h * 32 + grp * 8);
#pragma unroll
    for (int kt = 0; kt < 8; ++kt){
      S[qt][kt] = f4zero();
      S[qt][kt] = mfma16(qf, kfr[kt], S[qt][kt]);
    }
  }
  const float* brow = bias + (size_t)((b * 4 + h) * 32) * 128;
#pragma unroll
  for (int qt = 0; qt < 2; ++qt){
#pragma unroll
    for (int r = 0; r < 4; ++r){
      int q = qt * 16 + grp * 4 + r;
      float vals[8];
      float mx = -1e30f;
#pragma unroll
      for (int kt = 0; kt < 8; ++kt){
        float v = S[qt][kt][r] + brow[q * 128 + kt * 16 + rr];
        vals[kt] = v;
        mx = fmaxf(mx, v);
      }
#pragma unroll
      for (int m = 1; m < 16; m <<= 1) mx = fmaxf(mx, __shfl_xor(mx, m));
      float sum = 0.f;
#pragma unroll
      for (int kt = 0; kt < 8; ++kt){ vals[kt] = __expf(vals[kt] - mx); sum += vals[kt]; }
#pragma unroll
      for (int m = 1; m < 16; m <<= 1) sum += __shfl_xor(sum, m);
      float inv = 1.f / sum;
#pragma unroll
      for (int kt = 0; kt < 8; ++kt)
        P[h][q * 136 + kt * 16 + rr] = f2b(vals[kt] * inv);
    }
  }
  __syncthreads();
  f4 oacc[2][2];
#pragma unroll
  for (int qt = 0; qt < 2; ++qt)
#pragma unroll
    for (int dt = 0; dt < 2; ++dt) oacc[qt][dt] = f4zero();
#pragma unroll
  for (int kc = 0; kc < 4; ++kc){
#pragma unroll
    for (int qt = 0; qt < 2; ++qt){
      bf8 pa = *(const bf8*)(&P[h][(qt * 16 + rr) * 136 + kc * 32 + grp * 8]);
#pragma unroll
      for (int dt = 0; dt < 2; ++dt){
        bf8 vb = *(const bf8*)(&VT[h * 32 + dt * 16 + rr][kc * 32 + grp * 8]);
        oacc[qt][dt] = mfma16(pa, vb, oacc[qt][dt]);
      }
    }
  }
#pragma unroll
  for (int qt = 0; qt < 2; ++qt)
#pragma unroll
    for (int dt = 0; dt < 2; ++dt)
#pragma unroll
      for (int r = 0; r < 4; ++r)
        O[qt * 16 + grp * 4 + r][h * 32 + dt * 16 + rr] = f2b(oacc[qt][dt][r]);
  __syncthreads();
  f4 pacc[2][2];
#pragma unroll
  for (int qt = 0; qt < 2; ++qt)
#pragma unroll
    for (int ct = 0; ct < 2; ++ct) pacc[qt][ct] = f4zero();
#pragma unroll
  for (int kc = 0; kc < 4; ++kc){
    bf8 a0 = *(const bf8*)(&O[rr][kc * 32 + grp * 8]);
    bf8 a1 = *(const bf8*)(&O[16 + rr][kc * 32 + grp * 8]);
#pragma unroll
    for (int ct = 0; ct < 2; ++ct){
      bf8 wf = *(const bf8*)(outw + (size_t)(wave * 32 + ct * 16 + rr) * 128 + kc * 32 + grp * 8);
      pacc[0][ct] = mfma16(a0, wf, pacc[0][ct]);
      pacc[1][ct] = mfma16(a1, wf, pacc[1][ct]);
    }
  }
#pragma unroll
  for (int qt = 0; qt < 2; ++qt)
#pragma unroll
    for (int ct = 0; ct < 2; ++ct)
#pragma unroll
      for (int r = 0; r < 4; ++r){
        int q = qt * 16 + grp * 4 + r;
        int col = wave * 32 + ct * 16 + rr;
        size_t idx = (size_t)(b * 32 + q) * 128 + col;
        float v = a[idx] + pacc[qt][ct][r] + outb[col];
        a[idx] = v;
        aL[q][col] = v;
      }
  __syncthreads();
  {
    int r = t >> 3, s8 = t & 7;
    float sum = 0.f, sq = 0.f;
#pragma unroll
    for (int j = 0; j < 16; ++j){ float v = aL[r][s8 * 16 + j]; sum += v; sq += v * v; }
#pragma unroll
    for (int m = 1; m < 8; m <<= 1){ sum += __shfl_xor(sum, m); sq += __shfl_xor(sq, m); }
    float mu = sum * (1.f / 128.f);
    float var = sq * (1.f / 128.f) - mu * mu;
    float rs = rsqrtf(var + 1e-5f);
#pragma unroll
    for (int j = 0; j < 16; ++j){
      int c = s8 * 16 + j;
      lnA[(size_t)(b * 32 + r) * 128 + c] = (aL[r][c] - mu) * rs;
    }
  }
}

// ---------------------------------------------------------------- segment mean (atoms -> tokens)
__device__ __forceinline__ int lbound(const int* __restrict__ arr, int n, int v){
  int lo = 0, hi = n;
  while (lo < hi){ int mid = (lo + hi) >> 1; if (arr[mid] < v) lo = mid + 1; else hi = mid; }
  return lo;
}

__global__ __launch_bounds__(256) void k_segmean(const float* __restrict__ atom_out,
                                                 const int* __restrict__ a2t, u16* __restrict__ tokbf){
  const int tok = blockIdx.x;
  __shared__ int lo_s, hi_s;
  if (threadIdx.x == 0){
    lo_s = lbound(a2t, NATOMS, tok);
    hi_s = lbound(a2t, NATOMS, tok + 1);
  }
  __syncthreads();
  int lo = lo_s, hi = hi_s;
  float inv = 1.f / fmaxf((float)(hi - lo), 1.f);
  for (int c = threadIdx.x; c < 384; c += 256){
    float s = 0.f;
    for (int aa = lo; aa < hi; ++aa) s += atom_out[(size_t)aa * 384 + c];
    tokbf[(size_t)tok * 384 + c] = f2b(s * inv);
  }
}

// ---------------------------------------------------------------- pair head: tpf@Wp^T + u_i + u_j
__global__ __launch_bounds__(256) void k_pair(const float* __restrict__ tpf, const float* __restrict__ Wp,
                                              const float* __restrict__ u, float* __restrict__ out){
  __shared__ float stpf[32][32];
  const int blk = blockIdx.x;
  const int pair0 = blk * 32;
  const int t = threadIdx.x;
  for (int idx = t; idx < 1024; idx += 256){
    int pp = idx >> 5, k = idx & 31;
    int p = pair0 + pp;
    stpf[pp][k] = tpf[(size_t)p * 32 + k];
  }
  __syncthreads();
  const int c = t & 127;
  const int half = t >> 7;
  float w[32];
#pragma unroll
  for (int k = 0; k < 32; ++k) w[k] = Wp[c * 32 + k];
  const int i = pair0 >> 9;
  const float ui = u[(size_t)i * 256 + c];
  for (int pp = half * 16; pp < half * 16 + 16; ++pp){
    int p = pair0 + pp;
    int j = p & 511;
    float s = ui + u[(size_t)j * 256 + 128 + c];
#pragma unroll
    for (int k = 0; k < 32; ++k) s += stpf[pp][k] * w[k];
    out[(size_t)p * 128 + c] = s;
  }
}

// ================================================================ host
extern "C" void kernel_launch(void* const* d_in, const int* in_sizes, int n_in,
                              void* d_out, int out_size, void* d_ws, size_t ws_size,
                              hipStream_t stream){
  (void)in_sizes; (void)n_in; (void)out_size; (void)ws_size;
  const float* atom_feats = (const float*)d_in[0];
  const float* tpf        = (const float*)d_in[1];
  const float* W_cond     = (const float*)d_in[2];
  const float* W_ph       = (const float*)d_in[3];
  const float* W_pw       = (const float*)d_in[4];
  const float* W_mlp1     = (const float*)d_in[5];
  const float* W_mlp2     = (const float*)d_in[6];
  const float* pb_ln_w    = (const float*)d_in[7];
  const float* pb_ln_b    = (const float*)d_in[8];
  const float* pb_w       = (const float*)d_in[9];
  const float* sln_w      = (const float*)d_in[10];
  const float* qkv_w      = (const float*)d_in[11];
  const float* q_bias     = (const float*)d_in[12];
  const float* out_w      = (const float*)d_in[13];
  const float* out_b      = (const float*)d_in[14];
  const float* ada_w      = (const float*)d_in[15];
  const float* ta_w       = (const float*)d_in[16];
  const float* tb_w       = (const float*)d_in[17];
  const float* gate_w     = (const float*)d_in[18];
  const float* gate_b     = (const float*)d_in[19];
  const float* W_tok      = (const float*)d_in[20];
  const float* W_trunk    = (const float*)d_in[21];
  const float* W_struct   = (const float*)d_in[22];
  const float* W_pairin   = (const float*)d_in[23];
  const float* W_outer    = (const float*)d_in[24];
  const int*   a2t        = (const int*)d_in[28];

  char* wsb = (char*)d_ws;
  size_t off = 0;
  auto alc = [&](size_t bytes) -> void* {
    void* r = wsb + off;
    off = (off + bytes + 255) & ~(size_t)255;
    return r;
  };

  u16* af_bf     = (u16*)alc((size_t)NATOMS * 128 * 2);
  u16* wcond_bf  = (u16*)alc(16384 * 2);
  u16* sln_bfw   = (u16*)alc(98304 * 2);
  u16* qkv_bfw   = (u16*)alc(147456 * 2);
  u16* out_bfw   = (u16*)alc(49152 * 2);
  u16* ada_bfw   = (u16*)alc(98304 * 2);
  u16* ta_bfw    = (u16*)alc(196608 * 2);
  u16* tb_bfw    = (u16*)alc(98304 * 2);
  u16* gate_bfw  = (u16*)alc(49152 * 2);
  u16* tok_bfw   = (u16*)alc(49152 * 2);
  u16* trunk_bfw = (u16*)alc(147456 * 2);
  u16* struct_bfw= (u16*)alc(147456 * 2);
  u16* outer_bfw = (u16*)alc(98304 * 2);
  float* a_f     = (float*)alc((size_t)NATOMS * 128 * 4);
  float* lnA     = (float*)alc((size_t)NATOMS * 128 * 4);
  u16* sln_bf    = (u16*)alc((size_t)NATOMS * 128 * 2);
  u16* x_bf      = (u16*)alc((size_t)NATOMS * 128 * 2);
  u16* qkv_bf    = (u16*)alc((size_t)NATOMS * 384 * 2);
  u16* g_bf      = (u16*)alc((size_t)NATOMS * 256 * 2);
  float* gate_f  = (float*)alc((size_t)NATOMS * 128 * 4);
  u16* a_bf      = (u16*)alc((size_t)NATOMS * 128 * 2);
  float* ph      = (float*)alc((size_t)NATOMS * 16 * 4);
  float* pw      = (float*)alc((size_t)NATOMS * 16 * 4);
  float* bias    = (float*)alc((size_t)NBLK * 4 * 32 * 128 * 4);
  float* atom_out= bias; // alias: bias dead after layer-2 attention
  u16* tok_bf    = (u16*)alc(512 * 384 * 2);
  float* u_f     = (float*)alc(512 * 256 * 4);

  float* s_trunk  = (float*)d_out;
  float* s_struct = s_trunk + 512 * 384;
  float* pair_out = s_struct + 512 * 384;

  CvtArgs ca;
  const float* srcs[13] = {atom_feats, W_cond, sln_w, qkv_w, out_w, ada_w, ta_w, tb_w,
                           gate_w, W_tok, W_trunk, W_struct, W_outer};
  u16* dsts[13] = {af_bf, wcond_bf, sln_bfw, qkv_bfw, out_bfw, ada_bfw, ta_bfw, tb_bfw,
                   gate_bfw, tok_bfw, trunk_bfw, struct_bfw, outer_bfw};
  int n4s[13] = {NATOMS * 128 / 4, 4096, 24576, 36864, 12288, 24576, 49152, 24576,
                 12288, 12288, 36864, 36864, 24576};
  for (int s = 0; s < 13; ++s){ ca.src[s] = srcs[s]; ca.dst[s] = dsts[s]; ca.n4[s] = n4s[s]; }
  k_convert<<<512, 256, 0, stream>>>(ca);

  k_gemm_f32<128, 128><<<736, 256, 0, stream>>>(af_bf, wcond_bf, a_f);
  k_ln_phpw<<<2944, 256, 0, stream>>>(a_f, lnA, sln_bf, W_ph, W_pw, ph, pw);
  k_pb<<<NBLK * 8, 256, 0, stream>>>(ph, pw, W_mlp1, W_mlp2, pb_ln_w, pb_ln_b, pb_w, bias);

  for (int l = 0; l < 3; ++l){
    const u16* slnW  = sln_bfw  + (size_t)l * 256 * 128;
    const u16* qkvW  = qkv_bfw  + (size_t)l * 384 * 128;
    const u16* outW  = out_bfw  + (size_t)l * 128 * 128;
    const u16* adaW  = ada_bfw  + (size_t)l * 256 * 128;
    const u16* taW   = ta_bfw   + (size_t)l * 512 * 128;
    const u16* tbW   = tb_bfw   + (size_t)l * 128 * 256;
    const u16* gateW = gate_bfw + (size_t)l * 128 * 128;
    k_gemm_x<<<736, 256, 0, stream>>>(sln_bf, slnW, lnA, x_bf);
    k_gemm_qkv<<<736, 256, 0, stream>>>(x_bf, qkvW, q_bias + l * 128, qkv_bf);
    k_gemm_gate<<<736, 256, 0, stream>>>(sln_bf, gateW, gate_b + l * 128, gate_f);
    k_attn<<<NBLK, 256, 0, stream>>>(qkv_bf, bias, outW, out_b + l * 128, a_f, lnA);
    k_gemm_x<<<736, 256, 0, stream>>>(sln_bf, adaW, lnA, x_bf);
    k_gemm_glu<<<736, 256, 0, stream>>>(x_bf, taW, g_bf);
    k_gemm_tb<<<736, 256, 0, stream>>>(g_bf, tbW, gate_f, a_f, a_bf, lnA);
  }

  k_gemm_relu<<<736, 256, 0, stream>>>(a_bf, tok_bfw, atom_out);
  k_segmean<<<512, 256, 0, stream>>>(atom_out, a2t, tok_bf);
  k_gemm_f32<384, 384><<<32, 256, 0, stream>>>(tok_bf, trunk_bfw, s_trunk);
  k_gemm_f32<384, 384><<<32, 256, 0, stream>>>(tok_bf, struct_bfw, s_struct);
  k_gemm_f32<256, 384><<<32, 256, 0, stream>>>(tok_bf, outer_bfw, u_f);
  k_pair<<<8192, 256, 0, stream>>>(tpf, W_pairin, u_f, pair_out);
}

// Round 3
// 607.627 us; speedup vs baseline: 1.0248x; 1.0248x over previous
//
#include <hip/hip_runtime.h>
#include <cstddef>

typedef unsigned short u16;
typedef __attribute__((ext_vector_type(8))) short bf8;   // 8 x bf16 (4 VGPRs)
typedef __attribute__((ext_vector_type(4))) float f4;
typedef __attribute__((ext_vector_type(4))) unsigned short us4;

#define NATOMS 11776
#define NBLK   368

__device__ __forceinline__ u16 f2b(float x){
  union { float f; unsigned u; } v; v.f = x;
  unsigned r = v.u + 0x7fffu + ((v.u >> 16) & 1u);
  return (u16)(r >> 16);
}
__device__ __forceinline__ f4 f4zero(){ f4 z = {0.f,0.f,0.f,0.f}; return z; }
__device__ __forceinline__ f4 mfma16(bf8 a, bf8 b, f4 c){
  return __builtin_amdgcn_mfma_f32_16x16x32_bf16(a, b, c, 0, 0, 0);
}
__device__ __forceinline__ int iclamp(int v, int lo, int hi){ return v < lo ? lo : (v > hi ? hi : v); }

// ---------------------------------------------------------------- convert fp32 -> bf16
struct CvtArgs {
  const float* src[13];
  u16* dst[13];
  int n4[13];
};

__global__ __launch_bounds__(256) void k_convert(CvtArgs a){
  int stride = gridDim.x * 256;
  int tid = blockIdx.x * 256 + threadIdx.x;
  for (int s = 0; s < 13; ++s){
    const float4* src = (const float4*)a.src[s];
    us4* dst = (us4*)a.dst[s];
    int n = a.n4[s];
    for (int i = tid; i < n; i += stride){
      float4 v = src[i];
      us4 o;
      o.x = f2b(v.x); o.y = f2b(v.y); o.z = f2b(v.z); o.w = f2b(v.w);
      dst[i] = o;
    }
  }
}

// ---------------------------------------------------------------- generic 16-row MFMA strip GEMM
template<int N, int K>
__device__ __forceinline__ void gemm_strip(const u16* __restrict__ A, const u16* __restrict__ W, float* L){
  constexpr int CPW = N / 4;       // cols per wave
  constexpr int T = CPW / 16;      // 16x16 tiles per wave
  const int lane = threadIdx.x & 63;
  const int wave = threadIdx.x >> 6;
  const int rr = lane & 15, grp = lane >> 4;
  f4 acc[T];
#pragma unroll
  for (int t = 0; t < T; ++t) acc[t] = f4zero();
#pragma unroll
  for (int kc = 0; kc < K / 32; ++kc){
    bf8 af = *(const bf8*)(A + rr * K + kc * 32 + grp * 8);
#pragma unroll
    for (int t = 0; t < T; ++t){
      const u16* wp = W + (size_t)(wave * CPW + t * 16 + rr) * K + kc * 32 + grp * 8;
      acc[t] = mfma16(af, *(const bf8*)wp, acc[t]);
    }
  }
#pragma unroll
  for (int t = 0; t < T; ++t)
#pragma unroll
    for (int r = 0; r < 4; ++r)
      L[(grp * 4 + r) * N + wave * CPW + t * 16 + rr] = acc[t][r];
}

template<int N, int K>
__global__ __launch_bounds__(256) void k_gemm_f32(const u16* __restrict__ A, const u16* __restrict__ W,
                                                  float* __restrict__ out){
  __shared__ float L[16 * N];
  const int strip = blockIdx.x;
  gemm_strip<N, K>(A + (size_t)strip * 16 * K, W, L);
  __syncthreads();
  const size_t base = (size_t)strip * 16 * N;
  for (int i = threadIdx.x; i < 16 * N; i += 256) out[base + i] = L[i];
}

__global__ __launch_bounds__(256) void k_gemm_x(const u16* __restrict__ A, const u16* __restrict__ W,
                                                const float* __restrict__ lnA, u16* __restrict__ xout){
  __shared__ float L[16 * 256];
  const int strip = blockIdx.x;
  gemm_strip<256, 128>(A + (size_t)strip * 2048, W, L);
  __syncthreads();
  for (int i = threadIdx.x; i < 16 * 128; i += 256){
    int r = i >> 7, c = i & 127;
    float g1 = L[r * 256 + c], g2 = L[r * 256 + 128 + c];
    float s = 1.f / (1.f + __expf(-g1));
    size_t idx = (size_t)(strip * 16 + r) * 128 + c;
    xout[idx] = f2b(s * lnA[idx] + g2);
  }
}

__global__ __launch_bounds__(256) void k_gemm_qkv(const u16* __restrict__ A, const u16* __restrict__ W,
                                                  const float* __restrict__ qb, u16* __restrict__ out){
  __shared__ float L[16 * 384];
  const int strip = blockIdx.x;
  gemm_strip<384, 128>(A + (size_t)strip * 2048, W, L);
  __syncthreads();
  const float scale = 0.17677669529663687f; // 1/sqrt(32)
  for (int i = threadIdx.x; i < 16 * 384; i += 256){
    int r = i / 384, c = i - r * 384;
    float v = L[i];
    if (c < 128) v = (v + qb[c]) * scale;
    out[(size_t)(strip * 16 + r) * 384 + c] = f2b(v);
  }
}

__global__ __launch_bounds__(256) void k_gemm_gate(const u16* __restrict__ A, const u16* __restrict__ W,
                                                   const float* __restrict__ gb, float* __restrict__ gate){
  __shared__ float L[16 * 128];
  const int strip = blockIdx.x;
  gemm_strip<128, 128>(A + (size_t)strip * 2048, W, L);
  __syncthreads();
  for (int i = threadIdx.x; i < 2048; i += 256){
    int c = i & 127;
    gate[(size_t)strip * 2048 + i] = 1.f / (1.f + __expf(-(L[i] + gb[c])));
  }
}

__global__ __launch_bounds__(256) void k_gemm_relu(const u16* __restrict__ A, const u16* __restrict__ W,
                                                   float* __restrict__ out){
  __shared__ float L[16 * 384];
  const int strip = blockIdx.x;
  gemm_strip<384, 128>(A + (size_t)strip * 2048, W, L);
  __syncthreads();
  const size_t base = (size_t)strip * 16 * 384;
  for (int i = threadIdx.x; i < 16 * 384; i += 256) out[base + i] = fmaxf(L[i], 0.f);
}

__global__ __launch_bounds__(256) void k_gemm_glu(const u16* __restrict__ A, const u16* __restrict__ W,
                                                  u16* __restrict__ g){
  __shared__ float L[16 * 512];
  const int strip = blockIdx.x;
  gemm_strip<512, 128>(A + (size_t)strip * 2048, W, L);
  __syncthreads();
  for (int i = threadIdx.x; i < 16 * 256; i += 256){
    int r = i >> 8, c = i & 255;
    float ab1 = L[r * 512 + c], ab2 = L[r * 512 + 256 + c];
    float silu = ab1 / (1.f + __expf(-ab1));
    g[(size_t)(strip * 16 + r) * 256 + c] = f2b(silu * ab2);
  }
}

__global__ __launch_bounds__(256) void k_gemm_tb(const u16* __restrict__ A, const u16* __restrict__ W,
                                                 const float* __restrict__ gate, float* __restrict__ a,
                                                 u16* __restrict__ a_bf, float* __restrict__ lnA){
  __shared__ float L[16 * 128];
  const int strip = blockIdx.x;
  gemm_strip<128, 256>(A + (size_t)strip * 16 * 256, W, L);
  __syncthreads();
  for (int i = threadIdx.x; i < 2048; i += 256){
    size_t idx = (size_t)strip * 2048 + i;
    float v = a[idx] + gate[idx] * L[i];
    a[idx] = v;
    a_bf[idx] = f2b(v);
    L[i] = v;
  }
  __syncthreads();
  int r = threadIdx.x >> 4, s = threadIdx.x & 15;
  float sum = 0.f, sq = 0.f;
#pragma unroll
  for (int j = 0; j < 8; ++j){ float v = L[r * 128 + s * 8 + j]; sum += v; sq += v * v; }
#pragma unroll
  for (int m = 1; m < 16; m <<= 1){ sum += __shfl_xor(sum, m); sq += __shfl_xor(sq, m); }
  float mu = sum * (1.f / 128.f);
  float var = sq * (1.f / 128.f) - mu * mu;
  float rs = rsqrtf(var + 1e-5f);
#pragma unroll
  for (int j = 0; j < 8; ++j){
    int c = s * 8 + j;
    lnA[(size_t)(strip * 16 + r) * 128 + c] = (L[r * 128 + c] - mu) * rs;
  }
}

// ---------------------------------------------------------------- LN(c) + relu -> ph/pw projections
__global__ __launch_bounds__(256) void k_ln_phpw(const float* __restrict__ c, float* __restrict__ lnA,
                                                 u16* __restrict__ slnb, const float* __restrict__ Wph,
                                                 const float* __restrict__ Wpw, float* __restrict__ ph,
                                                 float* __restrict__ pw){
  __shared__ float rs[4][128];
  const int wave = threadIdx.x >> 6, lane = threadIdx.x & 63;
  const int row = blockIdx.x * 4 + wave;
  const float* cr = c + (size_t)row * 128;
  float2 v = *(const float2*)(cr + lane * 2);
  float sum = v.x + v.y, sq = v.x * v.x + v.y * v.y;
#pragma unroll
  for (int m = 1; m < 64; m <<= 1){ sum += __shfl_xor(sum, m); sq += __shfl_xor(sq, m); }
  float mu = sum * (1.f / 128.f);
  float var = sq * (1.f / 128.f) - mu * mu;
  float r = rsqrtf(var + 1e-5f);
  float s0 = (v.x - mu) * r, s1 = (v.y - mu) * r;
  size_t base = (size_t)row * 128 + lane * 2;
  lnA[base] = s0; lnA[base + 1] = s1;
  slnb[base] = f2b(s0); slnb[base + 1] = f2b(s1);
  rs[wave][lane * 2] = fmaxf(s0, 0.f); rs[wave][lane * 2 + 1] = fmaxf(s1, 0.f);
  __syncthreads();
  int h = lane & 15, part = lane >> 4;
  float acch = 0.f, accw = 0.f;
#pragma unroll
  for (int k = 0; k < 32; ++k){
    int kk = part * 32 + k;
    float rv = rs[wave][kk];
    acch += rv * Wph[h * 128 + kk];
    accw += rv * Wpw[h * 128 + kk];
  }
  acch += __shfl_xor(acch, 16); acch += __shfl_xor(acch, 32);
  accw += __shfl_xor(accw, 16); accw += __shfl_xor(accw, 32);
  if (lane < 16){
    ph[(size_t)row * 16 + h] = acch;
    pw[(size_t)row * 16 + h] = accw;
  }
}

// ---------------------------------------------------------------- pair-bias MLP v3: MFMA, weights in registers
// grid NBLK*8, 4 waves/block; wave handles one q (q = (blk&7)*4 + wave), 8 k-tiles of 16.
// MLP matmuls via mfma 16x16x32 with K padded 16->32 (zeros on both A and B: permutation-safe).
// LN affine folded into pb projection (w2 = pb_w*ln_w, bb = pb_w@ln_b).
__global__ __launch_bounds__(256) void k_pb(const float* __restrict__ ph, const float* __restrict__ pw,
                                            const float* __restrict__ W1, const float* __restrict__ W2,
                                            const float* __restrict__ lnw, const float* __restrict__ lnb,
                                            const float* __restrict__ pbw, float* __restrict__ bias){
  __shared__ __align__(16) u16 mt[4][16 * 24];  // per-wave m tile, row stride 24 u16 (48B, keeps b128 aligned)
  const int t = threadIdx.x;
  const int lane = t & 63, wave = t >> 6;
  const int rr = lane & 15, grp = lane >> 4;
  const int b = blockIdx.x >> 3, qg = blockIdx.x & 7;
  const int q = qg * 4 + wave;
  const int qa = b * 32 + q;

  // W1/W2 B-fragments in registers (lane rr = output row of W; k = grp*8+j, zero for k>=16)
  bf8 wf1 = {0,0,0,0,0,0,0,0}, wf2 = {0,0,0,0,0,0,0,0};
  if (grp < 2){
#pragma unroll
    for (int j = 0; j < 8; ++j){
      wf1[j] = (short)f2b(W1[rr * 16 + grp * 8 + j]);
      wf2[j] = (short)f2b(W2[rr * 16 + grp * 8 + j]);
    }
  }
  // folded LN->projection coefficients
  const float lnw_r = lnw[rr], lnb_r = lnb[rr];
  float sw2v[4], w2s[4], bbv[4];
#pragma unroll
  for (int h = 0; h < 4; ++h){
    float pv = pbw[h * 16 + rr];
    sw2v[h] = pv * lnw_r;
    float s = sw2v[h], b2 = pv * lnb_r;
#pragma unroll
    for (int m = 1; m < 16; m <<= 1){ s += __shfl_xor(s, m); b2 += __shfl_xor(b2, m); }
    w2s[h] = s; bbv[h] = b2;
  }
  // ph row for this q
  const float* phq = ph + (size_t)qa * 16;
  float pha[8];
  if (grp < 2){
#pragma unroll
    for (int j = 0; j < 8; ++j) pha[j] = phq[grp * 8 + j];
  }
  const float ph_r = phq[rr];
  u16* mw = &mt[wave][0];

  for (int kt = 0; kt < 8; ++kt){
    const int k0 = kt * 16;
    // A fragment: rows = k-pairs (k0+rr), elems = relu(ph[q]+pw[k]) bf16; zero k>=16
    bf8 af = {0,0,0,0,0,0,0,0};
    if (grp < 2){
      int win = b * 32 + k0 + rr - 48;
      int ka = iclamp(win, 0, NATOMS - 1);
      const float* pwr = pw + (size_t)ka * 16 + grp * 8;
#pragma unroll
      for (int j = 0; j < 8; ++j) af[j] = (short)f2b(fmaxf(pha[j] + pwr[j], 0.f));
    }
    f4 c1 = mfma16(af, wf1, f4zero());
    // m = relu(c1) -> LDS bf16 tile [pair][ch] (lane holds ch=rr for pairs grp*4+r)
#pragma unroll
    for (int r = 0; r < 4; ++r)
      mw[(grp * 4 + r) * 24 + rr] = f2b(fmaxf(c1[r], 0.f));
    __syncthreads();
    // second A fragment from LDS (transpose round-trip)
    bf8 mf = {0,0,0,0,0,0,0,0};
    if (grp < 2) mf = *(const bf8*)(mw + rr * 24 + grp * 8);
    f4 c2 = mfma16(mf, wf2, f4zero());
    __syncthreads();
    // residual + folded LN + 4-head projection via 16-lane reductions
    f4 pbA, pbB, pbC, pbD;
#pragma unroll
    for (int r = 0; r < 4; ++r){
      int win = b * 32 + k0 + grp * 4 + r - 48;
      bool valid = (win >= 0) && (win < NATOMS);
      int ka = iclamp(win, 0, NATOMS - 1);
      float v = c2[r] + ph_r + pw[(size_t)ka * 16 + rr];
      float s = v, ssq = v * v;
      float d0 = v * sw2v[0], d1 = v * sw2v[1];
      float d2 = v * sw2v[2], d3 = v * sw2v[3];
#pragma unroll
      for (int m = 1; m < 16; m <<= 1){
        s  += __shfl_xor(s, m);  ssq += __shfl_xor(ssq, m);
        d0 += __shfl_xor(d0, m); d1  += __shfl_xor(d1, m);
        d2 += __shfl_xor(d2, m); d3  += __shfl_xor(d3, m);
      }
      float mu = s * (1.f / 16.f);
      float var = ssq * (1.f / 16.f) - mu * mu;
      float rq = rsqrtf(var + 1e-5f);
      float nv = valid ? 0.f : -1e9f;
      pbA[r] = rq * (d0 - mu * w2s[0]) + bbv[0] + nv;
      pbB[r] = rq * (d1 - mu * w2s[1]) + bbv[1] + nv;
      pbC[r] = rq * (d2 - mu * w2s[2]) + bbv[2] + nv;
      pbD[r] = rq * (d3 - mu * w2s[3]) + bbv[3] + nv;
    }
    // write: lane rr<4 owns head h=rr; float4 = 4 consecutive k (grp*4+r)
    f4 o = pbA;
    o = (rr == 1) ? pbB : o;
    o = (rr == 2) ? pbC : o;
    o = (rr == 3) ? pbD : o;
    if (rr < 4){
      float4 ov = {o[0], o[1], o[2], o[3]};
      *(float4*)(bias + ((size_t)((b * 4 + rr) * 32) + q) * 128 + k0 + grp * 4) = ov;
    }
  }
}

// ---------------------------------------------------------------- block attention + out-proj + residual + row-LN
__global__ __launch_bounds__(256) void k_attn(const u16* __restrict__ qkv, const float* __restrict__ bias,
                                              const u16* __restrict__ outw, const float* __restrict__ outb,
                                              float* __restrict__ a, float* __restrict__ lnA){
  __shared__ u16 VT[128][136];
  __shared__ u16 P[4][32 * 136];
  __shared__ u16 O[32][136];
  __shared__ float aL[32][128];
  const int t = threadIdx.x;
  const int lane = t & 63, wave = t >> 6;
  const int b = blockIdx.x;
  const int rr = lane & 15, grp = lane >> 4;

  for (int i = 0; i < 8; ++i){
    int s = t + 256 * i;
    int ka = s & 127, d0 = (s >> 7) * 8;
    int win = b * 32 + ka - 48;
    int src = iclamp(win, 0, NATOMS - 1);
    bf8 v = *(const bf8*)(qkv + (size_t)src * 384 + 256 + d0);
#pragma unroll
    for (int j = 0; j < 8; ++j) VT[d0 + j][ka] = (u16)v[j];
  }
  __syncthreads();

  const int h = wave;
  bf8 kfr[8];
#pragma unroll
  for (int kt = 0; kt < 8; ++kt){
    int ka = kt * 16 + rr;
    int win = b * 32 + ka - 48;
    int src = iclamp(win, 0, NATOMS - 1);
    kfr[kt] = *(const bf8*)(qkv + (size_t)src * 384 + 128 + h * 32 + grp * 8);
  }
  f4 S[2][8];
#pragma unroll
  for (int qt = 0; qt < 2; ++qt){
    bf8 qf = *(const bf8*)(qkv + (size_t)(b * 32 + qt * 16 + rr) * 384 + h * 32 + grp * 8);
#pragma unroll
    for (int kt = 0; kt < 8; ++kt){
      S[qt][kt] = f4zero();
      S[qt][kt] = mfma16(qf, kfr[kt], S[qt][kt]);
    }
  }
  const float* brow = bias + (size_t)((b * 4 + h) * 32) * 128;
#pragma unroll
  for (int qt = 0; qt < 2; ++qt){
#pragma unroll
    for (int r = 0; r < 4; ++r){
      int q = qt * 16 + grp * 4 + r;
      float vals[8];
      float mx = -1e30f;
#pragma unroll
      for (int kt = 0; kt < 8; ++kt){
        float v = S[qt][kt][r] + brow[q * 128 + kt * 16 + rr];
        vals[kt] = v;
        mx = fmaxf(mx, v);
      }
#pragma unroll
      for (int m = 1; m < 16; m <<= 1) mx = fmaxf(mx, __shfl_xor(mx, m));
      float sum = 0.f;
#pragma unroll
      for (int kt = 0; kt < 8; ++kt){ vals[kt] = __expf(vals[kt] - mx); sum += vals[kt]; }
#pragma unroll
      for (int m = 1; m < 16; m <<= 1) sum += __shfl_xor(sum, m);
      float inv = 1.f / sum;
#pragma unroll
      for (int kt = 0; kt < 8; ++kt)
        P[h][q * 136 + kt * 16 + rr] = f2b(vals[kt] * inv);
    }
  }
  __syncthreads();
  f4 oacc[2][2];
#pragma unroll
  for (int qt = 0; qt < 2; ++qt)
#pragma unroll
    for (int dt = 0; dt < 2; ++dt) oacc[qt][dt] = f4zero();
#pragma unroll
  for (int kc = 0; kc < 4; ++kc){
#pragma unroll
    for (int qt = 0; qt < 2; ++qt){
      bf8 pa = *(const bf8*)(&P[h][(qt * 16 + rr) * 136 + kc * 32 + grp * 8]);
#pragma unroll
      for (int dt = 0; dt < 2; ++dt){
        bf8 vb = *(const bf8*)(&VT[h * 32 + dt * 16 + rr][kc * 32 + grp * 8]);
        oacc[qt][dt] = mfma16(pa, vb, oacc[qt][dt]);
      }
    }
  }
#pragma unroll
  for (int qt = 0; qt < 2; ++qt)
#pragma unroll
    for (int dt = 0; dt < 2; ++dt)
#pragma unroll
      for (int r = 0; r < 4; ++r)
        O[qt * 16 + grp * 4 + r][h * 32 + dt * 16 + rr] = f2b(oacc[qt][dt][r]);
  __syncthreads();
  f4 pacc[2][2];
#pragma unroll
  for (int qt = 0; qt < 2; ++qt)
#pragma unroll
    for (int ct = 0; ct < 2; ++ct) pacc[qt][ct] = f4zero();
#pragma unroll
  for (int kc = 0; kc < 4; ++kc){
    bf8 a0 = *(const bf8*)(&O[rr][kc * 32 + grp * 8]);
    bf8 a1 = *(const bf8*)(&O[16 + rr][kc * 32 + grp * 8]);
#pragma unroll
    for (int ct = 0; ct < 2; ++ct){
      bf8 wf = *(const bf8*)(outw + (size_t)(wave * 32 + ct * 16 + rr) * 128 + kc * 32 + grp * 8);
      pacc[0][ct] = mfma16(a0, wf, pacc[0][ct]);
      pacc[1][ct] = mfma16(a1, wf, pacc[1][ct]);
    }
  }
#pragma unroll
  for (int qt = 0; qt < 2; ++qt)
#pragma unroll
    for (int ct = 0; ct < 2; ++ct)
#pragma unroll
      for (int r = 0; r < 4; ++r){
        int q = qt * 16 + grp * 4 + r;
        int col = wave * 32 + ct * 16 + rr;
        size_t idx = (size_t)(b * 32 + q) * 128 + col;
        float v = a[idx] + pacc[qt][ct][r] + outb[col];
        a[idx] = v;
        aL[q][col] = v;
      }
  __syncthreads();
  {
    int r = t >> 3, s8 = t & 7;
    float sum = 0.f, sq = 0.f;
#pragma unroll
    for (int j = 0; j < 16; ++j){ float v = aL[r][s8 * 16 + j]; sum += v; sq += v * v; }
#pragma unroll
    for (int m = 1; m < 8; m <<= 1){ sum += __shfl_xor(sum, m); sq += __shfl_xor(sq, m); }
    float mu = sum * (1.f / 128.f);
    float var = sq * (1.f / 128.f) - mu * mu;
    float rs = rsqrtf(var + 1e-5f);
#pragma unroll
    for (int j = 0; j < 16; ++j){
      int c = s8 * 16 + j;
      lnA[(size_t)(b * 32 + r) * 128 + c] = (aL[r][c] - mu) * rs;
    }
  }
}

// ---------------------------------------------------------------- segment mean (atoms -> tokens)
__device__ __forceinline__ int lbound(const int* __restrict__ arr, int n, int v){
  int lo = 0, hi = n;
  while (lo < hi){ int mid = (lo + hi) >> 1; if (arr[mid] < v) lo = mid + 1; else hi = mid; }
  return lo;
}

__global__ __launch_bounds__(256) void k_segmean(const float* __restrict__ atom_out,
                                                 const int* __restrict__ a2t, u16* __restrict__ tokbf){
  const int tok = blockIdx.x;
  __shared__ int lo_s, hi_s;
  if (threadIdx.x == 0){
    lo_s = lbound(a2t, NATOMS, tok);
    hi_s = lbound(a2t, NATOMS, tok + 1);
  }
  __syncthreads();
  int lo = lo_s, hi = hi_s;
  float inv = 1.f / fmaxf((float)(hi - lo), 1.f);
  for (int c = threadIdx.x; c < 384; c += 256){
    float s = 0.f;
    for (int aa = lo; aa < hi; ++aa) s += atom_out[(size_t)aa * 384 + c];
    tokbf[(size_t)tok * 384 + c] = f2b(s * inv);
  }
}

// ---------------------------------------------------------------- pair head: tpf@Wp^T + u_i + u_j
__global__ __launch_bounds__(256) void k_pair(const float* __restrict__ tpf, const float* __restrict__ Wp,
                                              const float* __restrict__ u, float* __restrict__ out){
  __shared__ float stpf[32][32];
  const int blk = blockIdx.x;
  const int pair0 = blk * 32;
  const int t = threadIdx.x;
  for (int idx = t; idx < 1024; idx += 256){
    int pp = idx >> 5, k = idx & 31;
    int p = pair0 + pp;
    stpf[pp][k] = tpf[(size_t)p * 32 + k];
  }
  __syncthreads();
  const int c = t & 127;
  const int half = t >> 7;
  float w[32];
#pragma unroll
  for (int k = 0; k < 32; ++k) w[k] = Wp[c * 32 + k];
  const int i = pair0 >> 9;
  const float ui = u[(size_t)i * 256 + c];
  for (int pp = half * 16; pp < half * 16 + 16; ++pp){
    int p = pair0 + pp;
    int j = p & 511;
    float s = ui + u[(size_t)j * 256 + 128 + c];
#pragma unroll
    for (int k = 0; k < 32; ++k) s += stpf[pp][k] * w[k];
    out[(size_t)p * 128 + c] = s;
  }
}

// ================================================================ host
extern "C" void kernel_launch(void* const* d_in, const int* in_sizes, int n_in,
                              void* d_out, int out_size, void* d_ws, size_t ws_size,
                              hipStream_t stream){
  (void)in_sizes; (void)n_in; (void)out_size; (void)ws_size;
  const float* atom_feats = (const float*)d_in[0];
  const float* tpf        = (const float*)d_in[1];
  const float* W_cond     = (const float*)d_in[2];
  const float* W_ph       = (const float*)d_in[3];
  const float* W_pw       = (const float*)d_in[4];
  const float* W_mlp1     = (const float*)d_in[5];
  const float* W_mlp2     = (const float*)d_in[6];
  const float* pb_ln_w    = (const float*)d_in[7];
  const float* pb_ln_b    = (const float*)d_in[8];
  const float* pb_w       = (const float*)d_in[9];
  const float* sln_w      = (const float*)d_in[10];
  const float* qkv_w      = (const float*)d_in[11];
  const float* q_bias     = (const float*)d_in[12];
  const float* out_w      = (const float*)d_in[13];
  const float* out_b      = (const float*)d_in[14];
  const float* ada_w      = (const float*)d_in[15];
  const float* ta_w       = (const float*)d_in[16];
  const float* tb_w       = (const float*)d_in[17];
  const float* gate_w     = (const float*)d_in[18];
  const float* gate_b     = (const float*)d_in[19];
  const float* W_tok      = (const float*)d_in[20];
  const float* W_trunk    = (const float*)d_in[21];
  const float* W_struct   = (const float*)d_in[22];
  const float* W_pairin   = (const float*)d_in[23];
  const float* W_outer    = (const float*)d_in[24];
  const int*   a2t        = (const int*)d_in[28];

  char* wsb = (char*)d_ws;
  size_t off = 0;
  auto alc = [&](size_t bytes) -> void* {
    void* r = wsb + off;
    off = (off + bytes + 255) & ~(size_t)255;
    return r;
  };

  u16* af_bf     = (u16*)alc((size_t)NATOMS * 128 * 2);
  u16* wcond_bf  = (u16*)alc(16384 * 2);
  u16* sln_bfw   = (u16*)alc(98304 * 2);
  u16* qkv_bfw   = (u16*)alc(147456 * 2);
  u16* out_bfw   = (u16*)alc(49152 * 2);
  u16* ada_bfw   = (u16*)alc(98304 * 2);
  u16* ta_bfw    = (u16*)alc(196608 * 2);
  u16* tb_bfw    = (u16*)alc(98304 * 2);
  u16* gate_bfw  = (u16*)alc(49152 * 2);
  u16* tok_bfw   = (u16*)alc(49152 * 2);
  u16* trunk_bfw = (u16*)alc(147456 * 2);
  u16* struct_bfw= (u16*)alc(147456 * 2);
  u16* outer_bfw = (u16*)alc(98304 * 2);
  float* a_f     = (float*)alc((size_t)NATOMS * 128 * 4);
  float* lnA     = (float*)alc((size_t)NATOMS * 128 * 4);
  u16* sln_bf    = (u16*)alc((size_t)NATOMS * 128 * 2);
  u16* x_bf      = (u16*)alc((size_t)NATOMS * 128 * 2);
  u16* qkv_bf    = (u16*)alc((size_t)NATOMS * 384 * 2);
  u16* g_bf      = (u16*)alc((size_t)NATOMS * 256 * 2);
  float* gate_f  = (float*)alc((size_t)NATOMS * 128 * 4);
  u16* a_bf      = (u16*)alc((size_t)NATOMS * 128 * 2);
  float* ph      = (float*)alc((size_t)NATOMS * 16 * 4);
  float* pw      = (float*)alc((size_t)NATOMS * 16 * 4);
  float* bias    = (float*)alc((size_t)NBLK * 4 * 32 * 128 * 4);
  float* atom_out= bias; // alias: bias dead after layer-2 attention
  u16* tok_bf    = (u16*)alc(512 * 384 * 2);
  float* u_f     = (float*)alc(512 * 256 * 4);

  float* s_trunk  = (float*)d_out;
  float* s_struct = s_trunk + 512 * 384;
  float* pair_out = s_struct + 512 * 384;

  CvtArgs ca;
  const float* srcs[13] = {atom_feats, W_cond, sln_w, qkv_w, out_w, ada_w, ta_w, tb_w,
                           gate_w, W_tok, W_trunk, W_struct, W_outer};
  u16* dsts[13] = {af_bf, wcond_bf, sln_bfw, qkv_bfw, out_bfw, ada_bfw, ta_bfw, tb_bfw,
                   gate_bfw, tok_bfw, trunk_bfw, struct_bfw, outer_bfw};
  int n4s[13] = {NATOMS * 128 / 4, 4096, 24576, 36864, 12288, 24576, 49152, 24576,
                 12288, 12288, 36864, 36864, 24576};
  for (int s = 0; s < 13; ++s){ ca.src[s] = srcs[s]; ca.dst[s] = dsts[s]; ca.n4[s] = n4s[s]; }
  k_convert<<<512, 256, 0, stream>>>(ca);

  k_gemm_f32<128, 128><<<736, 256, 0, stream>>>(af_bf, wcond_bf, a_f);
  k_ln_phpw<<<2944, 256, 0, stream>>>(a_f, lnA, sln_bf, W_ph, W_pw, ph, pw);
  k_pb<<<NBLK * 8, 256, 0, stream>>>(ph, pw, W_mlp1, W_mlp2, pb_ln_w, pb_ln_b, pb_w, bias);

  for (int l = 0; l < 3; ++l){
    const u16* slnW  = sln_bfw  + (size_t)l * 256 * 128;
    const u16* qkvW  = qkv_bfw  + (size_t)l * 384 * 128;
    const u16* outW  = out_bfw  + (size_t)l * 128 * 128;
    const u16* adaW  = ada_bfw  + (size_t)l * 256 * 128;
    const u16* taW   = ta_bfw   + (size_t)l * 512 * 128;
    const u16* tbW   = tb_bfw   + (size_t)l * 128 * 256;
    const u16* gateW = gate_bfw + (size_t)l * 128 * 128;
    k_gemm_x<<<736, 256, 0, stream>>>(sln_bf, slnW, lnA, x_bf);
    k_gemm_qkv<<<736, 256, 0, stream>>>(x_bf, qkvW, q_bias + l * 128, qkv_bf);
    k_gemm_gate<<<736, 256, 0, stream>>>(sln_bf, gateW, gate_b + l * 128, gate_f);
    k_attn<<<NBLK, 256, 0, stream>>>(qkv_bf, bias, outW, out_b + l * 128, a_f, lnA);
    k_gemm_x<<<736, 256, 0, stream>>>(sln_bf, adaW, lnA, x_bf);
    k_gemm_glu<<<736, 256, 0, stream>>>(x_bf, taW, g_bf);
    k_gemm_tb<<<736, 256, 0, stream>>>(g_bf, tbW, gate_f, a_f, a_bf, lnA);
  }

  k_gemm_relu<<<736, 256, 0, stream>>>(a_bf, tok_bfw, atom_out);
  k_segmean<<<512, 256, 0, stream>>>(atom_out, a2t, tok_bf);
  k_gemm_f32<384, 384><<<32, 256, 0, stream>>>(tok_bf, trunk_bfw, s_trunk);
  k_gemm_f32<384, 384><<<32, 256, 0, stream>>>(tok_bf, struct_bfw, s_struct);
  k_gemm_f32<256, 384><<<32, 256, 0, stream>>>(tok_bf, outer_bfw, u_f);
  k_pair<<<8192, 256, 0, stream>>>(tpf, W_pairin, u_f, pair_out);
}

// Round 4
// 531.333 us; speedup vs baseline: 1.1720x; 1.1436x over previous
//
#include <hip/hip_runtime.h>
#include <cstddef>

typedef unsigned short u16;
typedef __attribute__((ext_vector_type(8))) short bf8;   // 8 x bf16 (4 VGPRs)
typedef __attribute__((ext_vector_type(4))) float f4;
typedef __attribute__((ext_vector_type(4))) unsigned short us4;

#define NATOMS 11776
#define NBLK   368

__device__ __forceinline__ u16 f2b(float x){
  union { float f; unsigned u; } v; v.f = x;
  unsigned r = v.u + 0x7fffu + ((v.u >> 16) & 1u);
  return (u16)(r >> 16);
}
__device__ __forceinline__ float b2f(u16 x){
  union { unsigned u; float f; } v; v.u = ((unsigned)x) << 16;
  return v.f;
}
__device__ __forceinline__ f4 f4zero(){ f4 z = {0.f,0.f,0.f,0.f}; return z; }
__device__ __forceinline__ f4 mfma16(bf8 a, bf8 b, f4 c){
  return __builtin_amdgcn_mfma_f32_16x16x32_bf16(a, b, c, 0, 0, 0);
}
__device__ __forceinline__ int iclamp(int v, int lo, int hi){ return v < lo ? lo : (v > hi ? hi : v); }
__device__ __forceinline__ void lds_fence(){
  asm volatile("s_waitcnt lgkmcnt(0)" ::: "memory");
  __builtin_amdgcn_sched_barrier(0);
}

// ---------------------------------------------------------------- convert fp32 -> bf16
struct CvtArgs {
  const float* src[13];
  u16* dst[13];
  int n4[13];
};

__global__ __launch_bounds__(256) void k_convert(CvtArgs a){
  int stride = gridDim.x * 256;
  int tid = blockIdx.x * 256 + threadIdx.x;
  for (int s = 0; s < 13; ++s){
    const float4* src = (const float4*)a.src[s];
    us4* dst = (us4*)a.dst[s];
    int n = a.n4[s];
    for (int i = tid; i < n; i += stride){
      float4 v = src[i];
      us4 o;
      o.x = f2b(v.x); o.y = f2b(v.y); o.z = f2b(v.z); o.w = f2b(v.w);
      dst[i] = o;
    }
  }
}

// ---------------------------------------------------------------- generic 16-row MFMA strip GEMM
template<int N, int K>
__device__ __forceinline__ void gemm_strip(const u16* __restrict__ A, const u16* __restrict__ W, float* L){
  constexpr int CPW = N / 4;       // cols per wave
  constexpr int T = CPW / 16;      // 16x16 tiles per wave
  const int lane = threadIdx.x & 63;
  const int wave = threadIdx.x >> 6;
  const int rr = lane & 15, grp = lane >> 4;
  f4 acc[T];
#pragma unroll
  for (int t = 0; t < T; ++t) acc[t] = f4zero();
#pragma unroll
  for (int kc = 0; kc < K / 32; ++kc){
    bf8 af = *(const bf8*)(A + rr * K + kc * 32 + grp * 8);
#pragma unroll
    for (int t = 0; t < T; ++t){
      const u16* wp = W + (size_t)(wave * CPW + t * 16 + rr) * K + kc * 32 + grp * 8;
      acc[t] = mfma16(af, *(const bf8*)wp, acc[t]);
    }
  }
#pragma unroll
  for (int t = 0; t < T; ++t)
#pragma unroll
    for (int r = 0; r < 4; ++r)
      L[(grp * 4 + r) * N + wave * CPW + t * 16 + rr] = acc[t][r];
}

template<int N, int K>
__global__ __launch_bounds__(256) void k_gemm_f32(const u16* __restrict__ A, const u16* __restrict__ W,
                                                  float* __restrict__ out){
  __shared__ float L[16 * N];
  const int strip = blockIdx.x;
  gemm_strip<N, K>(A + (size_t)strip * 16 * K, W, L);
  __syncthreads();
  const size_t base = (size_t)strip * 16 * N;
  for (int i = threadIdx.x; i < 16 * N; i += 256) out[base + i] = L[i];
}

__global__ __launch_bounds__(256) void k_gemm_x(const u16* __restrict__ A, const u16* __restrict__ W,
                                                const float* __restrict__ lnA, u16* __restrict__ xout){
  __shared__ float L[16 * 256];
  const int strip = blockIdx.x;
  gemm_strip<256, 128>(A + (size_t)strip * 2048, W, L);
  __syncthreads();
  for (int i = threadIdx.x; i < 16 * 128; i += 256){
    int r = i >> 7, c = i & 127;
    float g1 = L[r * 256 + c], g2 = L[r * 256 + 128 + c];
    float s = 1.f / (1.f + __expf(-g1));
    size_t idx = (size_t)(strip * 16 + r) * 128 + c;
    xout[idx] = f2b(s * lnA[idx] + g2);
  }
}

__global__ __launch_bounds__(256) void k_gemm_qkv(const u16* __restrict__ A, const u16* __restrict__ W,
                                                  const float* __restrict__ qb, u16* __restrict__ out){
  __shared__ float L[16 * 384];
  const int strip = blockIdx.x;
  gemm_strip<384, 128>(A + (size_t)strip * 2048, W, L);
  __syncthreads();
  const float scale = 0.17677669529663687f; // 1/sqrt(32)
  for (int i = threadIdx.x; i < 16 * 384; i += 256){
    int r = i / 384, c = i - r * 384;
    float v = L[i];
    if (c < 128) v = (v + qb[c]) * scale;
    out[(size_t)(strip * 16 + r) * 384 + c] = f2b(v);
  }
}

__global__ __launch_bounds__(256) void k_gemm_gate(const u16* __restrict__ A, const u16* __restrict__ W,
                                                   const float* __restrict__ gb, float* __restrict__ gate){
  __shared__ float L[16 * 128];
  const int strip = blockIdx.x;
  gemm_strip<128, 128>(A + (size_t)strip * 2048, W, L);
  __syncthreads();
  for (int i = threadIdx.x; i < 2048; i += 256){
    int c = i & 127;
    gate[(size_t)strip * 2048 + i] = 1.f / (1.f + __expf(-(L[i] + gb[c])));
  }
}

__global__ __launch_bounds__(256) void k_gemm_relu(const u16* __restrict__ A, const u16* __restrict__ W,
                                                   float* __restrict__ out){
  __shared__ float L[16 * 384];
  const int strip = blockIdx.x;
  gemm_strip<384, 128>(A + (size_t)strip * 2048, W, L);
  __syncthreads();
  const size_t base = (size_t)strip * 16 * 384;
  for (int i = threadIdx.x; i < 16 * 384; i += 256) out[base + i] = fmaxf(L[i], 0.f);
}

__global__ __launch_bounds__(256) void k_gemm_glu(const u16* __restrict__ A, const u16* __restrict__ W,
                                                  u16* __restrict__ g){
  __shared__ float L[16 * 512];
  const int strip = blockIdx.x;
  gemm_strip<512, 128>(A + (size_t)strip * 2048, W, L);
  __syncthreads();
  for (int i = threadIdx.x; i < 16 * 256; i += 256){
    int r = i >> 8, c = i & 255;
    float ab1 = L[r * 512 + c], ab2 = L[r * 512 + 256 + c];
    float silu = ab1 / (1.f + __expf(-ab1));
    g[(size_t)(strip * 16 + r) * 256 + c] = f2b(silu * ab2);
  }
}

__global__ __launch_bounds__(256) void k_gemm_tb(const u16* __restrict__ A, const u16* __restrict__ W,
                                                 const float* __restrict__ gate, float* __restrict__ a,
                                                 u16* __restrict__ a_bf, float* __restrict__ lnA){
  __shared__ float L[16 * 128];
  const int strip = blockIdx.x;
  gemm_strip<128, 256>(A + (size_t)strip * 16 * 256, W, L);
  __syncthreads();
  for (int i = threadIdx.x; i < 2048; i += 256){
    size_t idx = (size_t)strip * 2048 + i;
    float v = a[idx] + gate[idx] * L[i];
    a[idx] = v;
    a_bf[idx] = f2b(v);
    L[i] = v;
  }
  __syncthreads();
  int r = threadIdx.x >> 4, s = threadIdx.x & 15;
  float sum = 0.f, sq = 0.f;
#pragma unroll
  for (int j = 0; j < 8; ++j){ float v = L[r * 128 + s * 8 + j]; sum += v; sq += v * v; }
#pragma unroll
  for (int m = 1; m < 16; m <<= 1){ sum += __shfl_xor(sum, m); sq += __shfl_xor(sq, m); }
  float mu = sum * (1.f / 128.f);
  float var = sq * (1.f / 128.f) - mu * mu;
  float rs = rsqrtf(var + 1e-5f);
#pragma unroll
  for (int j = 0; j < 8; ++j){
    int c = s * 8 + j;
    lnA[(size_t)(strip * 16 + r) * 128 + c] = (L[r * 128 + c] - mu) * rs;
  }
}

// ---------------------------------------------------------------- LN(c) + relu -> ph/pw projections
__global__ __launch_bounds__(256) void k_ln_phpw(const float* __restrict__ c, float* __restrict__ lnA,
                                                 u16* __restrict__ slnb, const float* __restrict__ Wph,
                                                 const float* __restrict__ Wpw, float* __restrict__ ph,
                                                 float* __restrict__ pw){
  __shared__ float rs[4][128];
  const int wave = threadIdx.x >> 6, lane = threadIdx.x & 63;
  const int row = blockIdx.x * 4 + wave;
  const float* cr = c + (size_t)row * 128;
  float2 v = *(const float2*)(cr + lane * 2);
  float sum = v.x + v.y, sq = v.x * v.x + v.y * v.y;
#pragma unroll
  for (int m = 1; m < 64; m <<= 1){ sum += __shfl_xor(sum, m); sq += __shfl_xor(sq, m); }
  float mu = sum * (1.f / 128.f);
  float var = sq * (1.f / 128.f) - mu * mu;
  float r = rsqrtf(var + 1e-5f);
  float s0 = (v.x - mu) * r, s1 = (v.y - mu) * r;
  size_t base = (size_t)row * 128 + lane * 2;
  lnA[base] = s0; lnA[base + 1] = s1;
  slnb[base] = f2b(s0); slnb[base + 1] = f2b(s1);
  rs[wave][lane * 2] = fmaxf(s0, 0.f); rs[wave][lane * 2 + 1] = fmaxf(s1, 0.f);
  __syncthreads();
  int h = lane & 15, part = lane >> 4;
  float acch = 0.f, accw = 0.f;
#pragma unroll
  for (int k = 0; k < 32; ++k){
    int kk = part * 32 + k;
    float rv = rs[wave][kk];
    acch += rv * Wph[h * 128 + kk];
    accw += rv * Wpw[h * 128 + kk];
  }
  acch += __shfl_xor(acch, 16); acch += __shfl_xor(acch, 32);
  accw += __shfl_xor(accw, 16); accw += __shfl_xor(accw, 32);
  if (lane < 16){
    ph[(size_t)row * 16 + h] = acch;
    pw[(size_t)row * 16 + h] = accw;
  }
}

// ---------------------------------------------------------------- pair-bias MLP v4: all-MFMA, zero shuffles
// grid NBLK*8, 4 waves/block; wave handles one q (q=(blk&7)*4+wave), 8 k-tiles of 16.
// MLP matmuls: mfma 16x16x32, K padded 16->32 with zeros on BOTH operands.
// LN + 4-head projection ALSO via MFMA:
//   T1 = mfma(Vbf, Bproj) -> d_h = sum_cc v*sw2[h]   (cols 0..3)
//   T2 = mfma(Vbf, Bones) -> S = sum_cc v            (every col)
//   T3 = mfma(Vbf^2, Bones) -> Q = sum_cc v^2        (exact: bf16^2 fits fp32)
//   pb_h = rq*(d_h - mu*w2s_h) + bb_h,  mu=S/16, rq=rsqrt(Q/16-mu^2+1e-5)
// No __syncthreads (tiles are per-wave); in-wave LDS RAW fenced with lgkmcnt(0)+sched_barrier.
__global__ __launch_bounds__(256) void k_pb(const float* __restrict__ ph, const float* __restrict__ pw,
                                            const float* __restrict__ W1, const float* __restrict__ W2,
                                            const float* __restrict__ lnw, const float* __restrict__ lnb,
                                            const float* __restrict__ pbw, float* __restrict__ bias){
  __shared__ __align__(16) u16 mt[4][16 * 24];  // per-wave m tile (row stride 48B)
  __shared__ __align__(16) u16 vt[4][16 * 24];  // per-wave pfin tile
  const int t = threadIdx.x;
  const int lane = t & 63, wave = t >> 6;
  const int rr = lane & 15, grp = lane >> 4;
  const int b = blockIdx.x >> 3, qg = blockIdx.x & 7;
  const int q = qg * 4 + wave;
  const int qa = b * 32 + q;

  // B-fragments in registers (col = rr, k = grp*8+j; zero for k>=16)
  bf8 wf1 = {0,0,0,0,0,0,0,0}, wf2 = {0,0,0,0,0,0,0,0};
  bf8 bproj = {0,0,0,0,0,0,0,0}, bones = {0,0,0,0,0,0,0,0};
  if (grp < 2){
#pragma unroll
    for (int j = 0; j < 8; ++j){
      wf1[j] = (short)f2b(W1[rr * 16 + grp * 8 + j]);
      wf2[j] = (short)f2b(W2[rr * 16 + grp * 8 + j]);
      bones[j] = (short)0x3F80;  // bf16 1.0
    }
    if (rr < 4){
#pragma unroll
      for (int j = 0; j < 8; ++j)
        bproj[j] = (short)f2b(pbw[rr * 16 + grp * 8 + j] * lnw[grp * 8 + j]);
    }
  }
  // per-head folded constants (only lanes rr<4 use them)
  float w2s_r = 0.f, bb_r = 0.f;
  if (rr < 4){
#pragma unroll
    for (int cc = 0; cc < 16; ++cc){
      float pv = pbw[rr * 16 + cc];
      w2s_r += pv * lnw[cc];
      bb_r  += pv * lnb[cc];
    }
  }
  // ph row for this q
  const float* phq = ph + (size_t)qa * 16;
  float pha[8];
  if (grp < 2){
#pragma unroll
    for (int j = 0; j < 8; ++j) pha[j] = phq[grp * 8 + j];
  }
  const float ph_r = phq[rr];
  u16* mw = &mt[wave][0];
  u16* vw = &vt[wave][0];

  for (int kt = 0; kt < 8; ++kt){
    const int k0 = kt * 16;
    // A1 = relu(ph[q] + pw[k]) : row = k-pair (k0+rr), k-elem = channel
    bf8 af = {0,0,0,0,0,0,0,0};
    if (grp < 2){
      int winA = b * 32 + k0 + rr - 48;
      int kaA = iclamp(winA, 0, NATOMS - 1);
      const float* pwr = pw + (size_t)kaA * 16 + grp * 8;
#pragma unroll
      for (int j = 0; j < 8; ++j) af[j] = (short)f2b(fmaxf(pha[j] + pwr[j], 0.f));
    }
    f4 c1 = mfma16(af, wf1, f4zero());
    // m = relu(c1) -> per-wave LDS tile (D layout: pair=grp*4+r row, ch=rr col)
#pragma unroll
    for (int r = 0; r < 4; ++r)
      mw[(grp * 4 + r) * 24 + rr] = f2b(fmaxf(c1[r], 0.f));
    lds_fence();
    bf8 mf = {0,0,0,0,0,0,0,0};
    if (grp < 2) mf = *(const bf8*)(mw + rr * 24 + grp * 8);
    f4 c2 = mfma16(mf, wf2, f4zero());
    // pfin = c2 + p (residual), write bf16 tile
#pragma unroll
    for (int r = 0; r < 4; ++r){
      int win = b * 32 + k0 + grp * 4 + r - 48;
      int ka = iclamp(win, 0, NATOMS - 1);
      float v = c2[r] + ph_r + pw[(size_t)ka * 16 + rr];
      vw[(grp * 4 + r) * 24 + rr] = f2b(v);
    }
    lds_fence();
    bf8 vf = {0,0,0,0,0,0,0,0}, vf2 = {0,0,0,0,0,0,0,0};
    if (grp < 2){
      vf = *(const bf8*)(vw + rr * 24 + grp * 8);
#pragma unroll
      for (int j = 0; j < 8; ++j){
        float x = b2f((u16)vf[j]);
        union { float f; unsigned u; } s; s.f = x * x;
        vf2[j] = (short)(u16)(s.u >> 16);   // truncate: squares are non-negative
      }
    }
    f4 T1 = mfma16(vf, bproj, f4zero());
    f4 T2 = mfma16(vf, bones, f4zero());
    f4 T3 = mfma16(vf2, bones, f4zero());
    if (rr < 4){
      float4 o;
      float ov[4];
#pragma unroll
      for (int r = 0; r < 4; ++r){
        int win = b * 32 + k0 + grp * 4 + r - 48;
        bool valid = (win >= 0) && (win < NATOMS);
        float S = T2[r], Q = T3[r], d = T1[r];
        float mu = S * (1.f / 16.f);
        float var = Q * (1.f / 16.f) - mu * mu;
        float rq = rsqrtf(var + 1e-5f);
        ov[r] = rq * (d - mu * w2s_r) + bb_r + (valid ? 0.f : -1e9f);
      }
      o.x = ov[0]; o.y = ov[1]; o.z = ov[2]; o.w = ov[3];
      *(float4*)(bias + ((size_t)((b * 4 + rr) * 32) + q) * 128 + k0 + grp * 4) = o;
    }
  }
}

// ---------------------------------------------------------------- block attention + out-proj + residual + row-LN
__global__ __launch_bounds__(256) void k_attn(const u16* __restrict__ qkv, const float* __restrict__ bias,
                                              const u16* __restrict__ outw, const float* __restrict__ outb,
                                              float* __restrict__ a, float* __restrict__ lnA){
  __shared__ u16 VT[128][136];
  __shared__ u16 P[4][32 * 136];
  __shared__ u16 O[32][136];
  __shared__ float aL[32][128];
  const int t = threadIdx.x;
  const int lane = t & 63, wave = t >> 6;
  const int b = blockIdx.x;
  const int rr = lane & 15, grp = lane >> 4;

  for (int i = 0; i < 8; ++i){
    int s = t + 256 * i;
    int ka = s & 127, d0 = (s >> 7) * 8;
    int win = b * 32 + ka - 48;
    int src = iclamp(win, 0, NATOMS - 1);
    bf8 v = *(const bf8*)(qkv + (size_t)src * 384 + 256 + d0);
#pragma unroll
    for (int j = 0; j < 8; ++j) VT[d0 + j][ka] = (u16)v[j];
  }
  __syncthreads();

  const int h = wave;
  bf8 kfr[8];
#pragma unroll
  for (int kt = 0; kt < 8; ++kt){
    int ka = kt * 16 + rr;
    int win = b * 32 + ka - 48;
    int src = iclamp(win, 0, NATOMS - 1);
    kfr[kt] = *(const bf8*)(qkv + (size_t)src * 384 + 128 + h * 32 + grp * 8);
  }
  f4 S[2][8];
#pragma unroll
  for (int qt = 0; qt < 2; ++qt){
    bf8 qf = *(const bf8*)(qkv + (size_t)(b * 32 + qt * 16 + rr) * 384 + h * 32 + grp * 8);
#pragma unroll
    for (int kt = 0; kt < 8; ++kt){
      S[qt][kt] = f4zero();
      S[qt][kt] = mfma16(qf, kfr[kt], S[qt][kt]);
    }
  }
  const float* brow = bias + (size_t)((b * 4 + h) * 32) * 128;
#pragma unroll
  for (int qt = 0; qt < 2; ++qt){
#pragma unroll
    for (int r = 0; r < 4; ++r){
      int q = qt * 16 + grp * 4 + r;
      float vals[8];
      float mx = -1e30f;
#pragma unroll
      for (int kt = 0; kt < 8; ++kt){
        float v = S[qt][kt][r] + brow[q * 128 + kt * 16 + rr];
        vals[kt] = v;
        mx = fmaxf(mx, v);
      }
#pragma unroll
      for (int m = 1; m < 16; m <<= 1) mx = fmaxf(mx, __shfl_xor(mx, m));
      float sum = 0.f;
#pragma unroll
      for (int kt = 0; kt < 8; ++kt){ vals[kt] = __expf(vals[kt] - mx); sum += vals[kt]; }
#pragma unroll
      for (int m = 1; m < 16; m <<= 1) sum += __shfl_xor(sum, m);
      float inv = 1.f / sum;
#pragma unroll
      for (int kt = 0; kt < 8; ++kt)
        P[h][q * 136 + kt * 16 + rr] = f2b(vals[kt] * inv);
    }
  }
  __syncthreads();
  f4 oacc[2][2];
#pragma unroll
  for (int qt = 0; qt < 2; ++qt)
#pragma unroll
    for (int dt = 0; dt < 2; ++dt) oacc[qt][dt] = f4zero();
#pragma unroll
  for (int kc = 0; kc < 4; ++kc){
#pragma unroll
    for (int qt = 0; qt < 2; ++qt){
      bf8 pa = *(const bf8*)(&P[h][(qt * 16 + rr) * 136 + kc * 32 + grp * 8]);
#pragma unroll
      for (int dt = 0; dt < 2; ++dt){
        bf8 vb = *(const bf8*)(&VT[h * 32 + dt * 16 + rr][kc * 32 + grp * 8]);
        oacc[qt][dt] = mfma16(pa, vb, oacc[qt][dt]);
      }
    }
  }
#pragma unroll
  for (int qt = 0; qt < 2; ++qt)
#pragma unroll
    for (int dt = 0; dt < 2; ++dt)
#pragma unroll
      for (int r = 0; r < 4; ++r)
        O[qt * 16 + grp * 4 + r][h * 32 + dt * 16 + rr] = f2b(oacc[qt][dt][r]);
  __syncthreads();
  f4 pacc[2][2];
#pragma unroll
  for (int qt = 0; qt < 2; ++qt)
#pragma unroll
    for (int ct = 0; ct < 2; ++ct) pacc[qt][ct] = f4zero();
#pragma unroll
  for (int kc = 0; kc < 4; ++kc){
    bf8 a0 = *(const bf8*)(&O[rr][kc * 32 + grp * 8]);
    bf8 a1 = *(const bf8*)(&O[16 + rr][kc * 32 + grp * 8]);
#pragma unroll
    for (int ct = 0; ct < 2; ++ct){
      bf8 wf = *(const bf8*)(outw + (size_t)(wave * 32 + ct * 16 + rr) * 128 + kc * 32 + grp * 8);
      pacc[0][ct] = mfma16(a0, wf, pacc[0][ct]);
      pacc[1][ct] = mfma16(a1, wf, pacc[1][ct]);
    }
  }
#pragma unroll
  for (int qt = 0; qt < 2; ++qt)
#pragma unroll
    for (int ct = 0; ct < 2; ++ct)
#pragma unroll
      for (int r = 0; r < 4; ++r){
        int q = qt * 16 + grp * 4 + r;
        int col = wave * 32 + ct * 16 + rr;
        size_t idx = (size_t)(b * 32 + q) * 128 + col;
        float v = a[idx] + pacc[qt][ct][r] + outb[col];
        a[idx] = v;
        aL[q][col] = v;
      }
  __syncthreads();
  {
    int r = t >> 3, s8 = t & 7;
    float sum = 0.f, sq = 0.f;
#pragma unroll
    for (int j = 0; j < 16; ++j){ float v = aL[r][s8 * 16 + j]; sum += v; sq += v * v; }
#pragma unroll
    for (int m = 1; m < 8; m <<= 1){ sum += __shfl_xor(sum, m); sq += __shfl_xor(sq, m); }
    float mu = sum * (1.f / 128.f);
    float var = sq * (1.f / 128.f) - mu * mu;
    float rs = rsqrtf(var + 1e-5f);
#pragma unroll
    for (int j = 0; j < 16; ++j){
      int c = s8 * 16 + j;
      lnA[(size_t)(b * 32 + r) * 128 + c] = (aL[r][c] - mu) * rs;
    }
  }
}

// ---------------------------------------------------------------- segment mean (atoms -> tokens)
__device__ __forceinline__ int lbound(const int* __restrict__ arr, int n, int v){
  int lo = 0, hi = n;
  while (lo < hi){ int mid = (lo + hi) >> 1; if (arr[mid] < v) lo = mid + 1; else hi = mid; }
  return lo;
}

__global__ __launch_bounds__(256) void k_segmean(const float* __restrict__ atom_out,
                                                 const int* __restrict__ a2t, u16* __restrict__ tokbf){
  const int tok = blockIdx.x;
  __shared__ int lo_s, hi_s;
  if (threadIdx.x == 0){
    lo_s = lbound(a2t, NATOMS, tok);
    hi_s = lbound(a2t, NATOMS, tok + 1);
  }
  __syncthreads();
  int lo = lo_s, hi = hi_s;
  float inv = 1.f / fmaxf((float)(hi - lo), 1.f);
  for (int c = threadIdx.x; c < 384; c += 256){
    float s = 0.f;
    for (int aa = lo; aa < hi; ++aa) s += atom_out[(size_t)aa * 384 + c];
    tokbf[(size_t)tok * 384 + c] = f2b(s * inv);
  }
}

// ---------------------------------------------------------------- pair head: tpf@Wp^T + u_i + u_j
__global__ __launch_bounds__(256) void k_pair(const float* __restrict__ tpf, const float* __restrict__ Wp,
                                              const float* __restrict__ u, float* __restrict__ out){
  __shared__ float stpf[32][32];
  const int blk = blockIdx.x;
  const int pair0 = blk * 32;
  const int t = threadIdx.x;
  for (int idx = t; idx < 1024; idx += 256){
    int pp = idx >> 5, k = idx & 31;
    int p = pair0 + pp;
    stpf[pp][k] = tpf[(size_t)p * 32 + k];
  }
  __syncthreads();
  const int c = t & 127;
  const int half = t >> 7;
  float w[32];
#pragma unroll
  for (int k = 0; k < 32; ++k) w[k] = Wp[c * 32 + k];
  const int i = pair0 >> 9;
  const float ui = u[(size_t)i * 256 + c];
  for (int pp = half * 16; pp < half * 16 + 16; ++pp){
    int p = pair0 + pp;
    int j = p & 511;
    float s = ui + u[(size_t)j * 256 + 128 + c];
#pragma unroll
    for (int k = 0; k < 32; ++k) s += stpf[pp][k] * w[k];
    out[(size_t)p * 128 + c] = s;
  }
}

// ================================================================ host
extern "C" void kernel_launch(void* const* d_in, const int* in_sizes, int n_in,
                              void* d_out, int out_size, void* d_ws, size_t ws_size,
                              hipStream_t stream){
  (void)in_sizes; (void)n_in; (void)out_size; (void)ws_size;
  const float* atom_feats = (const float*)d_in[0];
  const float* tpf        = (const float*)d_in[1];
  const float* W_cond     = (const float*)d_in[2];
  const float* W_ph       = (const float*)d_in[3];
  const float* W_pw       = (const float*)d_in[4];
  const float* W_mlp1     = (const float*)d_in[5];
  const float* W_mlp2     = (const float*)d_in[6];
  const float* pb_ln_w    = (const float*)d_in[7];
  const float* pb_ln_b    = (const float*)d_in[8];
  const float* pb_w       = (const float*)d_in[9];
  const float* sln_w      = (const float*)d_in[10];
  const float* qkv_w      = (const float*)d_in[11];
  const float* q_bias     = (const float*)d_in[12];
  const float* out_w      = (const float*)d_in[13];
  const float* out_b      = (const float*)d_in[14];
  const float* ada_w      = (const float*)d_in[15];
  const float* ta_w       = (const float*)d_in[16];
  const float* tb_w       = (const float*)d_in[17];
  const float* gate_w     = (const float*)d_in[18];
  const float* gate_b     = (const float*)d_in[19];
  const float* W_tok      = (const float*)d_in[20];
  const float* W_trunk    = (const float*)d_in[21];
  const float* W_struct   = (const float*)d_in[22];
  const float* W_pairin   = (const float*)d_in[23];
  const float* W_outer    = (const float*)d_in[24];
  const int*   a2t        = (const int*)d_in[28];

  char* wsb = (char*)d_ws;
  size_t off = 0;
  auto alc = [&](size_t bytes) -> void* {
    void* r = wsb + off;
    off = (off + bytes + 255) & ~(size_t)255;
    return r;
  };

  u16* af_bf     = (u16*)alc((size_t)NATOMS * 128 * 2);
  u16* wcond_bf  = (u16*)alc(16384 * 2);
  u16* sln_bfw   = (u16*)alc(98304 * 2);
  u16* qkv_bfw   = (u16*)alc(147456 * 2);
  u16* out_bfw   = (u16*)alc(49152 * 2);
  u16* ada_bfw   = (u16*)alc(98304 * 2);
  u16* ta_bfw    = (u16*)alc(196608 * 2);
  u16* tb_bfw    = (u16*)alc(98304 * 2);
  u16* gate_bfw  = (u16*)alc(49152 * 2);
  u16* tok_bfw   = (u16*)alc(49152 * 2);
  u16* trunk_bfw = (u16*)alc(147456 * 2);
  u16* struct_bfw= (u16*)alc(147456 * 2);
  u16* outer_bfw = (u16*)alc(98304 * 2);
  float* a_f     = (float*)alc((size_t)NATOMS * 128 * 4);
  float* lnA     = (float*)alc((size_t)NATOMS * 128 * 4);
  u16* sln_bf    = (u16*)alc((size_t)NATOMS * 128 * 2);
  u16* x_bf      = (u16*)alc((size_t)NATOMS * 128 * 2);
  u16* qkv_bf    = (u16*)alc((size_t)NATOMS * 384 * 2);
  u16* g_bf      = (u16*)alc((size_t)NATOMS * 256 * 2);
  float* gate_f  = (float*)alc((size_t)NATOMS * 128 * 4);
  u16* a_bf      = (u16*)alc((size_t)NATOMS * 128 * 2);
  float* ph      = (float*)alc((size_t)NATOMS * 16 * 4);
  float* pw      = (float*)alc((size_t)NATOMS * 16 * 4);
  float* bias    = (float*)alc((size_t)NBLK * 4 * 32 * 128 * 4);
  float* atom_out= bias; // alias: bias dead after layer-2 attention
  u16* tok_bf    = (u16*)alc(512 * 384 * 2);
  float* u_f     = (float*)alc(512 * 256 * 4);

  float* s_trunk  = (float*)d_out;
  float* s_struct = s_trunk + 512 * 384;
  float* pair_out = s_struct + 512 * 384;

  CvtArgs ca;
  const float* srcs[13] = {atom_feats, W_cond, sln_w, qkv_w, out_w, ada_w, ta_w, tb_w,
                           gate_w, W_tok, W_trunk, W_struct, W_outer};
  u16* dsts[13] = {af_bf, wcond_bf, sln_bfw, qkv_bfw, out_bfw, ada_bfw, ta_bfw, tb_bfw,
                   gate_bfw, tok_bfw, trunk_bfw, struct_bfw, outer_bfw};
  int n4s[13] = {NATOMS * 128 / 4, 4096, 24576, 36864, 12288, 24576, 49152, 24576,
                 12288, 12288, 36864, 36864, 24576};
  for (int s = 0; s < 13; ++s){ ca.src[s] = srcs[s]; ca.dst[s] = dsts[s]; ca.n4[s] = n4s[s]; }
  k_convert<<<512, 256, 0, stream>>>(ca);

  k_gemm_f32<128, 128><<<736, 256, 0, stream>>>(af_bf, wcond_bf, a_f);
  k_ln_phpw<<<2944, 256, 0, stream>>>(a_f, lnA, sln_bf, W_ph, W_pw, ph, pw);
  k_pb<<<NBLK * 8, 256, 0, stream>>>(ph, pw, W_mlp1, W_mlp2, pb_ln_w, pb_ln_b, pb_w, bias);

  for (int l = 0; l < 3; ++l){
    const u16* slnW  = sln_bfw  + (size_t)l * 256 * 128;
    const u16* qkvW  = qkv_bfw  + (size_t)l * 384 * 128;
    const u16* outW  = out_bfw  + (size_t)l * 128 * 128;
    const u16* adaW  = ada_bfw  + (size_t)l * 256 * 128;
    const u16* taW   = ta_bfw   + (size_t)l * 512 * 128;
    const u16* tbW   = tb_bfw   + (size_t)l * 128 * 256;
    const u16* gateW = gate_bfw + (size_t)l * 128 * 128;
    k_gemm_x<<<736, 256, 0, stream>>>(sln_bf, slnW, lnA, x_bf);
    k_gemm_qkv<<<736, 256, 0, stream>>>(x_bf, qkvW, q_bias + l * 128, qkv_bf);
    k_gemm_gate<<<736, 256, 0, stream>>>(sln_bf, gateW, gate_b + l * 128, gate_f);
    k_attn<<<NBLK, 256, 0, stream>>>(qkv_bf, bias, outW, out_b + l * 128, a_f, lnA);
    k_gemm_x<<<736, 256, 0, stream>>>(sln_bf, adaW, lnA, x_bf);
    k_gemm_glu<<<736, 256, 0, stream>>>(x_bf, taW, g_bf);
    k_gemm_tb<<<736, 256, 0, stream>>>(g_bf, tbW, gate_f, a_f, a_bf, lnA);
  }

  k_gemm_relu<<<736, 256, 0, stream>>>(a_bf, tok_bfw, atom_out);
  k_segmean<<<512, 256, 0, stream>>>(atom_out, a2t, tok_bf);
  k_gemm_f32<384, 384><<<32, 256, 0, stream>>>(tok_bf, trunk_bfw, s_trunk);
  k_gemm_f32<384, 384><<<32, 256, 0, stream>>>(tok_bf, struct_bfw, s_struct);
  k_gemm_f32<256, 384><<<32, 256, 0, stream>>>(tok_bf, outer_bfw, u_f);
  k_pair<<<8192, 256, 0, stream>>>(tpf, W_pairin, u_f, pair_out);
}

// Round 5
// 502.019 us; speedup vs baseline: 1.2404x; 1.0584x over previous
//
#include <hip/hip_runtime.h>
#include <cstddef>

typedef unsigned short u16;
typedef __attribute__((ext_vector_type(8))) short bf8;   // 8 x bf16 (4 VGPRs)
typedef __attribute__((ext_vector_type(4))) float f4;
typedef __attribute__((ext_vector_type(4))) unsigned short us4;

#define NATOMS 11776
#define NBLK   368

__device__ __forceinline__ u16 f2b(float x){
  union { float f; unsigned u; } v; v.f = x;
  unsigned r = v.u + 0x7fffu + ((v.u >> 16) & 1u);
  return (u16)(r >> 16);
}
__device__ __forceinline__ float b2f(u16 x){
  union { unsigned u; float f; } v; v.u = ((unsigned)x) << 16;
  return v.f;
}
__device__ __forceinline__ f4 f4zero(){ f4 z = {0.f,0.f,0.f,0.f}; return z; }
__device__ __forceinline__ f4 mfma16(bf8 a, bf8 b, f4 c){
  return __builtin_amdgcn_mfma_f32_16x16x32_bf16(a, b, c, 0, 0, 0);
}
__device__ __forceinline__ int iclamp(int v, int lo, int hi){ return v < lo ? lo : (v > hi ? hi : v); }
__device__ __forceinline__ void lds_fence(){
  asm volatile("s_waitcnt lgkmcnt(0)" ::: "memory");
  __builtin_amdgcn_sched_barrier(0);
}

// ---------------------------------------------------------------- convert fp32 -> bf16
struct CvtArgs {
  const float* src[13];
  u16* dst[13];
  int n4[13];
};

__global__ __launch_bounds__(256) void k_convert(CvtArgs a){
  int stride = gridDim.x * 256;
  int tid = blockIdx.x * 256 + threadIdx.x;
  for (int s = 0; s < 13; ++s){
    const float4* src = (const float4*)a.src[s];
    us4* dst = (us4*)a.dst[s];
    int n = a.n4[s];
    for (int i = tid; i < n; i += stride){
      float4 v = src[i];
      us4 o;
      o.x = f2b(v.x); o.y = f2b(v.y); o.z = f2b(v.z); o.w = f2b(v.w);
      dst[i] = o;
    }
  }
}

// ---------------------------------------------------------------- generic 16-row MFMA strip GEMM
template<int N, int K>
__device__ __forceinline__ void gemm_strip(const u16* __restrict__ A, const u16* __restrict__ W, float* L){
  constexpr int CPW = N / 4;       // cols per wave
  constexpr int T = CPW / 16;      // 16x16 tiles per wave
  const int lane = threadIdx.x & 63;
  const int wave = threadIdx.x >> 6;
  const int rr = lane & 15, grp = lane >> 4;
  f4 acc[T];
#pragma unroll
  for (int t = 0; t < T; ++t) acc[t] = f4zero();
#pragma unroll
  for (int kc = 0; kc < K / 32; ++kc){
    bf8 af = *(const bf8*)(A + rr * K + kc * 32 + grp * 8);
#pragma unroll
    for (int t = 0; t < T; ++t){
      const u16* wp = W + (size_t)(wave * CPW + t * 16 + rr) * K + kc * 32 + grp * 8;
      acc[t] = mfma16(af, *(const bf8*)wp, acc[t]);
    }
  }
#pragma unroll
  for (int t = 0; t < T; ++t)
#pragma unroll
    for (int r = 0; r < 4; ++r)
      L[(grp * 4 + r) * N + wave * CPW + t * 16 + rr] = acc[t][r];
}

template<int N, int K>
__global__ __launch_bounds__(256) void k_gemm_f32(const u16* __restrict__ A, const u16* __restrict__ W,
                                                  float* __restrict__ out){
  __shared__ float L[16 * N];
  const int strip = blockIdx.x;
  gemm_strip<N, K>(A + (size_t)strip * 16 * K, W, L);
  __syncthreads();
  const size_t base = (size_t)strip * 16 * N;
  for (int i = threadIdx.x; i < 16 * N; i += 256) out[base + i] = L[i];
}

__global__ __launch_bounds__(256) void k_gemm_x(const u16* __restrict__ A, const u16* __restrict__ W,
                                                const float* __restrict__ lnA, u16* __restrict__ xout){
  __shared__ float L[16 * 256];
  const int strip = blockIdx.x;
  gemm_strip<256, 128>(A + (size_t)strip * 2048, W, L);
  __syncthreads();
  for (int i = threadIdx.x; i < 16 * 128; i += 256){
    int r = i >> 7, c = i & 127;
    float g1 = L[r * 256 + c], g2 = L[r * 256 + 128 + c];
    float s = 1.f / (1.f + __expf(-g1));
    size_t idx = (size_t)(strip * 16 + r) * 128 + c;
    xout[idx] = f2b(s * lnA[idx] + g2);
  }
}

__global__ __launch_bounds__(256) void k_gemm_qkv(const u16* __restrict__ A, const u16* __restrict__ W,
                                                  const float* __restrict__ qb, u16* __restrict__ out){
  __shared__ float L[16 * 384];
  const int strip = blockIdx.x;
  gemm_strip<384, 128>(A + (size_t)strip * 2048, W, L);
  __syncthreads();
  const float scale = 0.17677669529663687f; // 1/sqrt(32)
  for (int i = threadIdx.x; i < 16 * 384; i += 256){
    int r = i / 384, c = i - r * 384;
    float v = L[i];
    if (c < 128) v = (v + qb[c]) * scale;
    out[(size_t)(strip * 16 + r) * 384 + c] = f2b(v);
  }
}

__global__ __launch_bounds__(256) void k_gemm_gate(const u16* __restrict__ A, const u16* __restrict__ W,
                                                   const float* __restrict__ gb, float* __restrict__ gate){
  __shared__ float L[16 * 128];
  const int strip = blockIdx.x;
  gemm_strip<128, 128>(A + (size_t)strip * 2048, W, L);
  __syncthreads();
  for (int i = threadIdx.x; i < 2048; i += 256){
    int c = i & 127;
    gate[(size_t)strip * 2048 + i] = 1.f / (1.f + __expf(-(L[i] + gb[c])));
  }
}

__global__ __launch_bounds__(256) void k_gemm_relu(const u16* __restrict__ A, const u16* __restrict__ W,
                                                   float* __restrict__ out){
  __shared__ float L[16 * 384];
  const int strip = blockIdx.x;
  gemm_strip<384, 128>(A + (size_t)strip * 2048, W, L);
  __syncthreads();
  const size_t base = (size_t)strip * 16 * 384;
  for (int i = threadIdx.x; i < 16 * 384; i += 256) out[base + i] = fmaxf(L[i], 0.f);
}

__global__ __launch_bounds__(256) void k_gemm_glu(const u16* __restrict__ A, const u16* __restrict__ W,
                                                  u16* __restrict__ g){
  __shared__ float L[16 * 512];
  const int strip = blockIdx.x;
  gemm_strip<512, 128>(A + (size_t)strip * 2048, W, L);
  __syncthreads();
  for (int i = threadIdx.x; i < 16 * 256; i += 256){
    int r = i >> 8, c = i & 255;
    float ab1 = L[r * 512 + c], ab2 = L[r * 512 + 256 + c];
    float silu = ab1 / (1.f + __expf(-ab1));
    g[(size_t)(strip * 16 + r) * 256 + c] = f2b(silu * ab2);
  }
}

__global__ __launch_bounds__(256) void k_gemm_tb(const u16* __restrict__ A, const u16* __restrict__ W,
                                                 const float* __restrict__ gate, float* __restrict__ a,
                                                 u16* __restrict__ a_bf, float* __restrict__ lnA){
  __shared__ float L[16 * 128];
  const int strip = blockIdx.x;
  gemm_strip<128, 256>(A + (size_t)strip * 16 * 256, W, L);
  __syncthreads();
  for (int i = threadIdx.x; i < 2048; i += 256){
    size_t idx = (size_t)strip * 2048 + i;
    float v = a[idx] + gate[idx] * L[i];
    a[idx] = v;
    a_bf[idx] = f2b(v);
    L[i] = v;
  }
  __syncthreads();
  int r = threadIdx.x >> 4, s = threadIdx.x & 15;
  float sum = 0.f, sq = 0.f;
#pragma unroll
  for (int j = 0; j < 8; ++j){ float v = L[r * 128 + s * 8 + j]; sum += v; sq += v * v; }
#pragma unroll
  for (int m = 1; m < 16; m <<= 1){ sum += __shfl_xor(sum, m); sq += __shfl_xor(sq, m); }
  float mu = sum * (1.f / 128.f);
  float var = sq * (1.f / 128.f) - mu * mu;
  float rs = rsqrtf(var + 1e-5f);
#pragma unroll
  for (int j = 0; j < 8; ++j){
    int c = s * 8 + j;
    lnA[(size_t)(strip * 16 + r) * 128 + c] = (L[r * 128 + c] - mu) * rs;
  }
}

// ---------------------------------------------------------------- LN(c) + relu -> ph/pw projections
__global__ __launch_bounds__(256) void k_ln_phpw(const float* __restrict__ c, float* __restrict__ lnA,
                                                 u16* __restrict__ slnb, const float* __restrict__ Wph,
                                                 const float* __restrict__ Wpw, float* __restrict__ ph,
                                                 float* __restrict__ pw){
  __shared__ float rs[4][128];
  const int wave = threadIdx.x >> 6, lane = threadIdx.x & 63;
  const int row = blockIdx.x * 4 + wave;
  const float* cr = c + (size_t)row * 128;
  float2 v = *(const float2*)(cr + lane * 2);
  float sum = v.x + v.y, sq = v.x * v.x + v.y * v.y;
#pragma unroll
  for (int m = 1; m < 64; m <<= 1){ sum += __shfl_xor(sum, m); sq += __shfl_xor(sq, m); }
  float mu = sum * (1.f / 128.f);
  float var = sq * (1.f / 128.f) - mu * mu;
  float r = rsqrtf(var + 1e-5f);
  float s0 = (v.x - mu) * r, s1 = (v.y - mu) * r;
  size_t base = (size_t)row * 128 + lane * 2;
  lnA[base] = s0; lnA[base + 1] = s1;
  slnb[base] = f2b(s0); slnb[base + 1] = f2b(s1);
  rs[wave][lane * 2] = fmaxf(s0, 0.f); rs[wave][lane * 2 + 1] = fmaxf(s1, 0.f);
  __syncthreads();
  int h = lane & 15, part = lane >> 4;
  float acch = 0.f, accw = 0.f;
#pragma unroll
  for (int k = 0; k < 32; ++k){
    int kk = part * 32 + k;
    float rv = rs[wave][kk];
    acch += rv * Wph[h * 128 + kk];
    accw += rv * Wpw[h * 128 + kk];
  }
  acch += __shfl_xor(acch, 16); acch += __shfl_xor(acch, 32);
  accw += __shfl_xor(accw, 16); accw += __shfl_xor(accw, 32);
  if (lane < 16){
    ph[(size_t)row * 16 + h] = acch;
    pw[(size_t)row * 16 + h] = accw;
  }
}

// ---------------------------------------------------------------- pair-bias MLP v4: all-MFMA, zero shuffles
__global__ __launch_bounds__(256) void k_pb(const float* __restrict__ ph, const float* __restrict__ pw,
                                            const float* __restrict__ W1, const float* __restrict__ W2,
                                            const float* __restrict__ lnw, const float* __restrict__ lnb,
                                            const float* __restrict__ pbw, float* __restrict__ bias){
  __shared__ __align__(16) u16 mt[4][16 * 24];  // per-wave m tile (row stride 48B)
  __shared__ __align__(16) u16 vt[4][16 * 24];  // per-wave pfin tile
  const int t = threadIdx.x;
  const int lane = t & 63, wave = t >> 6;
  const int rr = lane & 15, grp = lane >> 4;
  const int b = blockIdx.x >> 3, qg = blockIdx.x & 7;
  const int q = qg * 4 + wave;
  const int qa = b * 32 + q;

  bf8 wf1 = {0,0,0,0,0,0,0,0}, wf2 = {0,0,0,0,0,0,0,0};
  bf8 bproj = {0,0,0,0,0,0,0,0}, bones = {0,0,0,0,0,0,0,0};
  if (grp < 2){
#pragma unroll
    for (int j = 0; j < 8; ++j){
      wf1[j] = (short)f2b(W1[rr * 16 + grp * 8 + j]);
      wf2[j] = (short)f2b(W2[rr * 16 + grp * 8 + j]);
      bones[j] = (short)0x3F80;  // bf16 1.0
    }
    if (rr < 4){
#pragma unroll
      for (int j = 0; j < 8; ++j)
        bproj[j] = (short)f2b(pbw[rr * 16 + grp * 8 + j] * lnw[grp * 8 + j]);
    }
  }
  float w2s_r = 0.f, bb_r = 0.f;
  if (rr < 4){
#pragma unroll
    for (int cc = 0; cc < 16; ++cc){
      float pv = pbw[rr * 16 + cc];
      w2s_r += pv * lnw[cc];
      bb_r  += pv * lnb[cc];
    }
  }
  const float* phq = ph + (size_t)qa * 16;
  float pha[8];
  if (grp < 2){
#pragma unroll
    for (int j = 0; j < 8; ++j) pha[j] = phq[grp * 8 + j];
  }
  const float ph_r = phq[rr];
  u16* mw = &mt[wave][0];
  u16* vw = &vt[wave][0];

  for (int kt = 0; kt < 8; ++kt){
    const int k0 = kt * 16;
    bf8 af = {0,0,0,0,0,0,0,0};
    if (grp < 2){
      int winA = b * 32 + k0 + rr - 48;
      int kaA = iclamp(winA, 0, NATOMS - 1);
      const float* pwr = pw + (size_t)kaA * 16 + grp * 8;
#pragma unroll
      for (int j = 0; j < 8; ++j) af[j] = (short)f2b(fmaxf(pha[j] + pwr[j], 0.f));
    }
    f4 c1 = mfma16(af, wf1, f4zero());
#pragma unroll
    for (int r = 0; r < 4; ++r)
      mw[(grp * 4 + r) * 24 + rr] = f2b(fmaxf(c1[r], 0.f));
    lds_fence();
    bf8 mf = {0,0,0,0,0,0,0,0};
    if (grp < 2) mf = *(const bf8*)(mw + rr * 24 + grp * 8);
    f4 c2 = mfma16(mf, wf2, f4zero());
#pragma unroll
    for (int r = 0; r < 4; ++r){
      int win = b * 32 + k0 + grp * 4 + r - 48;
      int ka = iclamp(win, 0, NATOMS - 1);
      float v = c2[r] + ph_r + pw[(size_t)ka * 16 + rr];
      vw[(grp * 4 + r) * 24 + rr] = f2b(v);
    }
    lds_fence();
    bf8 vf = {0,0,0,0,0,0,0,0}, vf2 = {0,0,0,0,0,0,0,0};
    if (grp < 2){
      vf = *(const bf8*)(vw + rr * 24 + grp * 8);
#pragma unroll
      for (int j = 0; j < 8; ++j){
        float x = b2f((u16)vf[j]);
        union { float f; unsigned u; } s; s.f = x * x;
        vf2[j] = (short)(u16)(s.u >> 16);   // truncate: squares are non-negative
      }
    }
    f4 T1 = mfma16(vf, bproj, f4zero());
    f4 T2 = mfma16(vf, bones, f4zero());
    f4 T3 = mfma16(vf2, bones, f4zero());
    if (rr < 4){
      float4 o;
      float ov[4];
#pragma unroll
      for (int r = 0; r < 4; ++r){
        int win = b * 32 + k0 + grp * 4 + r - 48;
        bool valid = (win >= 0) && (win < NATOMS);
        float S = T2[r], Q = T3[r], d = T1[r];
        float mu = S * (1.f / 16.f);
        float var = Q * (1.f / 16.f) - mu * mu;
        float rq = rsqrtf(var + 1e-5f);
        ov[r] = rq * (d - mu * w2s_r) + bb_r + (valid ? 0.f : -1e9f);
      }
      o.x = ov[0]; o.y = ov[1]; o.z = ov[2]; o.w = ov[3];
      *(float4*)(bias + ((size_t)((b * 4 + rr) * 32) + q) * 128 + k0 + grp * 4) = o;
    }
  }
}

// ---------------------------------------------------------------- block attention + out-proj + residual + row-LN
__global__ __launch_bounds__(256) void k_attn(const u16* __restrict__ qkv, const float* __restrict__ bias,
                                              const u16* __restrict__ outw, const float* __restrict__ outb,
                                              float* __restrict__ a, float* __restrict__ lnA){
  __shared__ u16 VT[128][136];
  __shared__ u16 P[4][32 * 136];
  __shared__ u16 O[32][136];
  __shared__ float aL[32][128];
  const int t = threadIdx.x;
  const int lane = t & 63, wave = t >> 6;
  const int b = blockIdx.x;
  const int rr = lane & 15, grp = lane >> 4;

  for (int i = 0; i < 8; ++i){
    int s = t + 256 * i;
    int ka = s & 127, d0 = (s >> 7) * 8;
    int win = b * 32 + ka - 48;
    int src = iclamp(win, 0, NATOMS - 1);
    bf8 v = *(const bf8*)(qkv + (size_t)src * 384 + 256 + d0);
#pragma unroll
    for (int j = 0; j < 8; ++j) VT[d0 + j][ka] = (u16)v[j];
  }
  __syncthreads();

  const int h = wave;
  bf8 kfr[8];
#pragma unroll
  for (int kt = 0; kt < 8; ++kt){
    int ka = kt * 16 + rr;
    int win = b * 32 + ka - 48;
    int src = iclamp(win, 0, NATOMS - 1);
    kfr[kt] = *(const bf8*)(qkv + (size_t)src * 384 + 128 + h * 32 + grp * 8);
  }
  f4 S[2][8];
#pragma unroll
  for (int qt = 0; qt < 2; ++qt){
    bf8 qf = *(const bf8*)(qkv + (size_t)(b * 32 + qt * 16 + rr) * 384 + h * 32 + grp * 8);
#pragma unroll
    for (int kt = 0; kt < 8; ++kt){
      S[qt][kt] = f4zero();
      S[qt][kt] = mfma16(qf, kfr[kt], S[qt][kt]);
    }
  }
  const float* brow = bias + (size_t)((b * 4 + h) * 32) * 128;
#pragma unroll
  for (int qt = 0; qt < 2; ++qt){
#pragma unroll
    for (int r = 0; r < 4; ++r){
      int q = qt * 16 + grp * 4 + r;
      float vals[8];
      float mx = -1e30f;
#pragma unroll
      for (int kt = 0; kt < 8; ++kt){
        float v = S[qt][kt][r] + brow[q * 128 + kt * 16 + rr];
        vals[kt] = v;
        mx = fmaxf(mx, v);
      }
#pragma unroll
      for (int m = 1; m < 16; m <<= 1) mx = fmaxf(mx, __shfl_xor(mx, m));
      float sum = 0.f;
#pragma unroll
      for (int kt = 0; kt < 8; ++kt){ vals[kt] = __expf(vals[kt] - mx); sum += vals[kt]; }
#pragma unroll
      for (int m = 1; m < 16; m <<= 1) sum += __shfl_xor(sum, m);
      float inv = 1.f / sum;
#pragma unroll
      for (int kt = 0; kt < 8; ++kt)
        P[h][q * 136 + kt * 16 + rr] = f2b(vals[kt] * inv);
    }
  }
  __syncthreads();
  f4 oacc[2][2];
#pragma unroll
  for (int qt = 0; qt < 2; ++qt)
#pragma unroll
    for (int dt = 0; dt < 2; ++dt) oacc[qt][dt] = f4zero();
#pragma unroll
  for (int kc = 0; kc < 4; ++kc){
#pragma unroll
    for (int qt = 0; qt < 2; ++qt){
      bf8 pa = *(const bf8*)(&P[h][(qt * 16 + rr) * 136 + kc * 32 + grp * 8]);
#pragma unroll
      for (int dt = 0; dt < 2; ++dt){
        bf8 vb = *(const bf8*)(&VT[h * 32 + dt * 16 + rr][kc * 32 + grp * 8]);
        oacc[qt][dt] = mfma16(pa, vb, oacc[qt][dt]);
      }
    }
  }
#pragma unroll
  for (int qt = 0; qt < 2; ++qt)
#pragma unroll
    for (int dt = 0; dt < 2; ++dt)
#pragma unroll
      for (int r = 0; r < 4; ++r)
        O[qt * 16 + grp * 4 + r][h * 32 + dt * 16 + rr] = f2b(oacc[qt][dt][r]);
  __syncthreads();
  f4 pacc[2][2];
#pragma unroll
  for (int qt = 0; qt < 2; ++qt)
#pragma unroll
    for (int ct = 0; ct < 2; ++ct) pacc[qt][ct] = f4zero();
#pragma unroll
  for (int kc = 0; kc < 4; ++kc){
    bf8 a0 = *(const bf8*)(&O[rr][kc * 32 + grp * 8]);
    bf8 a1 = *(const bf8*)(&O[16 + rr][kc * 32 + grp * 8]);
#pragma unroll
    for (int ct = 0; ct < 2; ++ct){
      bf8 wf = *(const bf8*)(outw + (size_t)(wave * 32 + ct * 16 + rr) * 128 + kc * 32 + grp * 8);
      pacc[0][ct] = mfma16(a0, wf, pacc[0][ct]);
      pacc[1][ct] = mfma16(a1, wf, pacc[1][ct]);
    }
  }
#pragma unroll
  for (int qt = 0; qt < 2; ++qt)
#pragma unroll
    for (int ct = 0; ct < 2; ++ct)
#pragma unroll
      for (int r = 0; r < 4; ++r){
        int q = qt * 16 + grp * 4 + r;
        int col = wave * 32 + ct * 16 + rr;
        size_t idx = (size_t)(b * 32 + q) * 128 + col;
        float v = a[idx] + pacc[qt][ct][r] + outb[col];
        a[idx] = v;
        aL[q][col] = v;
      }
  __syncthreads();
  {
    int r = t >> 3, s8 = t & 7;
    float sum = 0.f, sq = 0.f;
#pragma unroll
    for (int j = 0; j < 16; ++j){ float v = aL[r][s8 * 16 + j]; sum += v; sq += v * v; }
#pragma unroll
    for (int m = 1; m < 8; m <<= 1){ sum += __shfl_xor(sum, m); sq += __shfl_xor(sq, m); }
    float mu = sum * (1.f / 128.f);
    float var = sq * (1.f / 128.f) - mu * mu;
    float rs = rsqrtf(var + 1e-5f);
#pragma unroll
    for (int j = 0; j < 16; ++j){
      int c = s8 * 16 + j;
      lnA[(size_t)(b * 32 + r) * 128 + c] = (aL[r][c] - mu) * rs;
    }
  }
}

// ---------------------------------------------------------------- segment mean (atoms -> tokens)
__device__ __forceinline__ int lbound(const int* __restrict__ arr, int n, int v){
  int lo = 0, hi = n;
  while (lo < hi){ int mid = (lo + hi) >> 1; if (arr[mid] < v) lo = mid + 1; else hi = mid; }
  return lo;
}

__global__ __launch_bounds__(256) void k_segmean(const float* __restrict__ atom_out,
                                                 const int* __restrict__ a2t, u16* __restrict__ tokbf){
  const int tok = blockIdx.x;
  __shared__ int lo_s, hi_s;
  if (threadIdx.x == 0){
    lo_s = lbound(a2t, NATOMS, tok);
    hi_s = lbound(a2t, NATOMS, tok + 1);
  }
  __syncthreads();
  int lo = lo_s, hi = hi_s;
  float inv = 1.f / fmaxf((float)(hi - lo), 1.f);
  for (int c = threadIdx.x; c < 384; c += 256){
    float s = 0.f;
    for (int aa = lo; aa < hi; ++aa) s += atom_out[(size_t)aa * 384 + c];
    tokbf[(size_t)tok * 384 + c] = f2b(s * inv);
  }
}

// ---------------------------------------------------------------- pair head v2: MFMA GEMM (K=32) + u_i + u_j
// grid 4096 blocks x 4 waves; wave owns 16 pairs x 128 cols. Zero LDS/shuffles.
// A-frag: tpf row (fp32 -> bf16 in-register). B-frags: Wp rows. 8 mfma per wave.
__global__ __launch_bounds__(256) void k_pair(const float* __restrict__ tpf, const float* __restrict__ Wp,
                                              const float* __restrict__ u, float* __restrict__ out){
  const int lane = threadIdx.x & 63, wave = threadIdx.x >> 6;
  const int rr = lane & 15, grp = lane >> 4;
  const int pairbase = blockIdx.x * 64 + wave * 16;
  const int i = (blockIdx.x * 64) >> 9;      // 64 | 512 -> i constant per block
  // A-frag: row rr of this wave's 16 pairs, k = grp*8+j (fp32->bf16)
  bf8 af;
  {
    const float* tr = tpf + (size_t)(pairbase + rr) * 32 + grp * 8;
#pragma unroll
    for (int j = 0; j < 8; ++j) af[j] = (short)f2b(tr[j]);
  }
  f4 acc[8];
#pragma unroll
  for (int t = 0; t < 8; ++t){
    bf8 bf;
    const float* wr = Wp + (size_t)(t * 16 + rr) * 32 + grp * 8;
#pragma unroll
    for (int j = 0; j < 8; ++j) bf[j] = (short)f2b(wr[j]);
    acc[t] = mfma16(af, bf, f4zero());
  }
  // epilogue: + u_i[c] + u_j[128+c], store f32
  const float* ui = u + (size_t)i * 256;
#pragma unroll
  for (int t = 0; t < 8; ++t){
    int c = t * 16 + rr;
    float uic = ui[c];
#pragma unroll
    for (int r = 0; r < 4; ++r){
      int p = pairbase + grp * 4 + r;
      int j = p & 511;
      out[(size_t)p * 128 + c] = acc[t][r] + uic + u[(size_t)j * 256 + 128 + c];
    }
  }
}

// ================================================================ host
extern "C" void kernel_launch(void* const* d_in, const int* in_sizes, int n_in,
                              void* d_out, int out_size, void* d_ws, size_t ws_size,
                              hipStream_t stream){
  (void)in_sizes; (void)n_in; (void)out_size; (void)ws_size;
  const float* atom_feats = (const float*)d_in[0];
  const float* tpf        = (const float*)d_in[1];
  const float* W_cond     = (const float*)d_in[2];
  const float* W_ph       = (const float*)d_in[3];
  const float* W_pw       = (const float*)d_in[4];
  const float* W_mlp1     = (const float*)d_in[5];
  const float* W_mlp2     = (const float*)d_in[6];
  const float* pb_ln_w    = (const float*)d_in[7];
  const float* pb_ln_b    = (const float*)d_in[8];
  const float* pb_w       = (const float*)d_in[9];
  const float* sln_w      = (const float*)d_in[10];
  const float* qkv_w      = (const float*)d_in[11];
  const float* q_bias     = (const float*)d_in[12];
  const float* out_w      = (const float*)d_in[13];
  const float* out_b      = (const float*)d_in[14];
  const float* ada_w      = (const float*)d_in[15];
  const float* ta_w       = (const float*)d_in[16];
  const float* tb_w       = (const float*)d_in[17];
  const float* gate_w     = (const float*)d_in[18];
  const float* gate_b     = (const float*)d_in[19];
  const float* W_tok      = (const float*)d_in[20];
  const float* W_trunk    = (const float*)d_in[21];
  const float* W_struct   = (const float*)d_in[22];
  const float* W_pairin   = (const float*)d_in[23];
  const float* W_outer    = (const float*)d_in[24];
  const int*   a2t        = (const int*)d_in[28];

  char* wsb = (char*)d_ws;
  size_t off = 0;
  auto alc = [&](size_t bytes) -> void* {
    void* r = wsb + off;
    off = (off + bytes + 255) & ~(size_t)255;
    return r;
  };

  u16* af_bf     = (u16*)alc((size_t)NATOMS * 128 * 2);
  u16* wcond_bf  = (u16*)alc(16384 * 2);
  u16* sln_bfw   = (u16*)alc(98304 * 2);
  u16* qkv_bfw   = (u16*)alc(147456 * 2);
  u16* out_bfw   = (u16*)alc(49152 * 2);
  u16* ada_bfw   = (u16*)alc(98304 * 2);
  u16* ta_bfw    = (u16*)alc(196608 * 2);
  u16* tb_bfw    = (u16*)alc(98304 * 2);
  u16* gate_bfw  = (u16*)alc(49152 * 2);
  u16* tok_bfw   = (u16*)alc(49152 * 2);
  u16* trunk_bfw = (u16*)alc(147456 * 2);
  u16* struct_bfw= (u16*)alc(147456 * 2);
  u16* outer_bfw = (u16*)alc(98304 * 2);
  float* a_f     = (float*)alc((size_t)NATOMS * 128 * 4);
  float* lnA     = (float*)alc((size_t)NATOMS * 128 * 4);
  u16* sln_bf    = (u16*)alc((size_t)NATOMS * 128 * 2);
  u16* x_bf      = (u16*)alc((size_t)NATOMS * 128 * 2);
  u16* qkv_bf    = (u16*)alc((size_t)NATOMS * 384 * 2);
  u16* g_bf      = (u16*)alc((size_t)NATOMS * 256 * 2);
  float* gate_f  = (float*)alc((size_t)NATOMS * 128 * 4);
  u16* a_bf      = (u16*)alc((size_t)NATOMS * 128 * 2);
  float* ph      = (float*)alc((size_t)NATOMS * 16 * 4);
  float* pw      = (float*)alc((size_t)NATOMS * 16 * 4);
  float* bias    = (float*)alc((size_t)NBLK * 4 * 32 * 128 * 4);
  float* atom_out= bias; // alias: bias dead after layer-2 attention
  u16* tok_bf    = (u16*)alc(512 * 384 * 2);
  float* u_f     = (float*)alc(512 * 256 * 4);

  float* s_trunk  = (float*)d_out;
  float* s_struct = s_trunk + 512 * 384;
  float* pair_out = s_struct + 512 * 384;

  CvtArgs ca;
  const float* srcs[13] = {atom_feats, W_cond, sln_w, qkv_w, out_w, ada_w, ta_w, tb_w,
                           gate_w, W_tok, W_trunk, W_struct, W_outer};
  u16* dsts[13] = {af_bf, wcond_bf, sln_bfw, qkv_bfw, out_bfw, ada_bfw, ta_bfw, tb_bfw,
                   gate_bfw, tok_bfw, trunk_bfw, struct_bfw, outer_bfw};
  int n4s[13] = {NATOMS * 128 / 4, 4096, 24576, 36864, 12288, 24576, 49152, 24576,
                 12288, 12288, 36864, 36864, 24576};
  for (int s = 0; s < 13; ++s){ ca.src[s] = srcs[s]; ca.dst[s] = dsts[s]; ca.n4[s] = n4s[s]; }
  k_convert<<<512, 256, 0, stream>>>(ca);

  k_gemm_f32<128, 128><<<736, 256, 0, stream>>>(af_bf, wcond_bf, a_f);
  k_ln_phpw<<<2944, 256, 0, stream>>>(a_f, lnA, sln_bf, W_ph, W_pw, ph, pw);
  k_pb<<<NBLK * 8, 256, 0, stream>>>(ph, pw, W_mlp1, W_mlp2, pb_ln_w, pb_ln_b, pb_w, bias);

  for (int l = 0; l < 3; ++l){
    const u16* slnW  = sln_bfw  + (size_t)l * 256 * 128;
    const u16* qkvW  = qkv_bfw  + (size_t)l * 384 * 128;
    const u16* outW  = out_bfw  + (size_t)l * 128 * 128;
    const u16* adaW  = ada_bfw  + (size_t)l * 256 * 128;
    const u16* taW   = ta_bfw   + (size_t)l * 512 * 128;
    const u16* tbW   = tb_bfw   + (size_t)l * 128 * 256;
    const u16* gateW = gate_bfw + (size_t)l * 128 * 128;
    k_gemm_x<<<736, 256, 0, stream>>>(sln_bf, slnW, lnA, x_bf);
    k_gemm_qkv<<<736, 256, 0, stream>>>(x_bf, qkvW, q_bias + l * 128, qkv_bf);
    k_gemm_gate<<<736, 256, 0, stream>>>(sln_bf, gateW, gate_b + l * 128, gate_f);
    k_attn<<<NBLK, 256, 0, stream>>>(qkv_bf, bias, outW, out_b + l * 128, a_f, lnA);
    k_gemm_x<<<736, 256, 0, stream>>>(sln_bf, adaW, lnA, x_bf);
    k_gemm_glu<<<736, 256, 0, stream>>>(x_bf, taW, g_bf);
    k_gemm_tb<<<736, 256, 0, stream>>>(g_bf, tbW, gate_f, a_f, a_bf, lnA);
  }

  k_gemm_relu<<<736, 256, 0, stream>>>(a_bf, tok_bfw, atom_out);
  k_segmean<<<512, 256, 0, stream>>>(atom_out, a2t, tok_bf);
  k_gemm_f32<384, 384><<<32, 256, 0, stream>>>(tok_bf, trunk_bfw, s_trunk);
  k_gemm_f32<384, 384><<<32, 256, 0, stream>>>(tok_bf, struct_bfw, s_struct);
  k_gemm_f32<256, 384><<<32, 256, 0, stream>>>(tok_bf, outer_bfw, u_f);
  k_pair<<<4096, 256, 0, stream>>>(tpf, W_pairin, u_f, pair_out);
}

// Round 6
// 433.901 us; speedup vs baseline: 1.4351x; 1.1570x over previous
//
#include <hip/hip_runtime.h>
#include <cstddef>

typedef unsigned short u16;
typedef __attribute__((ext_vector_type(8))) short bf8;   // 8 x bf16 (4 VGPRs)
typedef __attribute__((ext_vector_type(4))) float f4;
typedef __attribute__((ext_vector_type(4))) unsigned short us4;

#define NATOMS 11776
#define NBLK   368

__device__ __forceinline__ u16 f2b(float x){
  union { float f; unsigned u; } v; v.f = x;
  unsigned r = v.u + 0x7fffu + ((v.u >> 16) & 1u);
  return (u16)(r >> 16);
}
__device__ __forceinline__ float b2f(u16 x){
  union { unsigned u; float f; } v; v.u = ((unsigned)x) << 16;
  return v.f;
}
__device__ __forceinline__ f4 f4zero(){ f4 z = {0.f,0.f,0.f,0.f}; return z; }
__device__ __forceinline__ f4 mfma16(bf8 a, bf8 b, f4 c){
  return __builtin_amdgcn_mfma_f32_16x16x32_bf16(a, b, c, 0, 0, 0);
}
__device__ __forceinline__ int iclamp(int v, int lo, int hi){ return v < lo ? lo : (v > hi ? hi : v); }
__device__ __forceinline__ void lds_fence(){
  asm volatile("s_waitcnt lgkmcnt(0)" ::: "memory");
  __builtin_amdgcn_sched_barrier(0);
}

// ---------------------------------------------------------------- convert fp32 -> bf16
struct CvtArgs {
  const float* src[13];
  u16* dst[13];
  int n4[13];
};

__global__ __launch_bounds__(256) void k_convert(CvtArgs a){
  int stride = gridDim.x * 256;
  int tid = blockIdx.x * 256 + threadIdx.x;
  for (int s = 0; s < 13; ++s){
    const float4* src = (const float4*)a.src[s];
    us4* dst = (us4*)a.dst[s];
    int n = a.n4[s];
    for (int i = tid; i < n; i += stride){
      float4 v = src[i];
      us4 o;
      o.x = f2b(v.x); o.y = f2b(v.y); o.z = f2b(v.z); o.w = f2b(v.w);
      dst[i] = o;
    }
  }
}

// ---------------------------------------------------------------- generic 16-row MFMA strip GEMM
// A may live in global or LDS (inlined -> addrspace inferred). LDA in u16 elems.
template<int N, int K, int LDA = K>
__device__ __forceinline__ void gemm_strip(const u16* __restrict__ A, const u16* __restrict__ W, float* L){
  constexpr int CPW = N / 4;       // cols per wave
  constexpr int T = CPW / 16;      // 16x16 tiles per wave
  const int lane = threadIdx.x & 63;
  const int wave = threadIdx.x >> 6;
  const int rr = lane & 15, grp = lane >> 4;
  f4 acc[T];
#pragma unroll
  for (int t = 0; t < T; ++t) acc[t] = f4zero();
#pragma unroll
  for (int kc = 0; kc < K / 32; ++kc){
    bf8 af = *(const bf8*)(A + rr * LDA + kc * 32 + grp * 8);
#pragma unroll
    for (int t = 0; t < T; ++t){
      const u16* wp = W + (size_t)(wave * CPW + t * 16 + rr) * K + kc * 32 + grp * 8;
      acc[t] = mfma16(af, *(const bf8*)wp, acc[t]);
    }
  }
#pragma unroll
  for (int t = 0; t < T; ++t)
#pragma unroll
    for (int r = 0; r < 4; ++r)
      L[(grp * 4 + r) * N + wave * CPW + t * 16 + rr] = acc[t][r];
}

template<int N, int K>
__global__ __launch_bounds__(256) void k_gemm_f32(const u16* __restrict__ A, const u16* __restrict__ W,
                                                  float* __restrict__ out){
  __shared__ float L[16 * N];
  const int strip = blockIdx.x;
  gemm_strip<N, K>(A + (size_t)strip * 16 * K, W, L);
  __syncthreads();
  const size_t base = (size_t)strip * 16 * N;
  for (int i = threadIdx.x; i < 16 * N; i += 256) out[base + i] = L[i];
}

// ---------------------------------------------------------------- fused pre-attention: sln->x->qkv + gate
__global__ __launch_bounds__(256) void k_pre(const u16* __restrict__ sln, const float* __restrict__ lnA,
                                             const u16* __restrict__ slnW, const u16* __restrict__ gateW,
                                             const u16* __restrict__ qkvW, const float* __restrict__ qb,
                                             const float* __restrict__ gbias,
                                             u16* __restrict__ qkv_out, float* __restrict__ gate_out){
  __shared__ float LB[16 * 384];
  __shared__ __align__(16) u16 X[16 * 136];   // padded: 272B row stride
  const int strip = blockIdx.x;
  const u16* Ag = sln + (size_t)strip * 2048;
  gemm_strip<256, 128>(Ag, slnW, LB);
  __syncthreads();
  for (int i = threadIdx.x; i < 2048; i += 256){
    int r = i >> 7, c = i & 127;
    float g1 = LB[r * 256 + c], g2 = LB[r * 256 + 128 + c];
    float s = 1.f / (1.f + __expf(-g1));
    X[r * 136 + c] = f2b(s * lnA[(size_t)(strip * 16 + r) * 128 + c] + g2);
  }
  __syncthreads();
  gemm_strip<128, 128>(Ag, gateW, LB);
  __syncthreads();
  for (int i = threadIdx.x; i < 2048; i += 256){
    int c = i & 127;
    gate_out[(size_t)strip * 2048 + i] = 1.f / (1.f + __expf(-(LB[i] + gbias[c])));
  }
  __syncthreads();
  gemm_strip<384, 128, 136>(X, qkvW, LB);
  __syncthreads();
  const float scale = 0.17677669529663687f; // 1/sqrt(32)
  for (int i = threadIdx.x; i < 16 * 384; i += 256){
    int r = i / 384, c = i - r * 384;
    float v = LB[i];
    if (c < 128) v = (v + qb[c]) * scale;
    qkv_out[(size_t)(strip * 16 + r) * 384 + c] = f2b(v);
  }
}

// ---------------------------------------------------------------- fused post-attention: ada->x2->ta->glu->tb->residual(+LN | +tok relu-GEMM)
template<int LAST>
__global__ __launch_bounds__(256) void k_post(const u16* __restrict__ sln, float* __restrict__ lnA,
                                              float* __restrict__ a, const float* __restrict__ gate,
                                              const u16* __restrict__ adaW, const u16* __restrict__ taW,
                                              const u16* __restrict__ tbW, const u16* __restrict__ tokW,
                                              float* __restrict__ atom_out){
  __shared__ float LB[16 * 512];
  __shared__ __align__(16) u16 X[16 * 136];
  __shared__ __align__(16) u16 G[16 * 264];   // padded: 528B row stride
  const int strip = blockIdx.x;
  const u16* Ag = sln + (size_t)strip * 2048;
  gemm_strip<256, 128>(Ag, adaW, LB);
  __syncthreads();
  for (int i = threadIdx.x; i < 2048; i += 256){
    int r = i >> 7, c = i & 127;
    float g1 = LB[r * 256 + c], g2 = LB[r * 256 + 128 + c];
    float s = 1.f / (1.f + __expf(-g1));
    X[r * 136 + c] = f2b(s * lnA[(size_t)(strip * 16 + r) * 128 + c] + g2);
  }
  __syncthreads();
  gemm_strip<512, 128, 136>(X, taW, LB);
  __syncthreads();
  for (int i = threadIdx.x; i < 16 * 256; i += 256){
    int r = i >> 8, c = i & 255;
    float ab1 = LB[r * 512 + c], ab2 = LB[r * 512 + 256 + c];
    G[r * 264 + c] = f2b(ab1 / (1.f + __expf(-ab1)) * ab2);
  }
  __syncthreads();
  gemm_strip<128, 256, 264>(G, tbW, LB);
  __syncthreads();
  for (int i = threadIdx.x; i < 2048; i += 256){
    size_t idx = (size_t)strip * 2048 + i;
    float v = a[idx] + gate[idx] * LB[i];
    a[idx] = v;
    LB[i] = v;
    if (LAST){ int r = i >> 7, c = i & 127; X[r * 136 + c] = f2b(v); }
  }
  __syncthreads();
  if (!LAST){
    int r = threadIdx.x >> 4, s = threadIdx.x & 15;
    float sum = 0.f, sq = 0.f;
#pragma unroll
    for (int j = 0; j < 8; ++j){ float v = LB[r * 128 + s * 8 + j]; sum += v; sq += v * v; }
#pragma unroll
    for (int m = 1; m < 16; m <<= 1){ sum += __shfl_xor(sum, m); sq += __shfl_xor(sq, m); }
    float mu = sum * (1.f / 128.f);
    float var = sq * (1.f / 128.f) - mu * mu;
    float rs = rsqrtf(var + 1e-5f);
#pragma unroll
    for (int j = 0; j < 8; ++j){
      int c = s * 8 + j;
      lnA[(size_t)(strip * 16 + r) * 128 + c] = (LB[r * 128 + c] - mu) * rs;
    }
  } else {
    // atom_out = relu(a_bf16 @ W_tok^T)
    gemm_strip<384, 128, 136>(X, tokW, LB);
    __syncthreads();
    const size_t base = (size_t)strip * 16 * 384;
    for (int i = threadIdx.x; i < 16 * 384; i += 256) atom_out[base + i] = fmaxf(LB[i], 0.f);
  }
}

// ---------------------------------------------------------------- LN(c) + relu -> ph/pw projections
__global__ __launch_bounds__(256) void k_ln_phpw(const float* __restrict__ c, float* __restrict__ lnA,
                                                 u16* __restrict__ slnb, const float* __restrict__ Wph,
                                                 const float* __restrict__ Wpw, float* __restrict__ ph,
                                                 float* __restrict__ pw){
  __shared__ float rs[4][128];
  const int wave = threadIdx.x >> 6, lane = threadIdx.x & 63;
  const int row = blockIdx.x * 4 + wave;
  const float* cr = c + (size_t)row * 128;
  float2 v = *(const float2*)(cr + lane * 2);
  float sum = v.x + v.y, sq = v.x * v.x + v.y * v.y;
#pragma unroll
  for (int m = 1; m < 64; m <<= 1){ sum += __shfl_xor(sum, m); sq += __shfl_xor(sq, m); }
  float mu = sum * (1.f / 128.f);
  float var = sq * (1.f / 128.f) - mu * mu;
  float r = rsqrtf(var + 1e-5f);
  float s0 = (v.x - mu) * r, s1 = (v.y - mu) * r;
  size_t base = (size_t)row * 128 + lane * 2;
  lnA[base] = s0; lnA[base + 1] = s1;
  slnb[base] = f2b(s0); slnb[base + 1] = f2b(s1);
  rs[wave][lane * 2] = fmaxf(s0, 0.f); rs[wave][lane * 2 + 1] = fmaxf(s1, 0.f);
  __syncthreads();
  int h = lane & 15, part = lane >> 4;
  float acch = 0.f, accw = 0.f;
#pragma unroll
  for (int k = 0; k < 32; ++k){
    int kk = part * 32 + k;
    float rv = rs[wave][kk];
    acch += rv * Wph[h * 128 + kk];
    accw += rv * Wpw[h * 128 + kk];
  }
  acch += __shfl_xor(acch, 16); acch += __shfl_xor(acch, 32);
  accw += __shfl_xor(accw, 16); accw += __shfl_xor(accw, 32);
  if (lane < 16){
    ph[(size_t)row * 16 + h] = acch;
    pw[(size_t)row * 16 + h] = accw;
  }
}

// ---------------------------------------------------------------- pair-bias MLP v4: all-MFMA, zero shuffles
__global__ __launch_bounds__(256) void k_pb(const float* __restrict__ ph, const float* __restrict__ pw,
                                            const float* __restrict__ W1, const float* __restrict__ W2,
                                            const float* __restrict__ lnw, const float* __restrict__ lnb,
                                            const float* __restrict__ pbw, float* __restrict__ bias){
  __shared__ __align__(16) u16 mt[4][16 * 24];
  __shared__ __align__(16) u16 vt[4][16 * 24];
  const int t = threadIdx.x;
  const int lane = t & 63, wave = t >> 6;
  const int rr = lane & 15, grp = lane >> 4;
  const int b = blockIdx.x >> 3, qg = blockIdx.x & 7;
  const int q = qg * 4 + wave;
  const int qa = b * 32 + q;

  bf8 wf1 = {0,0,0,0,0,0,0,0}, wf2 = {0,0,0,0,0,0,0,0};
  bf8 bproj = {0,0,0,0,0,0,0,0}, bones = {0,0,0,0,0,0,0,0};
  if (grp < 2){
#pragma unroll
    for (int j = 0; j < 8; ++j){
      wf1[j] = (short)f2b(W1[rr * 16 + grp * 8 + j]);
      wf2[j] = (short)f2b(W2[rr * 16 + grp * 8 + j]);
      bones[j] = (short)0x3F80;
    }
    if (rr < 4){
#pragma unroll
      for (int j = 0; j < 8; ++j)
        bproj[j] = (short)f2b(pbw[rr * 16 + grp * 8 + j] * lnw[grp * 8 + j]);
    }
  }
  float w2s_r = 0.f, bb_r = 0.f;
  if (rr < 4){
#pragma unroll
    for (int cc = 0; cc < 16; ++cc){
      float pv = pbw[rr * 16 + cc];
      w2s_r += pv * lnw[cc];
      bb_r  += pv * lnb[cc];
    }
  }
  const float* phq = ph + (size_t)qa * 16;
  float pha[8];
  if (grp < 2){
#pragma unroll
    for (int j = 0; j < 8; ++j) pha[j] = phq[grp * 8 + j];
  }
  const float ph_r = phq[rr];
  u16* mw = &mt[wave][0];
  u16* vw = &vt[wave][0];

  for (int kt = 0; kt < 8; ++kt){
    const int k0 = kt * 16;
    bf8 af = {0,0,0,0,0,0,0,0};
    if (grp < 2){
      int winA = b * 32 + k0 + rr - 48;
      int kaA = iclamp(winA, 0, NATOMS - 1);
      const float* pwr = pw + (size_t)kaA * 16 + grp * 8;
#pragma unroll
      for (int j = 0; j < 8; ++j) af[j] = (short)f2b(fmaxf(pha[j] + pwr[j], 0.f));
    }
    f4 c1 = mfma16(af, wf1, f4zero());
#pragma unroll
    for (int r = 0; r < 4; ++r)
      mw[(grp * 4 + r) * 24 + rr] = f2b(fmaxf(c1[r], 0.f));
    lds_fence();
    bf8 mf = {0,0,0,0,0,0,0,0};
    if (grp < 2) mf = *(const bf8*)(mw + rr * 24 + grp * 8);
    f4 c2 = mfma16(mf, wf2, f4zero());
#pragma unroll
    for (int r = 0; r < 4; ++r){
      int win = b * 32 + k0 + grp * 4 + r - 48;
      int ka = iclamp(win, 0, NATOMS - 1);
      float v = c2[r] + ph_r + pw[(size_t)ka * 16 + rr];
      vw[(grp * 4 + r) * 24 + rr] = f2b(v);
    }
    lds_fence();
    bf8 vf = {0,0,0,0,0,0,0,0}, vf2 = {0,0,0,0,0,0,0,0};
    if (grp < 2){
      vf = *(const bf8*)(vw + rr * 24 + grp * 8);
#pragma unroll
      for (int j = 0; j < 8; ++j){
        float x = b2f((u16)vf[j]);
        union { float f; unsigned u; } s; s.f = x * x;
        vf2[j] = (short)(u16)(s.u >> 16);
      }
    }
    f4 T1 = mfma16(vf, bproj, f4zero());
    f4 T2 = mfma16(vf, bones, f4zero());
    f4 T3 = mfma16(vf2, bones, f4zero());
    if (rr < 4){
      float4 o;
      float ov[4];
#pragma unroll
      for (int r = 0; r < 4; ++r){
        int win = b * 32 + k0 + grp * 4 + r - 48;
        bool valid = (win >= 0) && (win < NATOMS);
        float S = T2[r], Q = T3[r], d = T1[r];
        float mu = S * (1.f / 16.f);
        float var = Q * (1.f / 16.f) - mu * mu;
        float rq = rsqrtf(var + 1e-5f);
        ov[r] = rq * (d - mu * w2s_r) + bb_r + (valid ? 0.f : -1e9f);
      }
      o.x = ov[0]; o.y = ov[1]; o.z = ov[2]; o.w = ov[3];
      *(float4*)(bias + ((size_t)((b * 4 + rr) * 32) + q) * 128 + k0 + grp * 4) = o;
    }
  }
}

// ---------------------------------------------------------------- block attention + out-proj + residual + row-LN
__global__ __launch_bounds__(256) void k_attn(const u16* __restrict__ qkv, const float* __restrict__ bias,
                                              const u16* __restrict__ outw, const float* __restrict__ outb,
                                              float* __restrict__ a, float* __restrict__ lnA){
  __shared__ u16 VT[128][136];
  __shared__ u16 P[4][32 * 136];
  __shared__ u16 O[32][136];
  __shared__ float aL[32][128];
  const int t = threadIdx.x;
  const int lane = t & 63, wave = t >> 6;
  const int b = blockIdx.x;
  const int rr = lane & 15, grp = lane >> 4;

  for (int i = 0; i < 8; ++i){
    int s = t + 256 * i;
    int ka = s & 127, d0 = (s >> 7) * 8;
    int win = b * 32 + ka - 48;
    int src = iclamp(win, 0, NATOMS - 1);
    bf8 v = *(const bf8*)(qkv + (size_t)src * 384 + 256 + d0);
#pragma unroll
    for (int j = 0; j < 8; ++j) VT[d0 + j][ka] = (u16)v[j];
  }
  __syncthreads();

  const int h = wave;
  bf8 kfr[8];
#pragma unroll
  for (int kt = 0; kt < 8; ++kt){
    int ka = kt * 16 + rr;
    int win = b * 32 + ka - 48;
    int src = iclamp(win, 0, NATOMS - 1);
    kfr[kt] = *(const bf8*)(qkv + (size_t)src * 384 + 128 + h * 32 + grp * 8);
  }
  f4 S[2][8];
#pragma unroll
  for (int qt = 0; qt < 2; ++qt){
    bf8 qf = *(const bf8*)(qkv + (size_t)(b * 32 + qt * 16 + rr) * 384 + h * 32 + grp * 8);
#pragma unroll
    for (int kt = 0; kt < 8; ++kt){
      S[qt][kt] = f4zero();
      S[qt][kt] = mfma16(qf, kfr[kt], S[qt][kt]);
    }
  }
  const float* brow = bias + (size_t)((b * 4 + h) * 32) * 128;
#pragma unroll
  for (int qt = 0; qt < 2; ++qt){
#pragma unroll
    for (int r = 0; r < 4; ++r){
      int q = qt * 16 + grp * 4 + r;
      float vals[8];
      float mx = -1e30f;
#pragma unroll
      for (int kt = 0; kt < 8; ++kt){
        float v = S[qt][kt][r] + brow[q * 128 + kt * 16 + rr];
        vals[kt] = v;
        mx = fmaxf(mx, v);
      }
#pragma unroll
      for (int m = 1; m < 16; m <<= 1) mx = fmaxf(mx, __shfl_xor(mx, m));
      float sum = 0.f;
#pragma unroll
      for (int kt = 0; kt < 8; ++kt){ vals[kt] = __expf(vals[kt] - mx); sum += vals[kt]; }
#pragma unroll
      for (int m = 1; m < 16; m <<= 1) sum += __shfl_xor(sum, m);
      float inv = 1.f / sum;
#pragma unroll
      for (int kt = 0; kt < 8; ++kt)
        P[h][q * 136 + kt * 16 + rr] = f2b(vals[kt] * inv);
    }
  }
  __syncthreads();
  f4 oacc[2][2];
#pragma unroll
  for (int qt = 0; qt < 2; ++qt)
#pragma unroll
    for (int dt = 0; dt < 2; ++dt) oacc[qt][dt] = f4zero();
#pragma unroll
  for (int kc = 0; kc < 4; ++kc){
#pragma unroll
    for (int qt = 0; qt < 2; ++qt){
      bf8 pa = *(const bf8*)(&P[h][(qt * 16 + rr) * 136 + kc * 32 + grp * 8]);
#pragma unroll
      for (int dt = 0; dt < 2; ++dt){
        bf8 vb = *(const bf8*)(&VT[h * 32 + dt * 16 + rr][kc * 32 + grp * 8]);
        oacc[qt][dt] = mfma16(pa, vb, oacc[qt][dt]);
      }
    }
  }
#pragma unroll
  for (int qt = 0; qt < 2; ++qt)
#pragma unroll
    for (int dt = 0; dt < 2; ++dt)
#pragma unroll
      for (int r = 0; r < 4; ++r)
        O[qt * 16 + grp * 4 + r][h * 32 + dt * 16 + rr] = f2b(oacc[qt][dt][r]);
  __syncthreads();
  f4 pacc[2][2];
#pragma unroll
  for (int qt = 0; qt < 2; ++qt)
#pragma unroll
    for (int ct = 0; ct < 2; ++ct) pacc[qt][ct] = f4zero();
#pragma unroll
  for (int kc = 0; kc < 4; ++kc){
    bf8 a0 = *(const bf8*)(&O[rr][kc * 32 + grp * 8]);
    bf8 a1 = *(const bf8*)(&O[16 + rr][kc * 32 + grp * 8]);
#pragma unroll
    for (int ct = 0; ct < 2; ++ct){
      bf8 wf = *(const bf8*)(outw + (size_t)(wave * 32 + ct * 16 + rr) * 128 + kc * 32 + grp * 8);
      pacc[0][ct] = mfma16(a0, wf, pacc[0][ct]);
      pacc[1][ct] = mfma16(a1, wf, pacc[1][ct]);
    }
  }
#pragma unroll
  for (int qt = 0; qt < 2; ++qt)
#pragma unroll
    for (int ct = 0; ct < 2; ++ct)
#pragma unroll
      for (int r = 0; r < 4; ++r){
        int q = qt * 16 + grp * 4 + r;
        int col = wave * 32 + ct * 16 + rr;
        size_t idx = (size_t)(b * 32 + q) * 128 + col;
        float v = a[idx] + pacc[qt][ct][r] + outb[col];
        a[idx] = v;
        aL[q][col] = v;
      }
  __syncthreads();
  {
    int r = t >> 3, s8 = t & 7;
    float sum = 0.f, sq = 0.f;
#pragma unroll
    for (int j = 0; j < 16; ++j){ float v = aL[r][s8 * 16 + j]; sum += v; sq += v * v; }
#pragma unroll
    for (int m = 1; m < 8; m <<= 1){ sum += __shfl_xor(sum, m); sq += __shfl_xor(sq, m); }
    float mu = sum * (1.f / 128.f);
    float var = sq * (1.f / 128.f) - mu * mu;
    float rs = rsqrtf(var + 1e-5f);
#pragma unroll
    for (int j = 0; j < 16; ++j){
      int c = s8 * 16 + j;
      lnA[(size_t)(b * 32 + r) * 128 + c] = (aL[r][c] - mu) * rs;
    }
  }
}

// ---------------------------------------------------------------- segment mean (atoms -> tokens)
__device__ __forceinline__ int lbound(const int* __restrict__ arr, int n, int v){
  int lo = 0, hi = n;
  while (lo < hi){ int mid = (lo + hi) >> 1; if (arr[mid] < v) lo = mid + 1; else hi = mid; }
  return lo;
}

__global__ __launch_bounds__(256) void k_segmean(const float* __restrict__ atom_out,
                                                 const int* __restrict__ a2t, u16* __restrict__ tokbf){
  const int tok = blockIdx.x;
  __shared__ int lo_s, hi_s;
  if (threadIdx.x == 0){
    lo_s = lbound(a2t, NATOMS, tok);
    hi_s = lbound(a2t, NATOMS, tok + 1);
  }
  __syncthreads();
  int lo = lo_s, hi = hi_s;
  float inv = 1.f / fmaxf((float)(hi - lo), 1.f);
  for (int c = threadIdx.x; c < 384; c += 256){
    float s = 0.f;
    for (int aa = lo; aa < hi; ++aa) s += atom_out[(size_t)aa * 384 + c];
    tokbf[(size_t)tok * 384 + c] = f2b(s * inv);
  }
}

// ---------------------------------------------------------------- fused token head: trunk|struct|outer (catW 1024 rows)
__global__ __launch_bounds__(256) void k_tok(const u16* __restrict__ tok, const u16* __restrict__ catW,
                                             float* __restrict__ s_trunk, float* __restrict__ s_struct,
                                             float* __restrict__ u_f){
  __shared__ float LB[16 * 1024];
  const int strip = blockIdx.x;
  gemm_strip<1024, 384>(tok + (size_t)strip * 16 * 384, catW, LB);
  __syncthreads();
  for (int i = threadIdx.x; i < 16 * 1024; i += 256){
    int r = i >> 10, c = i & 1023;
    int row = strip * 16 + r;
    float v = LB[i];
    if (c < 384) s_trunk[(size_t)row * 384 + c] = v;
    else if (c < 768) s_struct[(size_t)row * 384 + (c - 384)] = v;
    else u_f[(size_t)row * 256 + (c - 768)] = v;
  }
}

// ---------------------------------------------------------------- pair head v2: MFMA GEMM (K=32) + u_i + u_j
__global__ __launch_bounds__(256) void k_pair(const float* __restrict__ tpf, const float* __restrict__ Wp,
                                              const float* __restrict__ u, float* __restrict__ out){
  const int lane = threadIdx.x & 63, wave = threadIdx.x >> 6;
  const int rr = lane & 15, grp = lane >> 4;
  const int pairbase = blockIdx.x * 64 + wave * 16;
  const int i = (blockIdx.x * 64) >> 9;
  bf8 af;
  {
    const float* tr = tpf + (size_t)(pairbase + rr) * 32 + grp * 8;
#pragma unroll
    for (int j = 0; j < 8; ++j) af[j] = (short)f2b(tr[j]);
  }
  f4 acc[8];
#pragma unroll
  for (int t = 0; t < 8; ++t){
    bf8 bf;
    const float* wr = Wp + (size_t)(t * 16 + rr) * 32 + grp * 8;
#pragma unroll
    for (int j = 0; j < 8; ++j) bf[j] = (short)f2b(wr[j]);
    acc[t] = mfma16(af, bf, f4zero());
  }
  const float* ui = u + (size_t)i * 256;
#pragma unroll
  for (int t = 0; t < 8; ++t){
    int c = t * 16 + rr;
    float uic = ui[c];
#pragma unroll
    for (int r = 0; r < 4; ++r){
      int p = pairbase + grp * 4 + r;
      int j = p & 511;
      out[(size_t)p * 128 + c] = acc[t][r] + uic + u[(size_t)j * 256 + 128 + c];
    }
  }
}

// ================================================================ host
extern "C" void kernel_launch(void* const* d_in, const int* in_sizes, int n_in,
                              void* d_out, int out_size, void* d_ws, size_t ws_size,
                              hipStream_t stream){
  (void)in_sizes; (void)n_in; (void)out_size; (void)ws_size;
  const float* atom_feats = (const float*)d_in[0];
  const float* tpf        = (const float*)d_in[1];
  const float* W_cond     = (const float*)d_in[2];
  const float* W_ph       = (const float*)d_in[3];
  const float* W_pw       = (const float*)d_in[4];
  const float* W_mlp1     = (const float*)d_in[5];
  const float* W_mlp2     = (const float*)d_in[6];
  const float* pb_ln_w    = (const float*)d_in[7];
  const float* pb_ln_b    = (const float*)d_in[8];
  const float* pb_w       = (const float*)d_in[9];
  const float* sln_w      = (const float*)d_in[10];
  const float* qkv_w      = (const float*)d_in[11];
  const float* q_bias     = (const float*)d_in[12];
  const float* out_w      = (const float*)d_in[13];
  const float* out_b      = (const float*)d_in[14];
  const float* ada_w      = (const float*)d_in[15];
  const float* ta_w       = (const float*)d_in[16];
  const float* tb_w       = (const float*)d_in[17];
  const float* gate_w     = (const float*)d_in[18];
  const float* gate_b     = (const float*)d_in[19];
  const float* W_tok      = (const float*)d_in[20];
  const float* W_trunk    = (const float*)d_in[21];
  const float* W_struct   = (const float*)d_in[22];
  const float* W_pairin   = (const float*)d_in[23];
  const float* W_outer    = (const float*)d_in[24];
  const int*   a2t        = (const int*)d_in[28];

  char* wsb = (char*)d_ws;
  size_t off = 0;
  auto alc = [&](size_t bytes) -> void* {
    void* r = wsb + off;
    off = (off + bytes + 255) & ~(size_t)255;
    return r;
  };

  u16* af_bf     = (u16*)alc((size_t)NATOMS * 128 * 2);
  u16* wcond_bf  = (u16*)alc(16384 * 2);
  u16* sln_bfw   = (u16*)alc(98304 * 2);
  u16* qkv_bfw   = (u16*)alc(147456 * 2);
  u16* out_bfw   = (u16*)alc(49152 * 2);
  u16* ada_bfw   = (u16*)alc(98304 * 2);
  u16* ta_bfw    = (u16*)alc(196608 * 2);
  u16* tb_bfw    = (u16*)alc(98304 * 2);
  u16* gate_bfw  = (u16*)alc(49152 * 2);
  u16* tok_bfw   = (u16*)alc(49152 * 2);
  // NOTE: trunk/struct/outer allocated contiguously (sizes are 256B multiples)
  // -> used as one concatenated [1024][384] weight for k_tok.
  u16* trunk_bfw = (u16*)alc(147456 * 2);
  u16* struct_bfw= (u16*)alc(147456 * 2);
  u16* outer_bfw = (u16*)alc(98304 * 2);
  float* a_f     = (float*)alc((size_t)NATOMS * 128 * 4);
  float* lnA     = (float*)alc((size_t)NATOMS * 128 * 4);
  u16* sln_bf    = (u16*)alc((size_t)NATOMS * 128 * 2);
  u16* qkv_bf    = (u16*)alc((size_t)NATOMS * 384 * 2);
  float* gate_f  = (float*)alc((size_t)NATOMS * 128 * 4);
  float* ph      = (float*)alc((size_t)NATOMS * 16 * 4);
  float* pw      = (float*)alc((size_t)NATOMS * 16 * 4);
  float* bias    = (float*)alc((size_t)NBLK * 4 * 32 * 128 * 4);
  float* atom_out= bias; // alias: bias dead after layer-2 attention
  u16* tok_bf    = (u16*)alc(512 * 384 * 2);
  float* u_f     = (float*)alc(512 * 256 * 4);

  float* s_trunk  = (float*)d_out;
  float* s_struct = s_trunk + 512 * 384;
  float* pair_out = s_struct + 512 * 384;

  CvtArgs ca;
  const float* srcs[13] = {atom_feats, W_cond, sln_w, qkv_w, out_w, ada_w, ta_w, tb_w,
                           gate_w, W_tok, W_trunk, W_struct, W_outer};
  u16* dsts[13] = {af_bf, wcond_bf, sln_bfw, qkv_bfw, out_bfw, ada_bfw, ta_bfw, tb_bfw,
                   gate_bfw, tok_bfw, trunk_bfw, struct_bfw, outer_bfw};
  int n4s[13] = {NATOMS * 128 / 4, 4096, 24576, 36864, 12288, 24576, 49152, 24576,
                 12288, 12288, 36864, 36864, 24576};
  for (int s = 0; s < 13; ++s){ ca.src[s] = srcs[s]; ca.dst[s] = dsts[s]; ca.n4[s] = n4s[s]; }
  k_convert<<<512, 256, 0, stream>>>(ca);

  k_gemm_f32<128, 128><<<736, 256, 0, stream>>>(af_bf, wcond_bf, a_f);
  k_ln_phpw<<<2944, 256, 0, stream>>>(a_f, lnA, sln_bf, W_ph, W_pw, ph, pw);
  k_pb<<<NBLK * 8, 256, 0, stream>>>(ph, pw, W_mlp1, W_mlp2, pb_ln_w, pb_ln_b, pb_w, bias);

  for (int l = 0; l < 3; ++l){
    const u16* slnW  = sln_bfw  + (size_t)l * 256 * 128;
    const u16* qkvW  = qkv_bfw  + (size_t)l * 384 * 128;
    const u16* outW  = out_bfw  + (size_t)l * 128 * 128;
    const u16* adaW  = ada_bfw  + (size_t)l * 256 * 128;
    const u16* taW   = ta_bfw   + (size_t)l * 512 * 128;
    const u16* tbW   = tb_bfw   + (size_t)l * 128 * 256;
    const u16* gateW = gate_bfw + (size_t)l * 128 * 128;
    k_pre<<<736, 256, 0, stream>>>(sln_bf, lnA, slnW, gateW, qkvW,
                                   q_bias + l * 128, gate_b + l * 128, qkv_bf, gate_f);
    k_attn<<<NBLK, 256, 0, stream>>>(qkv_bf, bias, outW, out_b + l * 128, a_f, lnA);
    if (l < 2)
      k_post<0><<<736, 256, 0, stream>>>(sln_bf, lnA, a_f, gate_f, adaW, taW, tbW,
                                         tok_bfw, atom_out);
    else
      k_post<1><<<736, 256, 0, stream>>>(sln_bf, lnA, a_f, gate_f, adaW, taW, tbW,
                                         tok_bfw, atom_out);
  }

  k_segmean<<<512, 256, 0, stream>>>(atom_out, a2t, tok_bf);
  k_tok<<<32, 256, 0, stream>>>(tok_bf, trunk_bfw, s_trunk, s_struct, u_f);
  k_pair<<<4096, 256, 0, stream>>>(tpf, W_pairin, u_f, pair_out);
}

// Round 7
// 390.591 us; speedup vs baseline: 1.5943x; 1.1109x over previous
//
#include <hip/hip_runtime.h>
#include <cstddef>

typedef unsigned short u16;
typedef __attribute__((ext_vector_type(8))) short bf8;   // 8 x bf16 (4 VGPRs)
typedef __attribute__((ext_vector_type(4))) float f4;
typedef __attribute__((ext_vector_type(4))) unsigned short us4;

#define NATOMS 11776
#define NBLK   368

__device__ __forceinline__ u16 f2b(float x){
  union { float f; unsigned u; } v; v.f = x;
  unsigned r = v.u + 0x7fffu + ((v.u >> 16) & 1u);
  return (u16)(r >> 16);
}
__device__ __forceinline__ float b2f(u16 x){
  union { unsigned u; float f; } v; v.u = ((unsigned)x) << 16;
  return v.f;
}
__device__ __forceinline__ f4 f4zero(){ f4 z = {0.f,0.f,0.f,0.f}; return z; }
__device__ __forceinline__ f4 mfma16(bf8 a, bf8 b, f4 c){
  return __builtin_amdgcn_mfma_f32_16x16x32_bf16(a, b, c, 0, 0, 0);
}
__device__ __forceinline__ int iclamp(int v, int lo, int hi){ return v < lo ? lo : (v > hi ? hi : v); }
__device__ __forceinline__ void lds_fence(){
  asm volatile("s_waitcnt lgkmcnt(0)" ::: "memory");
  __builtin_amdgcn_sched_barrier(0);
}
__device__ __forceinline__ bf8 cvt_f32x8(const float* __restrict__ p){
  float4 a = *(const float4*)p, b = *(const float4*)(p + 4);
  bf8 o;
  o[0] = (short)f2b(a.x); o[1] = (short)f2b(a.y); o[2] = (short)f2b(a.z); o[3] = (short)f2b(a.w);
  o[4] = (short)f2b(b.x); o[5] = (short)f2b(b.y); o[6] = (short)f2b(b.z); o[7] = (short)f2b(b.w);
  return o;
}

// ---------------------------------------------------------------- convert fp32 -> bf16 (weights only)
struct CvtArgs {
  const float* src[11];
  u16* dst[11];
  int n4[11];
};

__global__ __launch_bounds__(256) void k_convert(CvtArgs a){
  int stride = gridDim.x * 256;
  int tid = blockIdx.x * 256 + threadIdx.x;
  for (int s = 0; s < 11; ++s){
    const float4* src = (const float4*)a.src[s];
    us4* dst = (us4*)a.dst[s];
    int n = a.n4[s];
    for (int i = tid; i < n; i += stride){
      float4 v = src[i];
      us4 o;
      o.x = f2b(v.x); o.y = f2b(v.y); o.z = f2b(v.z); o.w = f2b(v.w);
      dst[i] = o;
    }
  }
}

// ---------------------------------------------------------------- generic 16-row MFMA strip GEMM
// A may live in global or LDS (inlined -> addrspace inferred). LDA in u16 elems.
template<int N, int K, int LDA = K>
__device__ __forceinline__ void gemm_strip(const u16* __restrict__ A, const u16* __restrict__ W, float* L){
  constexpr int CPW = N / 4;       // cols per wave
  constexpr int T = CPW / 16;      // 16x16 tiles per wave
  const int lane = threadIdx.x & 63;
  const int wave = threadIdx.x >> 6;
  const int rr = lane & 15, grp = lane >> 4;
  f4 acc[T];
#pragma unroll
  for (int t = 0; t < T; ++t) acc[t] = f4zero();
#pragma unroll
  for (int kc = 0; kc < K / 32; ++kc){
    bf8 af = *(const bf8*)(A + rr * LDA + kc * 32 + grp * 8);
#pragma unroll
    for (int t = 0; t < T; ++t){
      const u16* wp = W + (size_t)(wave * CPW + t * 16 + rr) * K + kc * 32 + grp * 8;
      acc[t] = mfma16(af, *(const bf8*)wp, acc[t]);
    }
  }
#pragma unroll
  for (int t = 0; t < T; ++t)
#pragma unroll
    for (int r = 0; r < 4; ++r)
      L[(grp * 4 + r) * N + wave * CPW + t * 16 + rr] = acc[t][r];
}

// ---------------------------------------------------------------- fused: c = af@Wc^T, LN, ph/pw (fp32 inputs, in-reg cvt)
__global__ __launch_bounds__(256) void k_cond(const float* __restrict__ af, const float* __restrict__ Wc,
                                              const float* __restrict__ Wph, const float* __restrict__ Wpw,
                                              float* __restrict__ a_f, float* __restrict__ lnA,
                                              u16* __restrict__ sln_bf, float* __restrict__ ph,
                                              float* __restrict__ pw){
  __shared__ float LB[16 * 128];
  __shared__ __align__(16) u16 X[16 * 136];   // relu(s_ln) bf16
  const int strip = blockIdx.x;
  const int lane = threadIdx.x & 63, wave = threadIdx.x >> 6;
  const int rr = lane & 15, grp = lane >> 4;
  // GEMM: 16x128 = af16 @ Wc^T (both fp32 -> bf16 in register)
  {
    f4 acc[2];
    acc[0] = f4zero(); acc[1] = f4zero();
#pragma unroll
    for (int kc = 0; kc < 4; ++kc){
      bf8 afr = cvt_f32x8(af + (size_t)(strip * 16 + rr) * 128 + kc * 32 + grp * 8);
#pragma unroll
      for (int t = 0; t < 2; ++t){
        bf8 bfr = cvt_f32x8(Wc + (size_t)(wave * 32 + t * 16 + rr) * 128 + kc * 32 + grp * 8);
        acc[t] = mfma16(afr, bfr, acc[t]);
      }
    }
#pragma unroll
    for (int t = 0; t < 2; ++t)
#pragma unroll
      for (int r = 0; r < 4; ++r)
        LB[(grp * 4 + r) * 128 + wave * 32 + t * 16 + rr] = acc[t][r];
  }
  __syncthreads();
  // a_f = c; row-LN -> lnA, sln_bf; relu -> X
  {
    int r = threadIdx.x >> 4, s = threadIdx.x & 15;
    float sum = 0.f, sq = 0.f;
#pragma unroll
    for (int j = 0; j < 8; ++j){ float v = LB[r * 128 + s * 8 + j]; sum += v; sq += v * v; }
#pragma unroll
    for (int m = 1; m < 16; m <<= 1){ sum += __shfl_xor(sum, m); sq += __shfl_xor(sq, m); }
    float mu = sum * (1.f / 128.f);
    float var = sq * (1.f / 128.f) - mu * mu;
    float rs = rsqrtf(var + 1e-5f);
#pragma unroll
    for (int j = 0; j < 8; ++j){
      int c = s * 8 + j;
      float v = LB[r * 128 + c];
      size_t idx = (size_t)(strip * 16 + r) * 128 + c;
      a_f[idx] = v;
      float ln = (v - mu) * rs;
      lnA[idx] = ln;
      sln_bf[idx] = f2b(ln);
      X[r * 136 + c] = f2b(fmaxf(ln, 0.f));
    }
  }
  __syncthreads();
  // ph/pw: 16x16 each, waves 0/1
  if (wave < 2){
    const float* Wsel = wave ? Wpw : Wph;
    f4 acc = f4zero();
#pragma unroll
    for (int kc = 0; kc < 4; ++kc){
      bf8 afr = *(const bf8*)(&X[rr * 136 + kc * 32 + grp * 8]);
      bf8 bfr = cvt_f32x8(Wsel + (size_t)rr * 128 + kc * 32 + grp * 8);
      acc = mfma16(afr, bfr, acc);
    }
    float* out = wave ? pw : ph;
#pragma unroll
    for (int r = 0; r < 4; ++r)
      out[(size_t)(strip * 16 + grp * 4 + r) * 16 + rr] = acc[r];
  }
}

// ---------------------------------------------------------------- fused pre-attention: sln->x->qkv
__global__ __launch_bounds__(256) void k_pre(const u16* __restrict__ sln, const float* __restrict__ lnA,
                                             const u16* __restrict__ slnW, const u16* __restrict__ qkvW,
                                             const float* __restrict__ qb, u16* __restrict__ qkv_out){
  __shared__ float LB[16 * 384];
  __shared__ __align__(16) u16 X[16 * 136];
  const int strip = blockIdx.x;
  const u16* Ag = sln + (size_t)strip * 2048;
  gemm_strip<256, 128>(Ag, slnW, LB);
  __syncthreads();
  for (int i = threadIdx.x; i < 2048; i += 256){
    int r = i >> 7, c = i & 127;
    float g1 = LB[r * 256 + c], g2 = LB[r * 256 + 128 + c];
    float s = 1.f / (1.f + __expf(-g1));
    X[r * 136 + c] = f2b(s * lnA[(size_t)(strip * 16 + r) * 128 + c] + g2);
  }
  __syncthreads();
  gemm_strip<384, 128, 136>(X, qkvW, LB);
  __syncthreads();
  const float scale = 0.17677669529663687f; // 1/sqrt(32)
  for (int i = threadIdx.x; i < 16 * 384; i += 256){
    int r = i / 384, c = i - r * 384;
    float v = LB[i];
    if (c < 128) v = (v + qb[c]) * scale;
    qkv_out[(size_t)(strip * 16 + r) * 384 + c] = f2b(v);
  }
}

// ---------------------------------------------------------------- fused post-attention: gate + ada->x2->ta->glu->tb->residual(+LN | +tok relu-GEMM)
template<int LAST>
__global__ __launch_bounds__(256) void k_post(const u16* __restrict__ sln, float* __restrict__ lnA,
                                              float* __restrict__ a,
                                              const u16* __restrict__ gateW, const float* __restrict__ gbias,
                                              const u16* __restrict__ adaW, const u16* __restrict__ taW,
                                              const u16* __restrict__ tbW, const u16* __restrict__ tokW,
                                              float* __restrict__ atom_out){
  __shared__ float LB[16 * 512];
  __shared__ __align__(16) u16 X[16 * 136];
  __shared__ __align__(16) u16 G[16 * 264];
  const int strip = blockIdx.x;
  const u16* Ag = sln + (size_t)strip * 2048;
  // gate -> registers
  float gv[8];
  gemm_strip<128, 128>(Ag, gateW, LB);
  __syncthreads();
#pragma unroll
  for (int ii = 0; ii < 8; ++ii){
    int i = threadIdx.x + 256 * ii;
    int c = i & 127;
    gv[ii] = 1.f / (1.f + __expf(-(LB[i] + gbias[c])));
  }
  __syncthreads();
  gemm_strip<256, 128>(Ag, adaW, LB);
  __syncthreads();
  for (int i = threadIdx.x; i < 2048; i += 256){
    int r = i >> 7, c = i & 127;
    float g1 = LB[r * 256 + c], g2 = LB[r * 256 + 128 + c];
    float s = 1.f / (1.f + __expf(-g1));
    X[r * 136 + c] = f2b(s * lnA[(size_t)(strip * 16 + r) * 128 + c] + g2);
  }
  __syncthreads();
  gemm_strip<512, 128, 136>(X, taW, LB);
  __syncthreads();
  for (int i = threadIdx.x; i < 16 * 256; i += 256){
    int r = i >> 8, c = i & 255;
    float ab1 = LB[r * 512 + c], ab2 = LB[r * 512 + 256 + c];
    G[r * 264 + c] = f2b(ab1 / (1.f + __expf(-ab1)) * ab2);
  }
  __syncthreads();
  gemm_strip<128, 256, 264>(G, tbW, LB);
  __syncthreads();
#pragma unroll
  for (int ii = 0; ii < 8; ++ii){
    int i = threadIdx.x + 256 * ii;
    size_t idx = (size_t)strip * 2048 + i;
    float v = a[idx] + gv[ii] * LB[i];
    a[idx] = v;
    LB[i] = v;
    if (LAST){ int r = i >> 7, c = i & 127; X[r * 136 + c] = f2b(v); }
  }
  __syncthreads();
  if (!LAST){
    int r = threadIdx.x >> 4, s = threadIdx.x & 15;
    float sum = 0.f, sq = 0.f;
#pragma unroll
    for (int j = 0; j < 8; ++j){ float v = LB[r * 128 + s * 8 + j]; sum += v; sq += v * v; }
#pragma unroll
    for (int m = 1; m < 16; m <<= 1){ sum += __shfl_xor(sum, m); sq += __shfl_xor(sq, m); }
    float mu = sum * (1.f / 128.f);
    float var = sq * (1.f / 128.f) - mu * mu;
    float rs = rsqrtf(var + 1e-5f);
#pragma unroll
    for (int j = 0; j < 8; ++j){
      int c = s * 8 + j;
      lnA[(size_t)(strip * 16 + r) * 128 + c] = (LB[r * 128 + c] - mu) * rs;
    }
  } else {
    gemm_strip<384, 128, 136>(X, tokW, LB);
    __syncthreads();
    const size_t base = (size_t)strip * 16 * 384;
    for (int i = threadIdx.x; i < 16 * 384; i += 256) atom_out[base + i] = fmaxf(LB[i], 0.f);
  }
}

// ---------------------------------------------------------------- pair-bias MLP: all-MFMA, zero shuffles
__global__ __launch_bounds__(256) void k_pb(const float* __restrict__ ph, const float* __restrict__ pw,
                                            const float* __restrict__ W1, const float* __restrict__ W2,
                                            const float* __restrict__ lnw, const float* __restrict__ lnb,
                                            const float* __restrict__ pbw, float* __restrict__ bias){
  __shared__ __align__(16) u16 mt[4][16 * 24];
  __shared__ __align__(16) u16 vt[4][16 * 24];
  const int t = threadIdx.x;
  const int lane = t & 63, wave = t >> 6;
  const int rr = lane & 15, grp = lane >> 4;
  const int b = blockIdx.x >> 3, qg = blockIdx.x & 7;
  const int q = qg * 4 + wave;
  const int qa = b * 32 + q;

  bf8 wf1 = {0,0,0,0,0,0,0,0}, wf2 = {0,0,0,0,0,0,0,0};
  bf8 bproj = {0,0,0,0,0,0,0,0}, bones = {0,0,0,0,0,0,0,0};
  if (grp < 2){
#pragma unroll
    for (int j = 0; j < 8; ++j){
      wf1[j] = (short)f2b(W1[rr * 16 + grp * 8 + j]);
      wf2[j] = (short)f2b(W2[rr * 16 + grp * 8 + j]);
      bones[j] = (short)0x3F80;
    }
    if (rr < 4){
#pragma unroll
      for (int j = 0; j < 8; ++j)
        bproj[j] = (short)f2b(pbw[rr * 16 + grp * 8 + j] * lnw[grp * 8 + j]);
    }
  }
  float w2s_r = 0.f, bb_r = 0.f;
  if (rr < 4){
#pragma unroll
    for (int cc = 0; cc < 16; ++cc){
      float pv = pbw[rr * 16 + cc];
      w2s_r += pv * lnw[cc];
      bb_r  += pv * lnb[cc];
    }
  }
  const float* phq = ph + (size_t)qa * 16;
  float pha[8];
  if (grp < 2){
#pragma unroll
    for (int j = 0; j < 8; ++j) pha[j] = phq[grp * 8 + j];
  }
  const float ph_r = phq[rr];
  u16* mw = &mt[wave][0];
  u16* vw = &vt[wave][0];

  for (int kt = 0; kt < 8; ++kt){
    const int k0 = kt * 16;
    bf8 af = {0,0,0,0,0,0,0,0};
    if (grp < 2){
      int winA = b * 32 + k0 + rr - 48;
      int kaA = iclamp(winA, 0, NATOMS - 1);
      const float* pwr = pw + (size_t)kaA * 16 + grp * 8;
#pragma unroll
      for (int j = 0; j < 8; ++j) af[j] = (short)f2b(fmaxf(pha[j] + pwr[j], 0.f));
    }
    f4 c1 = mfma16(af, wf1, f4zero());
#pragma unroll
    for (int r = 0; r < 4; ++r)
      mw[(grp * 4 + r) * 24 + rr] = f2b(fmaxf(c1[r], 0.f));
    lds_fence();
    bf8 mf = {0,0,0,0,0,0,0,0};
    if (grp < 2) mf = *(const bf8*)(mw + rr * 24 + grp * 8);
    f4 c2 = mfma16(mf, wf2, f4zero());
#pragma unroll
    for (int r = 0; r < 4; ++r){
      int win = b * 32 + k0 + grp * 4 + r - 48;
      int ka = iclamp(win, 0, NATOMS - 1);
      float v = c2[r] + ph_r + pw[(size_t)ka * 16 + rr];
      vw[(grp * 4 + r) * 24 + rr] = f2b(v);
    }
    lds_fence();
    bf8 vf = {0,0,0,0,0,0,0,0}, vf2 = {0,0,0,0,0,0,0,0};
    if (grp < 2){
      vf = *(const bf8*)(vw + rr * 24 + grp * 8);
#pragma unroll
      for (int j = 0; j < 8; ++j){
        float x = b2f((u16)vf[j]);
        union { float f; unsigned u; } s; s.f = x * x;
        vf2[j] = (short)(u16)(s.u >> 16);
      }
    }
    f4 T1 = mfma16(vf, bproj, f4zero());
    f4 T2 = mfma16(vf, bones, f4zero());
    f4 T3 = mfma16(vf2, bones, f4zero());
    if (rr < 4){
      float4 o;
      float ov[4];
#pragma unroll
      for (int r = 0; r < 4; ++r){
        int win = b * 32 + k0 + grp * 4 + r - 48;
        bool valid = (win >= 0) && (win < NATOMS);
        float S = T2[r], Q = T3[r], d = T1[r];
        float mu = S * (1.f / 16.f);
        float var = Q * (1.f / 16.f) - mu * mu;
        float rq = rsqrtf(var + 1e-5f);
        ov[r] = rq * (d - mu * w2s_r) + bb_r + (valid ? 0.f : -1e9f);
      }
      o.x = ov[0]; o.y = ov[1]; o.z = ov[2]; o.w = ov[3];
      *(float4*)(bias + ((size_t)((b * 4 + rr) * 32) + q) * 128 + k0 + grp * 4) = o;
    }
  }
}

// ---------------------------------------------------------------- block attention + out-proj + residual + row-LN
// LDS diet: 79.4 KB -> 2 blocks/CU (aL replaced by 1KB partial-sum exchange)
__global__ __launch_bounds__(256) void k_attn(const u16* __restrict__ qkv, const float* __restrict__ bias,
                                              const u16* __restrict__ outw, const float* __restrict__ outb,
                                              float* __restrict__ a, float* __restrict__ lnA){
  __shared__ u16 VT[128][136];
  __shared__ u16 P[4][32 * 136];
  __shared__ u16 O[32][136];
  __shared__ float part2[32][8];   // per-row LN partials: [q][wave*2 + {sum,sq}]
  const int t = threadIdx.x;
  const int lane = t & 63, wave = t >> 6;
  const int b = blockIdx.x;
  const int rr = lane & 15, grp = lane >> 4;

  for (int i = 0; i < 8; ++i){
    int s = t + 256 * i;
    int ka = s & 127, d0 = (s >> 7) * 8;
    int win = b * 32 + ka - 48;
    int src = iclamp(win, 0, NATOMS - 1);
    bf8 v = *(const bf8*)(qkv + (size_t)src * 384 + 256 + d0);
#pragma unroll
    for (int j = 0; j < 8; ++j) VT[d0 + j][ka] = (u16)v[j];
  }
  __syncthreads();

  const int h = wave;
  bf8 kfr[8];
#pragma unroll
  for (int kt = 0; kt < 8; ++kt){
    int ka = kt * 16 + rr;
    int win = b * 32 + ka - 48;
    int src = iclamp(win, 0, NATOMS - 1);
    kfr[kt] = *(const bf8*)(qkv + (size_t)src * 384 + 128 + h * 32 + grp * 8);
  }
  f4 S[2][8];
#pragma unroll
  for (int qt = 0; qt < 2; ++qt){
    bf8 qf = *(const bf8*)(qkv + (size_t)(b * 32 + qt * 16 + rr) * 384 + h * 32 + grp * 8);
#pragma unroll
    for (int kt = 0; kt < 8; ++kt){
      S[qt][kt] = f4zero();
      S[qt][kt] = mfma16(qf, kfr[kt], S[qt][kt]);
    }
  }
  const float* brow = bias + (size_t)((b * 4 + h) * 32) * 128;
#pragma unroll
  for (int qt = 0; qt < 2; ++qt){
#pragma unroll
    for (int r = 0; r < 4; ++r){
      int q = qt * 16 + grp * 4 + r;
      float vals[8];
      float mx = -1e30f;
#pragma unroll
      for (int kt = 0; kt < 8; ++kt){
        float v = S[qt][kt][r] + brow[q * 128 + kt * 16 + rr];
        vals[kt] = v;
        mx = fmaxf(mx, v);
      }
#pragma unroll
      for (int m = 1; m < 16; m <<= 1) mx = fmaxf(mx, __shfl_xor(mx, m));
      float sum = 0.f;
#pragma unroll
      for (int kt = 0; kt < 8; ++kt){ vals[kt] = __expf(vals[kt] - mx); sum += vals[kt]; }
#pragma unroll
      for (int m = 1; m < 16; m <<= 1) sum += __shfl_xor(sum, m);
      float inv = 1.f / sum;
#pragma unroll
      for (int kt = 0; kt < 8; ++kt)
        P[h][q * 136 + kt * 16 + rr] = f2b(vals[kt] * inv);
    }
  }
  __syncthreads();
  f4 oacc[2][2];
#pragma unroll
  for (int qt = 0; qt < 2; ++qt)
#pragma unroll
    for (int dt = 0; dt < 2; ++dt) oacc[qt][dt] = f4zero();
#pragma unroll
  for (int kc = 0; kc < 4; ++kc){
#pragma unroll
    for (int qt = 0; qt < 2; ++qt){
      bf8 pa = *(const bf8*)(&P[h][(qt * 16 + rr) * 136 + kc * 32 + grp * 8]);
#pragma unroll
      for (int dt = 0; dt < 2; ++dt){
        bf8 vb = *(const bf8*)(&VT[h * 32 + dt * 16 + rr][kc * 32 + grp * 8]);
        oacc[qt][dt] = mfma16(pa, vb, oacc[qt][dt]);
      }
    }
  }
#pragma unroll
  for (int qt = 0; qt < 2; ++qt)
#pragma unroll
    for (int dt = 0; dt < 2; ++dt)
#pragma unroll
      for (int r = 0; r < 4; ++r)
        O[qt * 16 + grp * 4 + r][h * 32 + dt * 16 + rr] = f2b(oacc[qt][dt][r]);
  __syncthreads();
  f4 pacc[2][2];
#pragma unroll
  for (int qt = 0; qt < 2; ++qt)
#pragma unroll
    for (int ct = 0; ct < 2; ++ct) pacc[qt][ct] = f4zero();
#pragma unroll
  for (int kc = 0; kc < 4; ++kc){
    bf8 a0 = *(const bf8*)(&O[rr][kc * 32 + grp * 8]);
    bf8 a1 = *(const bf8*)(&O[16 + rr][kc * 32 + grp * 8]);
#pragma unroll
    for (int ct = 0; ct < 2; ++ct){
      bf8 wf = *(const bf8*)(outw + (size_t)(wave * 32 + ct * 16 + rr) * 128 + kc * 32 + grp * 8);
      pacc[0][ct] = mfma16(a0, wf, pacc[0][ct]);
      pacc[1][ct] = mfma16(a1, wf, pacc[1][ct]);
    }
  }
  // residual + partial-sum LN (no full-tile staging)
  float vv[2][2][4];
#pragma unroll
  for (int qt = 0; qt < 2; ++qt)
#pragma unroll
    for (int ct = 0; ct < 2; ++ct)
#pragma unroll
      for (int r = 0; r < 4; ++r){
        int q = qt * 16 + grp * 4 + r;
        int col = wave * 32 + ct * 16 + rr;
        size_t idx = (size_t)(b * 32 + q) * 128 + col;
        float v = a[idx] + pacc[qt][ct][r] + outb[col];
        a[idx] = v;
        vv[qt][ct][r] = v;
      }
#pragma unroll
  for (int qt = 0; qt < 2; ++qt)
#pragma unroll
    for (int r = 0; r < 4; ++r){
      float ps = vv[qt][0][r] + vv[qt][1][r];
      float pq = vv[qt][0][r] * vv[qt][0][r] + vv[qt][1][r] * vv[qt][1][r];
#pragma unroll
      for (int m = 1; m < 16; m <<= 1){ ps += __shfl_xor(ps, m); pq += __shfl_xor(pq, m); }
      if (rr == 0){
        int q = qt * 16 + grp * 4 + r;
        part2[q][wave * 2] = ps;
        part2[q][wave * 2 + 1] = pq;
      }
    }
  __syncthreads();
#pragma unroll
  for (int qt = 0; qt < 2; ++qt)
#pragma unroll
    for (int r = 0; r < 4; ++r){
      int q = qt * 16 + grp * 4 + r;
      f4 p0 = *(const f4*)&part2[q][0];
      f4 p1 = *(const f4*)&part2[q][4];
      float S = p0[0] + p0[2] + p1[0] + p1[2];
      float Q = p0[1] + p0[3] + p1[1] + p1[3];
      float mu = S * (1.f / 128.f);
      float var = Q * (1.f / 128.f) - mu * mu;
      float rs = rsqrtf(var + 1e-5f);
#pragma unroll
      for (int ct = 0; ct < 2; ++ct){
        int col = wave * 32 + ct * 16 + rr;
        lnA[(size_t)(b * 32 + q) * 128 + col] = (vv[qt][ct][r] - mu) * rs;
      }
    }
}

// ---------------------------------------------------------------- segment mean (atoms -> tokens)
__device__ __forceinline__ int lbound(const int* __restrict__ arr, int n, int v){
  int lo = 0, hi = n;
  while (lo < hi){ int mid = (lo + hi) >> 1; if (arr[mid] < v) lo = mid + 1; else hi = mid; }
  return lo;
}

__global__ __launch_bounds__(256) void k_segmean(const float* __restrict__ atom_out,
                                                 const int* __restrict__ a2t, u16* __restrict__ tokbf){
  const int tok = blockIdx.x;
  __shared__ int lo_s, hi_s;
  if (threadIdx.x == 0){
    lo_s = lbound(a2t, NATOMS, tok);
    hi_s = lbound(a2t, NATOMS, tok + 1);
  }
  __syncthreads();
  int lo = lo_s, hi = hi_s;
  float inv = 1.f / fmaxf((float)(hi - lo), 1.f);
  for (int c = threadIdx.x; c < 384; c += 256){
    float s = 0.f;
    for (int aa = lo; aa < hi; ++aa) s += atom_out[(size_t)aa * 384 + c];
    tokbf[(size_t)tok * 384 + c] = f2b(s * inv);
  }
}

// ---------------------------------------------------------------- fused token head: trunk|struct|outer (catW 1024 rows)
__global__ __launch_bounds__(256) void k_tok(const u16* __restrict__ tok, const u16* __restrict__ catW,
                                             float* __restrict__ s_trunk, float* __restrict__ s_struct,
                                             float* __restrict__ u_f){
  __shared__ float LB[16 * 1024];
  const int strip = blockIdx.x;
  gemm_strip<1024, 384>(tok + (size_t)strip * 16 * 384, catW, LB);
  __syncthreads();
  for (int i = threadIdx.x; i < 16 * 1024; i += 256){
    int r = i >> 10, c = i & 1023;
    int row = strip * 16 + r;
    float v = LB[i];
    if (c < 384) s_trunk[(size_t)row * 384 + c] = v;
    else if (c < 768) s_struct[(size_t)row * 384 + (c - 384)] = v;
    else u_f[(size_t)row * 256 + (c - 768)] = v;
  }
}

// ---------------------------------------------------------------- pair head: MFMA GEMM (K=32) + u_i + u_j
__global__ __launch_bounds__(256) void k_pair(const float* __restrict__ tpf, const float* __restrict__ Wp,
                                              const float* __restrict__ u, float* __restrict__ out){
  const int lane = threadIdx.x & 63, wave = threadIdx.x >> 6;
  const int rr = lane & 15, grp = lane >> 4;
  const int pairbase = blockIdx.x * 64 + wave * 16;
  const int i = (blockIdx.x * 64) >> 9;
  bf8 af;
  {
    const float* tr = tpf + (size_t)(pairbase + rr) * 32 + grp * 8;
#pragma unroll
    for (int j = 0; j < 8; ++j) af[j] = (short)f2b(tr[j]);
  }
  f4 acc[8];
#pragma unroll
  for (int t = 0; t < 8; ++t){
    bf8 bf;
    const float* wr = Wp + (size_t)(t * 16 + rr) * 32 + grp * 8;
#pragma unroll
    for (int j = 0; j < 8; ++j) bf[j] = (short)f2b(wr[j]);
    acc[t] = mfma16(af, bf, f4zero());
  }
  const float* ui = u + (size_t)i * 256;
#pragma unroll
  for (int t = 0; t < 8; ++t){
    int c = t * 16 + rr;
    float uic = ui[c];
#pragma unroll
    for (int r = 0; r < 4; ++r){
      int p = pairbase + grp * 4 + r;
      int j = p & 511;
      out[(size_t)p * 128 + c] = acc[t][r] + uic + u[(size_t)j * 256 + 128 + c];
    }
  }
}

// ================================================================ host
extern "C" void kernel_launch(void* const* d_in, const int* in_sizes, int n_in,
                              void* d_out, int out_size, void* d_ws, size_t ws_size,
                              hipStream_t stream){
  (void)in_sizes; (void)n_in; (void)out_size; (void)ws_size;
  const float* atom_feats = (const float*)d_in[0];
  const float* tpf        = (const float*)d_in[1];
  const float* W_cond     = (const float*)d_in[2];
  const float* W_ph       = (const float*)d_in[3];
  const float* W_pw       = (const float*)d_in[4];
  const float* W_mlp1     = (const float*)d_in[5];
  const float* W_mlp2     = (const float*)d_in[6];
  const float* pb_ln_w    = (const float*)d_in[7];
  const float* pb_ln_b    = (const float*)d_in[8];
  const float* pb_w       = (const float*)d_in[9];
  const float* sln_w      = (const float*)d_in[10];
  const float* qkv_w      = (const float*)d_in[11];
  const float* q_bias     = (const float*)d_in[12];
  const float* out_w      = (const float*)d_in[13];
  const float* out_b      = (const float*)d_in[14];
  const float* ada_w      = (const float*)d_in[15];
  const float* ta_w       = (const float*)d_in[16];
  const float* tb_w       = (const float*)d_in[17];
  const float* gate_w     = (const float*)d_in[18];
  const float* gate_b     = (const float*)d_in[19];
  const float* W_tok      = (const float*)d_in[20];
  const float* W_trunk    = (const float*)d_in[21];
  const float* W_struct   = (const float*)d_in[22];
  const float* W_pairin   = (const float*)d_in[23];
  const float* W_outer    = (const float*)d_in[24];
  const int*   a2t        = (const int*)d_in[28];

  char* wsb = (char*)d_ws;
  size_t off = 0;
  auto alc = [&](size_t bytes) -> void* {
    void* r = wsb + off;
    off = (off + bytes + 255) & ~(size_t)255;
    return r;
  };

  u16* sln_bfw   = (u16*)alc(98304 * 2);
  u16* qkv_bfw   = (u16*)alc(147456 * 2);
  u16* out_bfw   = (u16*)alc(49152 * 2);
  u16* ada_bfw   = (u16*)alc(98304 * 2);
  u16* ta_bfw    = (u16*)alc(196608 * 2);
  u16* tb_bfw    = (u16*)alc(98304 * 2);
  u16* gate_bfw  = (u16*)alc(49152 * 2);
  u16* tok_bfw   = (u16*)alc(49152 * 2);
  // trunk/struct/outer contiguous -> one concatenated [1024][384] weight for k_tok
  u16* trunk_bfw = (u16*)alc(147456 * 2);
  u16* struct_bfw= (u16*)alc(147456 * 2);
  u16* outer_bfw = (u16*)alc(98304 * 2);
  float* a_f     = (float*)alc((size_t)NATOMS * 128 * 4);
  float* lnA     = (float*)alc((size_t)NATOMS * 128 * 4);
  u16* sln_bf    = (u16*)alc((size_t)NATOMS * 128 * 2);
  u16* qkv_bf    = (u16*)alc((size_t)NATOMS * 384 * 2);
  float* ph      = (float*)alc((size_t)NATOMS * 16 * 4);
  float* pw      = (float*)alc((size_t)NATOMS * 16 * 4);
  float* bias    = (float*)alc((size_t)NBLK * 4 * 32 * 128 * 4);
  float* atom_out= bias; // alias: bias dead after layer-2 attention
  u16* tok_bf    = (u16*)alc(512 * 384 * 2);
  float* u_f     = (float*)alc(512 * 256 * 4);

  float* s_trunk  = (float*)d_out;
  float* s_struct = s_trunk + 512 * 384;
  float* pair_out = s_struct + 512 * 384;

  CvtArgs ca;
  const float* srcs[11] = {sln_w, qkv_w, out_w, ada_w, ta_w, tb_w, gate_w,
                           W_tok, W_trunk, W_struct, W_outer};
  u16* dsts[11] = {sln_bfw, qkv_bfw, out_bfw, ada_bfw, ta_bfw, tb_bfw, gate_bfw,
                   tok_bfw, trunk_bfw, struct_bfw, outer_bfw};
  int n4s[11] = {24576, 36864, 12288, 24576, 49152, 24576, 12288,
                 12288, 36864, 36864, 24576};
  for (int s = 0; s < 11; ++s){ ca.src[s] = srcs[s]; ca.dst[s] = dsts[s]; ca.n4[s] = n4s[s]; }
  k_convert<<<256, 256, 0, stream>>>(ca);

  k_cond<<<736, 256, 0, stream>>>(atom_feats, W_cond, W_ph, W_pw, a_f, lnA, sln_bf, ph, pw);
  k_pb<<<NBLK * 8, 256, 0, stream>>>(ph, pw, W_mlp1, W_mlp2, pb_ln_w, pb_ln_b, pb_w, bias);

  for (int l = 0; l < 3; ++l){
    const u16* slnW  = sln_bfw  + (size_t)l * 256 * 128;
    const u16* qkvW  = qkv_bfw  + (size_t)l * 384 * 128;
    const u16* outW  = out_bfw  + (size_t)l * 128 * 128;
    const u16* adaW  = ada_bfw  + (size_t)l * 256 * 128;
    const u16* taW   = ta_bfw   + (size_t)l * 512 * 128;
    const u16* tbW   = tb_bfw   + (size_t)l * 128 * 256;
    const u16* gateW = gate_bfw + (size_t)l * 128 * 128;
    k_pre<<<736, 256, 0, stream>>>(sln_bf, lnA, slnW, qkvW, q_bias + l * 128, qkv_bf);
    k_attn<<<NBLK, 256, 0, stream>>>(qkv_bf, bias, outW, out_b + l * 128, a_f, lnA);
    if (l < 2)
      k_post<0><<<736, 256, 0, stream>>>(sln_bf, lnA, a_f, gateW, gate_b + l * 128,
                                         adaW, taW, tbW, tok_bfw, atom_out);
    else
      k_post<1><<<736, 256, 0, stream>>>(sln_bf, lnA, a_f, gateW, gate_b + l * 128,
                                         adaW, taW, tbW, tok_bfw, atom_out);
  }

  k_segmean<<<512, 256, 0, stream>>>(atom_out, a2t, tok_bf);
  k_tok<<<32, 256, 0, stream>>>(tok_bf, trunk_bfw, s_trunk, s_struct, u_f);
  k_pair<<<4096, 256, 0, stream>>>(tpf, W_pairin, u_f, pair_out);
}

// Round 8
// 354.072 us; speedup vs baseline: 1.7587x; 1.1031x over previous
//
#include <hip/hip_runtime.h>
#include <cstddef>

typedef unsigned short u16;
typedef __attribute__((ext_vector_type(8))) short bf8;   // 8 x bf16 (4 VGPRs)
typedef __attribute__((ext_vector_type(4))) float f4;
typedef __attribute__((ext_vector_type(4))) unsigned short us4;

#define NATOMS 11776
#define NBLK   368

__device__ __forceinline__ u16 f2b(float x){
  union { float f; unsigned u; } v; v.f = x;
  unsigned r = v.u + 0x7fffu + ((v.u >> 16) & 1u);
  return (u16)(r >> 16);
}
__device__ __forceinline__ float b2f(u16 x){
  union { unsigned u; float f; } v; v.u = ((unsigned)x) << 16;
  return v.f;
}
__device__ __forceinline__ f4 f4zero(){ f4 z = {0.f,0.f,0.f,0.f}; return z; }
__device__ __forceinline__ f4 mfma16(bf8 a, bf8 b, f4 c){
  return __builtin_amdgcn_mfma_f32_16x16x32_bf16(a, b, c, 0, 0, 0);
}
__device__ __forceinline__ int iclamp(int v, int lo, int hi){ return v < lo ? lo : (v > hi ? hi : v); }
__device__ __forceinline__ void lds_fence(){
  asm volatile("s_waitcnt lgkmcnt(0)" ::: "memory");
  __builtin_amdgcn_sched_barrier(0);
}
__device__ __forceinline__ bf8 cvt_f32x8(const float* __restrict__ p){
  float4 a = *(const float4*)p, b = *(const float4*)(p + 4);
  bf8 o;
  o[0] = (short)f2b(a.x); o[1] = (short)f2b(a.y); o[2] = (short)f2b(a.z); o[3] = (short)f2b(a.w);
  o[4] = (short)f2b(b.x); o[5] = (short)f2b(b.y); o[6] = (short)f2b(b.z); o[7] = (short)f2b(b.w);
  return o;
}

// ---------------------------------------------------------------- convert fp32 -> bf16 (weights only)
struct CvtArgs {
  const float* src[11];
  u16* dst[11];
  int n4[11];
};

__global__ __launch_bounds__(256) void k_convert(CvtArgs a){
  int stride = gridDim.x * 256;
  int tid = blockIdx.x * 256 + threadIdx.x;
  for (int s = 0; s < 11; ++s){
    const float4* src = (const float4*)a.src[s];
    us4* dst = (us4*)a.dst[s];
    int n = a.n4[s];
    for (int i = tid; i < n; i += stride){
      float4 v = src[i];
      us4 o;
      o.x = f2b(v.x); o.y = f2b(v.y); o.z = f2b(v.z); o.w = f2b(v.w);
      dst[i] = o;
    }
  }
}

// ---------------------------------------------------------------- generic 16-row MFMA strip GEMM
template<int N, int K, int LDA = K>
__device__ __forceinline__ void gemm_strip(const u16* __restrict__ A, const u16* __restrict__ W, float* L){
  constexpr int CPW = N / 4;       // cols per wave
  constexpr int T = CPW / 16;      // 16x16 tiles per wave
  const int lane = threadIdx.x & 63;
  const int wave = threadIdx.x >> 6;
  const int rr = lane & 15, grp = lane >> 4;
  f4 acc[T];
#pragma unroll
  for (int t = 0; t < T; ++t) acc[t] = f4zero();
#pragma unroll
  for (int kc = 0; kc < K / 32; ++kc){
    bf8 af = *(const bf8*)(A + rr * LDA + kc * 32 + grp * 8);
#pragma unroll
    for (int t = 0; t < T; ++t){
      const u16* wp = W + (size_t)(wave * CPW + t * 16 + rr) * K + kc * 32 + grp * 8;
      acc[t] = mfma16(af, *(const bf8*)wp, acc[t]);
    }
  }
#pragma unroll
  for (int t = 0; t < T; ++t)
#pragma unroll
    for (int r = 0; r < 4; ++r)
      L[(grp * 4 + r) * N + wave * CPW + t * 16 + rr] = acc[t][r];
}

// ---------------------------------------------------------------- fused: cond + LN + ph/pw + pre(layer 0)
// c = af@Wc^T; LN -> a_f, sln_bf; ph/pw; gb = sln@slnW0; x = sig(gb1)*ln + gb2; qkv0 = x@qkvW0
__global__ __launch_bounds__(256) void k_cond_pre(const float* __restrict__ af, const float* __restrict__ Wc,
                                                  const float* __restrict__ Wph, const float* __restrict__ Wpw,
                                                  float* __restrict__ a_f, u16* __restrict__ sln_bf,
                                                  float* __restrict__ ph, float* __restrict__ pw,
                                                  const u16* __restrict__ slnW, const u16* __restrict__ qkvW,
                                                  const float* __restrict__ qb, u16* __restrict__ qkv_out){
  __shared__ float LB[16 * 384];
  __shared__ __align__(16) u16 Xs[16 * 136];  // s_ln bf16
  __shared__ __align__(16) u16 Xr[16 * 136];  // relu(s_ln) bf16
  __shared__ __align__(16) u16 Xx[16 * 136];  // x bf16
  __shared__ float LNf[16 * 128];             // s_ln f32
  const int strip = blockIdx.x;
  const int lane = threadIdx.x & 63, wave = threadIdx.x >> 6;
  const int rr = lane & 15, grp = lane >> 4;
  // 1. c = af @ Wc^T (fp32 -> bf16 in register)
  {
    f4 acc[2];
    acc[0] = f4zero(); acc[1] = f4zero();
#pragma unroll
    for (int kc = 0; kc < 4; ++kc){
      bf8 afr = cvt_f32x8(af + (size_t)(strip * 16 + rr) * 128 + kc * 32 + grp * 8);
#pragma unroll
      for (int t = 0; t < 2; ++t){
        bf8 bfr = cvt_f32x8(Wc + (size_t)(wave * 32 + t * 16 + rr) * 128 + kc * 32 + grp * 8);
        acc[t] = mfma16(afr, bfr, acc[t]);
      }
    }
#pragma unroll
    for (int t = 0; t < 2; ++t)
#pragma unroll
      for (int r = 0; r < 4; ++r)
        LB[(grp * 4 + r) * 128 + wave * 32 + t * 16 + rr] = acc[t][r];
  }
  __syncthreads();
  // 2. LN -> a_f, sln_bf, Xs, Xr, LNf
  {
    int r = threadIdx.x >> 4, s = threadIdx.x & 15;
    float sum = 0.f, sq = 0.f;
#pragma unroll
    for (int j = 0; j < 8; ++j){ float v = LB[r * 128 + s * 8 + j]; sum += v; sq += v * v; }
#pragma unroll
    for (int m = 1; m < 16; m <<= 1){ sum += __shfl_xor(sum, m); sq += __shfl_xor(sq, m); }
    float mu = sum * (1.f / 128.f);
    float var = sq * (1.f / 128.f) - mu * mu;
    float rs = rsqrtf(var + 1e-5f);
#pragma unroll
    for (int j = 0; j < 8; ++j){
      int c = s * 8 + j;
      float v = LB[r * 128 + c];
      size_t idx = (size_t)(strip * 16 + r) * 128 + c;
      a_f[idx] = v;
      float ln = (v - mu) * rs;
      LNf[r * 128 + c] = ln;
      u16 lb = f2b(ln);
      sln_bf[idx] = lb;
      Xs[r * 136 + c] = lb;
      Xr[r * 136 + c] = f2b(fmaxf(ln, 0.f));
    }
  }
  __syncthreads();
  // 3. gb = s_ln @ slnW
  gemm_strip<256, 128, 136>(Xs, slnW, LB);
  __syncthreads();
  // 4. x = sigmoid(gb1)*ln + gb2
  for (int i = threadIdx.x; i < 2048; i += 256){
    int r = i >> 7, c = i & 127;
    float g1 = LB[r * 256 + c], g2 = LB[r * 256 + 128 + c];
    float s = 1.f / (1.f + __expf(-g1));
    Xx[r * 136 + c] = f2b(s * LNf[r * 128 + c] + g2);
  }
  __syncthreads();
  // 5. qkv = x @ qkvW
  gemm_strip<384, 128, 136>(Xx, qkvW, LB);
  __syncthreads();
  const float scale = 0.17677669529663687f;
  for (int i = threadIdx.x; i < 16 * 384; i += 256){
    int r = i / 384, c = i - r * 384;
    float v = LB[i];
    if (c < 128) v = (v + qb[c]) * scale;
    qkv_out[(size_t)(strip * 16 + r) * 384 + c] = f2b(v);
  }
  // 6. ph/pw (waves 0/1, reads Xr)
  if (wave < 2){
    const float* Wsel = wave ? Wpw : Wph;
    f4 acc = f4zero();
#pragma unroll
    for (int kc = 0; kc < 4; ++kc){
      bf8 afr = *(const bf8*)(&Xr[rr * 136 + kc * 32 + grp * 8]);
      bf8 bfr = cvt_f32x8(Wsel + (size_t)rr * 128 + kc * 32 + grp * 8);
      acc = mfma16(afr, bfr, acc);
    }
    float* out = wave ? pw : ph;
#pragma unroll
    for (int r = 0; r < 4; ++r)
      out[(size_t)(strip * 16 + grp * 4 + r) * 16 + rr] = acc[r];
  }
}

// ---------------------------------------------------------------- fused post(l) [+ pre(l+1) | + tok relu-GEMM]
// gate + ada->x2->ta->glu->tb->residual; then LAST ? tok-GEMM : LN(LDS)+sln2->x->qkv2
template<int LAST>
__global__ __launch_bounds__(256) void k_postpre(const u16* __restrict__ sln, const float* __restrict__ lnA,
                                                 float* __restrict__ a,
                                                 const u16* __restrict__ gateW, const float* __restrict__ gbias,
                                                 const u16* __restrict__ adaW, const u16* __restrict__ taW,
                                                 const u16* __restrict__ tbW,
                                                 const u16* __restrict__ slnW2, const u16* __restrict__ qkvW2,
                                                 const float* __restrict__ qb2, u16* __restrict__ qkv_out,
                                                 const u16* __restrict__ tokW, float* __restrict__ atom_out){
  __shared__ float LB[16 * 512];
  __shared__ __align__(16) u16 X[16 * 136];
  __shared__ __align__(16) u16 G[16 * 264];
  __shared__ float LNf[16 * 128];
  const int strip = blockIdx.x;
  const u16* Ag = sln + (size_t)strip * 2048;
  // gate -> registers
  float gv[8];
  gemm_strip<128, 128>(Ag, gateW, LB);
  __syncthreads();
#pragma unroll
  for (int ii = 0; ii < 8; ++ii){
    int i = threadIdx.x + 256 * ii;
    int c = i & 127;
    gv[ii] = 1.f / (1.f + __expf(-(LB[i] + gbias[c])));
  }
  __syncthreads();
  gemm_strip<256, 128>(Ag, adaW, LB);
  __syncthreads();
  for (int i = threadIdx.x; i < 2048; i += 256){
    int r = i >> 7, c = i & 127;
    float g1 = LB[r * 256 + c], g2 = LB[r * 256 + 128 + c];
    float s = 1.f / (1.f + __expf(-g1));
    X[r * 136 + c] = f2b(s * lnA[(size_t)(strip * 16 + r) * 128 + c] + g2);
  }
  __syncthreads();
  gemm_strip<512, 128, 136>(X, taW, LB);
  __syncthreads();
  for (int i = threadIdx.x; i < 16 * 256; i += 256){
    int r = i >> 8, c = i & 255;
    float ab1 = LB[r * 512 + c], ab2 = LB[r * 512 + 256 + c];
    G[r * 264 + c] = f2b(ab1 / (1.f + __expf(-ab1)) * ab2);
  }
  __syncthreads();
  gemm_strip<128, 256, 264>(G, tbW, LB);
  __syncthreads();
#pragma unroll
  for (int ii = 0; ii < 8; ++ii){
    int i = threadIdx.x + 256 * ii;
    size_t idx = (size_t)strip * 2048 + i;
    float v = a[idx] + gv[ii] * LB[i];
    a[idx] = v;
    LB[i] = v;
    if (LAST){ int r = i >> 7, c = i & 127; X[r * 136 + c] = f2b(v); }
  }
  __syncthreads();
  if (!LAST){
    // LN (LDS only — consumed by fused pre below)
    {
      int r = threadIdx.x >> 4, s = threadIdx.x & 15;
      float sum = 0.f, sq = 0.f;
#pragma unroll
      for (int j = 0; j < 8; ++j){ float v = LB[r * 128 + s * 8 + j]; sum += v; sq += v * v; }
#pragma unroll
      for (int m = 1; m < 16; m <<= 1){ sum += __shfl_xor(sum, m); sq += __shfl_xor(sq, m); }
      float mu = sum * (1.f / 128.f);
      float var = sq * (1.f / 128.f) - mu * mu;
      float rs = rsqrtf(var + 1e-5f);
#pragma unroll
      for (int j = 0; j < 8; ++j){
        int c = s * 8 + j;
        LNf[r * 128 + c] = (LB[r * 128 + c] - mu) * rs;
      }
    }
    __syncthreads();
    // pre(l+1): gb = s_ln @ slnW2
    gemm_strip<256, 128>(Ag, slnW2, LB);
    __syncthreads();
    for (int i = threadIdx.x; i < 2048; i += 256){
      int r = i >> 7, c = i & 127;
      float g1 = LB[r * 256 + c], g2 = LB[r * 256 + 128 + c];
      float s = 1.f / (1.f + __expf(-g1));
      X[r * 136 + c] = f2b(s * LNf[r * 128 + c] + g2);
    }
    __syncthreads();
    gemm_strip<384, 128, 136>(X, qkvW2, LB);
    __syncthreads();
    const float scale = 0.17677669529663687f;
    for (int i = threadIdx.x; i < 16 * 384; i += 256){
      int r = i / 384, c = i - r * 384;
      float v = LB[i];
      if (c < 128) v = (v + qb2[c]) * scale;
      qkv_out[(size_t)(strip * 16 + r) * 384 + c] = f2b(v);
    }
  } else {
    gemm_strip<384, 128, 136>(X, tokW, LB);
    __syncthreads();
    const size_t base = (size_t)strip * 16 * 384;
    for (int i = threadIdx.x; i < 16 * 384; i += 256) atom_out[base + i] = fmaxf(LB[i], 0.f);
  }
}

// ---------------------------------------------------------------- pair-bias MLP: all-MFMA, zero shuffles
__global__ __launch_bounds__(256) void k_pb(const float* __restrict__ ph, const float* __restrict__ pw,
                                            const float* __restrict__ W1, const float* __restrict__ W2,
                                            const float* __restrict__ lnw, const float* __restrict__ lnb,
                                            const float* __restrict__ pbw, float* __restrict__ bias){
  __shared__ __align__(16) u16 mt[4][16 * 24];
  __shared__ __align__(16) u16 vt[4][16 * 24];
  const int t = threadIdx.x;
  const int lane = t & 63, wave = t >> 6;
  const int rr = lane & 15, grp = lane >> 4;
  const int b = blockIdx.x >> 3, qg = blockIdx.x & 7;
  const int q = qg * 4 + wave;
  const int qa = b * 32 + q;

  bf8 wf1 = {0,0,0,0,0,0,0,0}, wf2 = {0,0,0,0,0,0,0,0};
  bf8 bproj = {0,0,0,0,0,0,0,0}, bones = {0,0,0,0,0,0,0,0};
  if (grp < 2){
#pragma unroll
    for (int j = 0; j < 8; ++j){
      wf1[j] = (short)f2b(W1[rr * 16 + grp * 8 + j]);
      wf2[j] = (short)f2b(W2[rr * 16 + grp * 8 + j]);
      bones[j] = (short)0x3F80;
    }
    if (rr < 4){
#pragma unroll
      for (int j = 0; j < 8; ++j)
        bproj[j] = (short)f2b(pbw[rr * 16 + grp * 8 + j] * lnw[grp * 8 + j]);
    }
  }
  float w2s_r = 0.f, bb_r = 0.f;
  if (rr < 4){
#pragma unroll
    for (int cc = 0; cc < 16; ++cc){
      float pv = pbw[rr * 16 + cc];
      w2s_r += pv * lnw[cc];
      bb_r  += pv * lnb[cc];
    }
  }
  const float* phq = ph + (size_t)qa * 16;
  float pha[8];
  if (grp < 2){
#pragma unroll
    for (int j = 0; j < 8; ++j) pha[j] = phq[grp * 8 + j];
  }
  const float ph_r = phq[rr];
  u16* mw = &mt[wave][0];
  u16* vw = &vt[wave][0];

  for (int kt = 0; kt < 8; ++kt){
    const int k0 = kt * 16;
    bf8 af = {0,0,0,0,0,0,0,0};
    if (grp < 2){
      int winA = b * 32 + k0 + rr - 48;
      int kaA = iclamp(winA, 0, NATOMS - 1);
      const float* pwr = pw + (size_t)kaA * 16 + grp * 8;
#pragma unroll
      for (int j = 0; j < 8; ++j) af[j] = (short)f2b(fmaxf(pha[j] + pwr[j], 0.f));
    }
    f4 c1 = mfma16(af, wf1, f4zero());
#pragma unroll
    for (int r = 0; r < 4; ++r)
      mw[(grp * 4 + r) * 24 + rr] = f2b(fmaxf(c1[r], 0.f));
    lds_fence();
    bf8 mf = {0,0,0,0,0,0,0,0};
    if (grp < 2) mf = *(const bf8*)(mw + rr * 24 + grp * 8);
    f4 c2 = mfma16(mf, wf2, f4zero());
#pragma unroll
    for (int r = 0; r < 4; ++r){
      int win = b * 32 + k0 + grp * 4 + r - 48;
      int ka = iclamp(win, 0, NATOMS - 1);
      float v = c2[r] + ph_r + pw[(size_t)ka * 16 + rr];
      vw[(grp * 4 + r) * 24 + rr] = f2b(v);
    }
    lds_fence();
    bf8 vf = {0,0,0,0,0,0,0,0}, vf2 = {0,0,0,0,0,0,0,0};
    if (grp < 2){
      vf = *(const bf8*)(vw + rr * 24 + grp * 8);
#pragma unroll
      for (int j = 0; j < 8; ++j){
        float x = b2f((u16)vf[j]);
        union { float f; unsigned u; } s; s.f = x * x;
        vf2[j] = (short)(u16)(s.u >> 16);
      }
    }
    f4 T1 = mfma16(vf, bproj, f4zero());
    f4 T2 = mfma16(vf, bones, f4zero());
    f4 T3 = mfma16(vf2, bones, f4zero());
    if (rr < 4){
      float4 o;
      float ov[4];
#pragma unroll
      for (int r = 0; r < 4; ++r){
        int win = b * 32 + k0 + grp * 4 + r - 48;
        bool valid = (win >= 0) && (win < NATOMS);
        float S = T2[r], Q = T3[r], d = T1[r];
        float mu = S * (1.f / 16.f);
        float var = Q * (1.f / 16.f) - mu * mu;
        float rq = rsqrtf(var + 1e-5f);
        ov[r] = rq * (d - mu * w2s_r) + bb_r + (valid ? 0.f : -1e9f);
      }
      o.x = ov[0]; o.y = ov[1]; o.z = ov[2]; o.w = ov[3];
      *(float4*)(bias + ((size_t)((b * 4 + rr) * 32) + q) * 128 + k0 + grp * 4) = o;
    }
  }
}

// ---------------------------------------------------------------- block attention + out-proj + residual + row-LN
__global__ __launch_bounds__(256) void k_attn(const u16* __restrict__ qkv, const float* __restrict__ bias,
                                              const u16* __restrict__ outw, const float* __restrict__ outb,
                                              float* __restrict__ a, float* __restrict__ lnA){
  __shared__ u16 VT[128][136];
  __shared__ u16 P[4][32 * 136];
  __shared__ u16 O[32][136];
  __shared__ float part2[32][8];
  const int t = threadIdx.x;
  const int lane = t & 63, wave = t >> 6;
  const int b = blockIdx.x;
  const int rr = lane & 15, grp = lane >> 4;

  for (int i = 0; i < 8; ++i){
    int s = t + 256 * i;
    int ka = s & 127, d0 = (s >> 7) * 8;
    int win = b * 32 + ka - 48;
    int src = iclamp(win, 0, NATOMS - 1);
    bf8 v = *(const bf8*)(qkv + (size_t)src * 384 + 256 + d0);
#pragma unroll
    for (int j = 0; j < 8; ++j) VT[d0 + j][ka] = (u16)v[j];
  }
  __syncthreads();

  const int h = wave;
  bf8 kfr[8];
#pragma unroll
  for (int kt = 0; kt < 8; ++kt){
    int ka = kt * 16 + rr;
    int win = b * 32 + ka - 48;
    int src = iclamp(win, 0, NATOMS - 1);
    kfr[kt] = *(const bf8*)(qkv + (size_t)src * 384 + 128 + h * 32 + grp * 8);
  }
  f4 S[2][8];
#pragma unroll
  for (int qt = 0; qt < 2; ++qt){
    bf8 qf = *(const bf8*)(qkv + (size_t)(b * 32 + qt * 16 + rr) * 384 + h * 32 + grp * 8);
#pragma unroll
    for (int kt = 0; kt < 8; ++kt){
      S[qt][kt] = f4zero();
      S[qt][kt] = mfma16(qf, kfr[kt], S[qt][kt]);
    }
  }
  const float* brow = bias + (size_t)((b * 4 + h) * 32) * 128;
#pragma unroll
  for (int qt = 0; qt < 2; ++qt){
#pragma unroll
    for (int r = 0; r < 4; ++r){
      int q = qt * 16 + grp * 4 + r;
      float vals[8];
      float mx = -1e30f;
#pragma unroll
      for (int kt = 0; kt < 8; ++kt){
        float v = S[qt][kt][r] + brow[q * 128 + kt * 16 + rr];
        vals[kt] = v;
        mx = fmaxf(mx, v);
      }
#pragma unroll
      for (int m = 1; m < 16; m <<= 1) mx = fmaxf(mx, __shfl_xor(mx, m));
      float sum = 0.f;
#pragma unroll
      for (int kt = 0; kt < 8; ++kt){ vals[kt] = __expf(vals[kt] - mx); sum += vals[kt]; }
#pragma unroll
      for (int m = 1; m < 16; m <<= 1) sum += __shfl_xor(sum, m);
      float inv = 1.f / sum;
#pragma unroll
      for (int kt = 0; kt < 8; ++kt)
        P[h][q * 136 + kt * 16 + rr] = f2b(vals[kt] * inv);
    }
  }
  __syncthreads();
  f4 oacc[2][2];
#pragma unroll
  for (int qt = 0; qt < 2; ++qt)
#pragma unroll
    for (int dt = 0; dt < 2; ++dt) oacc[qt][dt] = f4zero();
#pragma unroll
  for (int kc = 0; kc < 4; ++kc){
#pragma unroll
    for (int qt = 0; qt < 2; ++qt){
      bf8 pa = *(const bf8*)(&P[h][(qt * 16 + rr) * 136 + kc * 32 + grp * 8]);
#pragma unroll
      for (int dt = 0; dt < 2; ++dt){
        bf8 vb = *(const bf8*)(&VT[h * 32 + dt * 16 + rr][kc * 32 + grp * 8]);
        oacc[qt][dt] = mfma16(pa, vb, oacc[qt][dt]);
      }
    }
  }
#pragma unroll
  for (int qt = 0; qt < 2; ++qt)
#pragma unroll
    for (int dt = 0; dt < 2; ++dt)
#pragma unroll
      for (int r = 0; r < 4; ++r)
        O[qt * 16 + grp * 4 + r][h * 32 + dt * 16 + rr] = f2b(oacc[qt][dt][r]);
  __syncthreads();
  f4 pacc[2][2];
#pragma unroll
  for (int qt = 0; qt < 2; ++qt)
#pragma unroll
    for (int ct = 0; ct < 2; ++ct) pacc[qt][ct] = f4zero();
#pragma unroll
  for (int kc = 0; kc < 4; ++kc){
    bf8 a0 = *(const bf8*)(&O[rr][kc * 32 + grp * 8]);
    bf8 a1 = *(const bf8*)(&O[16 + rr][kc * 32 + grp * 8]);
#pragma unroll
    for (int ct = 0; ct < 2; ++ct){
      bf8 wf = *(const bf8*)(outw + (size_t)(wave * 32 + ct * 16 + rr) * 128 + kc * 32 + grp * 8);
      pacc[0][ct] = mfma16(a0, wf, pacc[0][ct]);
      pacc[1][ct] = mfma16(a1, wf, pacc[1][ct]);
    }
  }
  float vv[2][2][4];
#pragma unroll
  for (int qt = 0; qt < 2; ++qt)
#pragma unroll
    for (int ct = 0; ct < 2; ++ct)
#pragma unroll
      for (int r = 0; r < 4; ++r){
        int q = qt * 16 + grp * 4 + r;
        int col = wave * 32 + ct * 16 + rr;
        size_t idx = (size_t)(b * 32 + q) * 128 + col;
        float v = a[idx] + pacc[qt][ct][r] + outb[col];
        a[idx] = v;
        vv[qt][ct][r] = v;
      }
#pragma unroll
  for (int qt = 0; qt < 2; ++qt)
#pragma unroll
    for (int r = 0; r < 4; ++r){
      float ps = vv[qt][0][r] + vv[qt][1][r];
      float pq = vv[qt][0][r] * vv[qt][0][r] + vv[qt][1][r] * vv[qt][1][r];
#pragma unroll
      for (int m = 1; m < 16; m <<= 1){ ps += __shfl_xor(ps, m); pq += __shfl_xor(pq, m); }
      if (rr == 0){
        int q = qt * 16 + grp * 4 + r;
        part2[q][wave * 2] = ps;
        part2[q][wave * 2 + 1] = pq;
      }
    }
  __syncthreads();
#pragma unroll
  for (int qt = 0; qt < 2; ++qt)
#pragma unroll
    for (int r = 0; r < 4; ++r){
      int q = qt * 16 + grp * 4 + r;
      f4 p0 = *(const f4*)&part2[q][0];
      f4 p1 = *(const f4*)&part2[q][4];
      float S = p0[0] + p0[2] + p1[0] + p1[2];
      float Q = p0[1] + p0[3] + p1[1] + p1[3];
      float mu = S * (1.f / 128.f);
      float var = Q * (1.f / 128.f) - mu * mu;
      float rs = rsqrtf(var + 1e-5f);
#pragma unroll
      for (int ct = 0; ct < 2; ++ct){
        int col = wave * 32 + ct * 16 + rr;
        lnA[(size_t)(b * 32 + q) * 128 + col] = (vv[qt][ct][r] - mu) * rs;
      }
    }
}

// ---------------------------------------------------------------- segment mean (atoms -> tokens)
__device__ __forceinline__ int lbound(const int* __restrict__ arr, int n, int v){
  int lo = 0, hi = n;
  while (lo < hi){ int mid = (lo + hi) >> 1; if (arr[mid] < v) lo = mid + 1; else hi = mid; }
  return lo;
}

__global__ __launch_bounds__(256) void k_segmean(const float* __restrict__ atom_out,
                                                 const int* __restrict__ a2t, u16* __restrict__ tokbf){
  const int tok = blockIdx.x;
  __shared__ int lo_s, hi_s;
  if (threadIdx.x == 0){
    lo_s = lbound(a2t, NATOMS, tok);
    hi_s = lbound(a2t, NATOMS, tok + 1);
  }
  __syncthreads();
  int lo = lo_s, hi = hi_s;
  float inv = 1.f / fmaxf((float)(hi - lo), 1.f);
  for (int c = threadIdx.x; c < 384; c += 256){
    float s = 0.f;
    for (int aa = lo; aa < hi; ++aa) s += atom_out[(size_t)aa * 384 + c];
    tokbf[(size_t)tok * 384 + c] = f2b(s * inv);
  }
}

// ---------------------------------------------------------------- token head: grid 128 (strip x col-quarter)
__global__ __launch_bounds__(256) void k_tok(const u16* __restrict__ tok, const u16* __restrict__ catW,
                                             float* __restrict__ s_trunk, float* __restrict__ s_struct,
                                             float* __restrict__ u_f){
  __shared__ float LB[16 * 256];
  const int strip = blockIdx.x >> 2, quad = blockIdx.x & 3;
  gemm_strip<256, 384>(tok + (size_t)strip * 16 * 384, catW + (size_t)quad * 256 * 384, LB);
  __syncthreads();
  for (int i = threadIdx.x; i < 16 * 256; i += 256){
    int r = i >> 8, c = i & 255;
    int row = strip * 16 + r;
    int cg = quad * 256 + c;
    float v = LB[i];
    if (cg < 384) s_trunk[(size_t)row * 384 + cg] = v;
    else if (cg < 768) s_struct[(size_t)row * 384 + (cg - 384)] = v;
    else u_f[(size_t)row * 256 + (cg - 768)] = v;
  }
}

// ---------------------------------------------------------------- pair head: MFMA GEMM (K=32) + u_i + u_j
__global__ __launch_bounds__(256) void k_pair(const float* __restrict__ tpf, const float* __restrict__ Wp,
                                              const float* __restrict__ u, float* __restrict__ out){
  const int lane = threadIdx.x & 63, wave = threadIdx.x >> 6;
  const int rr = lane & 15, grp = lane >> 4;
  const int pairbase = blockIdx.x * 64 + wave * 16;
  const int i = (blockIdx.x * 64) >> 9;
  bf8 af;
  {
    const float* tr = tpf + (size_t)(pairbase + rr) * 32 + grp * 8;
#pragma unroll
    for (int j = 0; j < 8; ++j) af[j] = (short)f2b(tr[j]);
  }
  f4 acc[8];
#pragma unroll
  for (int t = 0; t < 8; ++t){
    bf8 bf;
    const float* wr = Wp + (size_t)(t * 16 + rr) * 32 + grp * 8;
#pragma unroll
    for (int j = 0; j < 8; ++j) bf[j] = (short)f2b(wr[j]);
    acc[t] = mfma16(af, bf, f4zero());
  }
  const float* ui = u + (size_t)i * 256;
#pragma unroll
  for (int t = 0; t < 8; ++t){
    int c = t * 16 + rr;
    float uic = ui[c];
#pragma unroll
    for (int r = 0; r < 4; ++r){
      int p = pairbase + grp * 4 + r;
      int j = p & 511;
      out[(size_t)p * 128 + c] = acc[t][r] + uic + u[(size_t)j * 256 + 128 + c];
    }
  }
}

// ================================================================ host
extern "C" void kernel_launch(void* const* d_in, const int* in_sizes, int n_in,
                              void* d_out, int out_size, void* d_ws, size_t ws_size,
                              hipStream_t stream){
  (void)in_sizes; (void)n_in; (void)out_size; (void)ws_size;
  const float* atom_feats = (const float*)d_in[0];
  const float* tpf        = (const float*)d_in[1];
  const float* W_cond     = (const float*)d_in[2];
  const float* W_ph       = (const float*)d_in[3];
  const float* W_pw       = (const float*)d_in[4];
  const float* W_mlp1     = (const float*)d_in[5];
  const float* W_mlp2     = (const float*)d_in[6];
  const float* pb_ln_w    = (const float*)d_in[7];
  const float* pb_ln_b    = (const float*)d_in[8];
  const float* pb_w       = (const float*)d_in[9];
  const float* sln_w      = (const float*)d_in[10];
  const float* qkv_w      = (const float*)d_in[11];
  const float* q_bias     = (const float*)d_in[12];
  const float* out_w      = (const float*)d_in[13];
  const float* out_b      = (const float*)d_in[14];
  const float* ada_w      = (const float*)d_in[15];
  const float* ta_w       = (const float*)d_in[16];
  const float* tb_w       = (const float*)d_in[17];
  const float* gate_w     = (const float*)d_in[18];
  const float* gate_b     = (const float*)d_in[19];
  const float* W_tok      = (const float*)d_in[20];
  const float* W_trunk    = (const float*)d_in[21];
  const float* W_struct   = (const float*)d_in[22];
  const float* W_pairin   = (const float*)d_in[23];
  const float* W_outer    = (const float*)d_in[24];
  const int*   a2t        = (const int*)d_in[28];

  char* wsb = (char*)d_ws;
  size_t off = 0;
  auto alc = [&](size_t bytes) -> void* {
    void* r = wsb + off;
    off = (off + bytes + 255) & ~(size_t)255;
    return r;
  };

  u16* sln_bfw   = (u16*)alc(98304 * 2);
  u16* qkv_bfw   = (u16*)alc(147456 * 2);
  u16* out_bfw   = (u16*)alc(49152 * 2);
  u16* ada_bfw   = (u16*)alc(98304 * 2);
  u16* ta_bfw    = (u16*)alc(196608 * 2);
  u16* tb_bfw    = (u16*)alc(98304 * 2);
  u16* gate_bfw  = (u16*)alc(49152 * 2);
  u16* tok_bfw   = (u16*)alc(49152 * 2);
  // trunk/struct/outer contiguous -> one concatenated [1024][384] weight for k_tok
  u16* trunk_bfw = (u16*)alc(147456 * 2);
  u16* struct_bfw= (u16*)alc(147456 * 2);
  u16* outer_bfw = (u16*)alc(98304 * 2);
  float* a_f     = (float*)alc((size_t)NATOMS * 128 * 4);
  float* lnA     = (float*)alc((size_t)NATOMS * 128 * 4);
  u16* sln_bf    = (u16*)alc((size_t)NATOMS * 128 * 2);
  u16* qkv_bf    = (u16*)alc((size_t)NATOMS * 384 * 2);
  float* ph      = (float*)alc((size_t)NATOMS * 16 * 4);
  float* pw      = (float*)alc((size_t)NATOMS * 16 * 4);
  float* bias    = (float*)alc((size_t)NBLK * 4 * 32 * 128 * 4);
  float* atom_out= bias; // alias: bias dead after layer-2 attention
  u16* tok_bf    = (u16*)alc(512 * 384 * 2);
  float* u_f     = (float*)alc(512 * 256 * 4);

  float* s_trunk  = (float*)d_out;
  float* s_struct = s_trunk + 512 * 384;
  float* pair_out = s_struct + 512 * 384;

  CvtArgs ca;
  const float* srcs[11] = {sln_w, qkv_w, out_w, ada_w, ta_w, tb_w, gate_w,
                           W_tok, W_trunk, W_struct, W_outer};
  u16* dsts[11] = {sln_bfw, qkv_bfw, out_bfw, ada_bfw, ta_bfw, tb_bfw, gate_bfw,
                   tok_bfw, trunk_bfw, struct_bfw, outer_bfw};
  int n4s[11] = {24576, 36864, 12288, 24576, 49152, 24576, 12288,
                 12288, 36864, 36864, 24576};
  for (int s = 0; s < 11; ++s){ ca.src[s] = srcs[s]; ca.dst[s] = dsts[s]; ca.n4[s] = n4s[s]; }
  k_convert<<<256, 256, 0, stream>>>(ca);

  // cond + LN + ph/pw + pre(layer 0)
  k_cond_pre<<<736, 256, 0, stream>>>(atom_feats, W_cond, W_ph, W_pw, a_f, sln_bf, ph, pw,
                                      sln_bfw, qkv_bfw, q_bias, qkv_bf);
  k_pb<<<NBLK * 8, 256, 0, stream>>>(ph, pw, W_mlp1, W_mlp2, pb_ln_w, pb_ln_b, pb_w, bias);

  for (int l = 0; l < 3; ++l){
    const u16* outW  = out_bfw  + (size_t)l * 128 * 128;
    const u16* adaW  = ada_bfw  + (size_t)l * 256 * 128;
    const u16* taW   = ta_bfw   + (size_t)l * 512 * 128;
    const u16* tbW   = tb_bfw   + (size_t)l * 128 * 256;
    const u16* gateW = gate_bfw + (size_t)l * 128 * 128;
    k_attn<<<NBLK, 256, 0, stream>>>(qkv_bf, bias, outW, out_b + l * 128, a_f, lnA);
    if (l < 2){
      const u16* slnW2 = sln_bfw + (size_t)(l + 1) * 256 * 128;
      const u16* qkvW2 = qkv_bfw + (size_t)(l + 1) * 384 * 128;
      k_postpre<0><<<736, 256, 0, stream>>>(sln_bf, lnA, a_f, gateW, gate_b + l * 128,
                                            adaW, taW, tbW, slnW2, qkvW2,
                                            q_bias + (l + 1) * 128, qkv_bf,
                                            nullptr, nullptr);
    } else {
      k_postpre<1><<<736, 256, 0, stream>>>(sln_bf, lnA, a_f, gateW, gate_b + l * 128,
                                            adaW, taW, tbW, nullptr, nullptr,
                                            nullptr, nullptr,
                                            tok_bfw, atom_out);
    }
  }

  k_segmean<<<512, 256, 0, stream>>>(atom_out, a2t, tok_bf);
  k_tok<<<128, 256, 0, stream>>>(tok_bf, trunk_bfw, s_trunk, s_struct, u_f);
  k_pair<<<4096, 256, 0, stream>>>(tpf, W_pairin, u_f, pair_out);
}